// Round 13
// baseline (354.654 us; speedup 1.0000x reference)
//
#include <hip/hip_runtime.h>
#include <cstdint>
#include <cstddef>

#define LSEQ 2048
#define NB   4
#define DMODEL 1024
#define DINNER 2048
#define NST  16
#define CH   128   // scan chunk length == GEMM tile height
#define SCH  (LSEQ / CH)   // 16 chunks
#define NBD  512           // NB * DINNER/16 (p2 layout)
#define STT  16    // scan steps per LDS tile (new p1/p3)
#define SDB  128   // channels per scan block (new p1/p3)

typedef short bf16x8 __attribute__((ext_vector_type(8)));
typedef float f32x4  __attribute__((ext_vector_type(4)));
typedef unsigned short ushort8v __attribute__((ext_vector_type(8)));

__device__ __forceinline__ float siluf(float x) { return x / (1.f + __expf(-x)); }

__device__ __forceinline__ unsigned short f2bf(float f) {
    unsigned u = __float_as_uint(f);
    u += 0x7FFF + ((u >> 16) & 1);     // round-to-nearest-even
    return (unsigned short)(u >> 16);
}
__device__ __forceinline__ float bf2f(unsigned short h) {
    return __uint_as_float(((unsigned)h) << 16);
}
__device__ __forceinline__ void gload_lds16(const void* g, void* l) {
    __builtin_amdgcn_global_load_lds(
        (const __attribute__((address_space(1))) unsigned int*)g,
        (__attribute__((address_space(3))) unsigned int*)l, 16, 0, 0);
}

// ---------------- fused RMSNorm + bf16 convert ----------------
__global__ __launch_bounds__(256) void rmsnorm_cvt_k(const float* __restrict__ x,
                                                     const float* __restrict__ nw,
                                                     unsigned short* __restrict__ o) {
    int row = blockIdx.x, t = threadIdx.x;
    float4 v = ((const float4*)(x + (size_t)row * DMODEL))[t];
    float s = v.x * v.x + v.y * v.y + v.z * v.z + v.w * v.w;
#pragma unroll
    for (int m = 32; m >= 1; m >>= 1) s += __shfl_xor(s, m);
    __shared__ float wsum[4];
    __shared__ float sinv;
    if ((t & 63) == 0) wsum[t >> 6] = s;
    __syncthreads();
    if (t == 0) {
        float tot = wsum[0] + wsum[1] + wsum[2] + wsum[3];
        sinv = rsqrtf(tot * (1.f / (float)DMODEL) + 1e-6f);
    }
    __syncthreads();
    float iv = sinv;
    float4 w = ((const float4*)nw)[t];
    ushort4 ov;
    ov.x = f2bf(v.x * iv * w.x); ov.y = f2bf(v.y * iv * w.y);
    ov.z = f2bf(v.z * iv * w.z); ov.w = f2bf(v.w * iv * w.w);
    ((ushort4*)(o + (size_t)row * DMODEL))[t] = ov;
}

// ---------------- fused weight conversions (4 matrices, 1 launch) ----------------
__global__ __launch_bounds__(256) void cvt_all_k(const float* __restrict__ s0, const float* __restrict__ s1,
                                                 const float* __restrict__ s2, const float* __restrict__ s3,
                                                 unsigned short* __restrict__ q0, unsigned short* __restrict__ q1,
                                                 unsigned short* __restrict__ q2, unsigned short* __restrict__ q3) {
    int i = blockIdx.x * 256 + threadIdx.x;
    const float* s; unsigned short* d; int off;
    if (i < 1048576)       { s = s0; d = q0; off = i; }
    else if (i < 1572864)  { s = s1; d = q1; off = i - 1048576; }
    else if (i < 1622016)  { s = s2; d = q2; off = i - 1572864; }
    else if (i < 1654784)  { s = s3; d = q3; off = i - 1622016; }
    else return;
    float4 v = ((const float4*)s)[off];
    ushort4 o;
    o.x = f2bf(v.x); o.y = f2bf(v.y); o.z = f2bf(v.z); o.w = f2bf(v.w);
    ((ushort4*)d)[off] = o;
}

// ---------------- bf16 MFMA NT GEMM: dbuf LDS + counted vmcnt + XOR swizzle (round-10) ----------------
template <int EPI>
__global__ __launch_bounds__(256) void gemm_bf16(
    const unsigned short* __restrict__ A, int lda,
    const unsigned short* __restrict__ W, int ldw,
    void* __restrict__ Cv, void* __restrict__ C2v, int ldc,
    int M, int N, int K, int nbx,
    const float* __restrict__ bias,
    const float* __restrict__ residual,
    unsigned short* __restrict__ aux,
    const int* __restrict__ lengths) {
    __shared__ __align__(16) unsigned short As[2][128 * 64];
    __shared__ __align__(16) unsigned short Bs[2][128 * 64];
    const int bid = blockIdx.x;
    const int bx = bid % nbx, by = bid / nbx;
    const int row0 = by * 128, col0 = bx * 128;
    const int t = threadIdx.x;

    const int len0 = lengths[row0 >> 11];
    if ((row0 & (LSEQ - 1)) >= len0) {
        if (EPI == 2) {
            float* C = (float*)Cv;
#pragma unroll
            for (int i = 0; i < 16; ++i) {
                int lin = i * 256 + t;
                int r = lin >> 5, c = (lin & 31) << 2;
                *(float4*)(C + (size_t)(row0 + r) * ldc + col0 + c) =
                    *(const float4*)(residual + (size_t)(row0 + r) * ldc + col0 + c);
            }
        }
        return;
    }

    const int lane = t & 63;
    const int w = t >> 6;
    const int wr = w >> 1, wc = w & 1;

    f32x4 acc[4][4];
#pragma unroll
    for (int m = 0; m < 4; ++m)
#pragma unroll
        for (int n = 0; n < 4; ++n) acc[m][n] = f32x4{0.f, 0.f, 0.f, 0.f};

    const int rA = lane & 15;
    const int kH = (lane >> 4) << 3;
    const int NT = K >> 6;
    const int swzR = (rA & 7) << 3;

    auto STAGE = [&](int sel, int k0) {
#pragma unroll
        for (int it = 0; it < 4; ++it) {
            int c = it * 256 + t;
            int r = c >> 3;
            int cc = ((c & 7) ^ (r & 7)) << 3;
            gload_lds16(A + (size_t)(row0 + r) * lda + k0 + cc, &As[sel][c << 3]);
            int wrow = col0 + r; if (wrow >= N) wrow = N - 1;
            gload_lds16(W + (size_t)wrow * ldw + k0 + cc, &Bs[sel][c << 3]);
        }
    };

    STAGE(0, 0);
    for (int kt = 0; kt < NT; ++kt) {
        const int cur = kt & 1;
        if (kt + 1 < NT) STAGE(cur ^ 1, (kt + 1) << 6);
        __builtin_amdgcn_sched_barrier(0);
        if (kt + 1 < NT) { asm volatile("s_waitcnt vmcnt(8)" ::: "memory"); }
        else             { asm volatile("s_waitcnt vmcnt(0)" ::: "memory"); }
        __builtin_amdgcn_sched_barrier(0);
        __builtin_amdgcn_s_barrier();
        __builtin_amdgcn_sched_barrier(0);
#pragma unroll
        for (int ks = 0; ks < 2; ++ks) {
            const int kkS = (ks * 32 + kH) ^ swzR;
            bf16x8 af[4], bfr[4];
#pragma unroll
            for (int m = 0; m < 4; ++m)
                af[m] = *(const bf16x8*)&As[cur][(wr * 64 + m * 16 + rA) * 64 + kkS];
#pragma unroll
            for (int n = 0; n < 4; ++n)
                bfr[n] = *(const bf16x8*)&Bs[cur][(wc * 64 + n * 16 + rA) * 64 + kkS];
#pragma unroll
            for (int m = 0; m < 4; ++m)
#pragma unroll
                for (int n = 0; n < 4; ++n)
                    acc[m][n] = __builtin_amdgcn_mfma_f32_16x16x32_bf16(
                        af[m], bfr[n], acc[m][n], 0, 0, 0);
        }
        __builtin_amdgcn_sched_barrier(0);
        asm volatile("s_waitcnt lgkmcnt(0)" ::: "memory");
        __builtin_amdgcn_s_barrier();
        __builtin_amdgcn_sched_barrier(0);
    }

    const int cl = lane & 15, rg = lane >> 4;
#pragma unroll
    for (int m = 0; m < 4; ++m) {
#pragma unroll
        for (int j = 0; j < 4; ++j) {
            const int row = row0 + wr * 64 + m * 16 + rg * 4 + j;
            float msk = 1.f;
            if (EPI == 1 || EPI == 2) {
                msk = ((row & (LSEQ - 1)) < len0) ? 1.f : 0.f;
            }
#pragma unroll
            for (int n = 0; n < 4; ++n) {
                const int col = col0 + wc * 64 + n * 16 + cl;
                float v = acc[m][n][j];
                if (EPI == 0) {
                    if (col < DINNER) ((float*)Cv)[(size_t)row * DINNER + col] = v;
                    else ((unsigned short*)C2v)[(size_t)row * DINNER + col - DINNER] = f2bf(v);
                } else if (EPI == 1) {
                    v += bias[col];
                    v = (v > 20.f) ? v : log1pf(__expf(v));
                    ((float*)Cv)[(size_t)row * ldc + col] = v * msk;
                } else if (EPI == 2) {
                    ((float*)Cv)[(size_t)row * ldc + col] =
                        residual[(size_t)row * ldc + col] + msk * v;
                } else {  // EPI 3
                    if (col < 64) aux[(size_t)row * 64 + col] = f2bf(v);
                    else if (col < 96) ((float*)Cv)[(size_t)row * 96 + col] = v;
                }
            }
        }
    }
}

// ---------------- causal depthwise conv (K=4) + SiLU + mask -> bf16 ----------------
__global__ __launch_bounds__(256) void conv_silu_k(const float* __restrict__ ur,
                                                   const float* __restrict__ cw,
                                                   const int* __restrict__ lengths,
                                                   unsigned short* __restrict__ u) {
    const int g = blockIdx.x;              // NB * 512
    const int b = g >> 9;
    const int rem = g & 511;
    const int l0 = (rem >> 1) << 3;
    const int d4 = (rem & 1) * 1024 + threadIdx.x * 4;
    const int len = lengths[b];
    const size_t rb = (size_t)b * LSEQ;
    if (l0 >= len) {
        const int lenUp = (len + CH - 1) & ~(CH - 1);
        if (l0 < lenUp) {
            ushort4 z4 = {0, 0, 0, 0};
#pragma unroll
            for (int i = 0; i < 8; ++i)
                *(ushort4*)(u + (rb + l0 + i) * DINNER + d4) = z4;
        }
        return;
    }
    float4 wq[4];
#pragma unroll
    for (int c = 0; c < 4; ++c) wq[c] = *(const float4*)(cw + 4 * (d4 + c));
    const float4 zero4 = {0.f, 0.f, 0.f, 0.f};
    float4 xm3 = (l0 - 3 >= 0 && l0 - 3 < len) ? *(const float4*)(ur + (rb + l0 - 3) * DINNER + d4) : zero4;
    float4 xm2 = (l0 - 2 >= 0 && l0 - 2 < len) ? *(const float4*)(ur + (rb + l0 - 2) * DINNER + d4) : zero4;
    float4 xm1 = (l0 - 1 >= 0 && l0 - 1 < len) ? *(const float4*)(ur + (rb + l0 - 1) * DINNER + d4) : zero4;
#pragma unroll
    for (int i = 0; i < 8; ++i) {
        const int l = l0 + i;
        const bool act = l < len;
        float4 x0 = act ? *(const float4*)(ur + (rb + l) * DINNER + d4) : zero4;
        float a0 = wq[0].x * xm3.x + wq[0].y * xm2.x + wq[0].z * xm1.x + wq[0].w * x0.x;
        float a1 = wq[1].x * xm3.y + wq[1].y * xm2.y + wq[1].z * xm1.y + wq[1].w * x0.y;
        float a2 = wq[2].x * xm3.z + wq[2].y * xm2.z + wq[2].z * xm1.z + wq[2].w * x0.z;
        float a3 = wq[3].x * xm3.w + wq[3].y * xm2.w + wq[3].z * xm1.w + wq[3].w * x0.w;
        ushort4 ov;
        ov.x = f2bf(act ? siluf(a0) : 0.f);
        ov.y = f2bf(act ? siluf(a1) : 0.f);
        ov.z = f2bf(act ? siluf(a2) : 0.f);
        ov.w = f2bf(act ? siluf(a3) : 0.f);
        *(ushort4*)(u + (rb + l) * DINNER + d4) = ov;
        xm3 = xm2; xm2 = xm1; xm1 = x0;
    }
}

// ---------------- scan phase 1 (channel-per-lane): per-chunk local scan ----------------
// grid = SCH * (NB*16); block = 128 threads, each owns channel d = dblk*128 + t.
// h chain bit-identical to old p1 (same op sequence) -> h_last unchanged.
__global__ __launch_bounds__(SDB) void scan_p1(const float* __restrict__ dlt,
                                               const unsigned short* __restrict__ uy,
                                               const float* __restrict__ xdbl,
                                               const float* __restrict__ A_log,
                                               const int* __restrict__ lengths,
                                               float* __restrict__ hloc,
                                               float* __restrict__ sumd) {
    __shared__ float2 sDU[STT][SDB];   // {delta, delta*u}  16 KB
    __shared__ float  sB[STT][16];     // 1 KB
    const int t = threadIdx.x;
    const int s = blockIdx.x >> 6;
    const int bd2 = blockIdx.x & 63;
    const int b = bd2 >> 4;
    const int d0 = (bd2 & 15) * SDB;
    const int d = d0 + t;
    const size_t hidx0 = ((size_t)(b * 128 + (d >> 4)) * SCH + s) * 256 + (d & 15) * 16;
    if (s * CH >= lengths[b]) {          // fully masked chunk: exact identity
#pragma unroll
        for (int i = 0; i < 4; ++i)
            *(float4*)(hloc + hidx0 + i * 4) = float4{0.f, 0.f, 0.f, 0.f};
        sumd[((b * 128 + (d >> 4)) * SCH + s) * 16 + (d & 15)] = 0.f;
        return;
    }
    float Av2[16], h[16];
#pragma unroll
    for (int i = 0; i < 16; ++i) {
        Av2[i] = -__expf(A_log[d * NST + i]) * 1.44269504f;
        h[i] = 0.f;
    }
    float sd = 0.f;
    const size_t base = (size_t)b * LSEQ + (size_t)s * CH;

    for (int l0 = 0; l0 < CH; l0 += STT) {
#pragma unroll
        for (int i = 0; i < 4; ++i) {
            int lin = i * SDB + t;
            int r = lin >> 5, c = (lin & 31) << 2;
            size_t row = base + l0 + r;
            float4 dv = *(const float4*)(dlt + row * DINNER + d0 + c);
            ushort4 uv = *(const ushort4*)(uy + row * DINNER + d0 + c);
            sDU[r][c + 0] = float2{dv.x, dv.x * bf2f(uv.x)};
            sDU[r][c + 1] = float2{dv.y, dv.y * bf2f(uv.y)};
            sDU[r][c + 2] = float2{dv.z, dv.z * bf2f(uv.z)};
            sDU[r][c + 3] = float2{dv.w, dv.w * bf2f(uv.w)};
        }
        {
            int r = t >> 3, n2 = (t & 7) << 1;
            float2 bv = *(const float2*)(xdbl + (base + l0 + r) * 96 + 64 + n2);
            sB[r][n2] = bv.x; sB[r][n2 + 1] = bv.y;
        }
        __syncthreads();
#pragma unroll
        for (int r = 0; r < STT; ++r) {
            float2 du = sDU[r][t];
            float4 b0 = *(const float4*)&sB[r][0];
            float4 b1 = *(const float4*)&sB[r][4];
            float4 b2 = *(const float4*)&sB[r][8];
            float4 b3 = *(const float4*)&sB[r][12];
            sd += du.x;
            h[0]  = fmaf(__builtin_amdgcn_exp2f(du.x * Av2[0]),  h[0],  du.y * b0.x);
            h[1]  = fmaf(__builtin_amdgcn_exp2f(du.x * Av2[1]),  h[1],  du.y * b0.y);
            h[2]  = fmaf(__builtin_amdgcn_exp2f(du.x * Av2[2]),  h[2],  du.y * b0.z);
            h[3]  = fmaf(__builtin_amdgcn_exp2f(du.x * Av2[3]),  h[3],  du.y * b0.w);
            h[4]  = fmaf(__builtin_amdgcn_exp2f(du.x * Av2[4]),  h[4],  du.y * b1.x);
            h[5]  = fmaf(__builtin_amdgcn_exp2f(du.x * Av2[5]),  h[5],  du.y * b1.y);
            h[6]  = fmaf(__builtin_amdgcn_exp2f(du.x * Av2[6]),  h[6],  du.y * b1.z);
            h[7]  = fmaf(__builtin_amdgcn_exp2f(du.x * Av2[7]),  h[7],  du.y * b1.w);
            h[8]  = fmaf(__builtin_amdgcn_exp2f(du.x * Av2[8]),  h[8],  du.y * b2.x);
            h[9]  = fmaf(__builtin_amdgcn_exp2f(du.x * Av2[9]),  h[9],  du.y * b2.y);
            h[10] = fmaf(__builtin_amdgcn_exp2f(du.x * Av2[10]), h[10], du.y * b2.z);
            h[11] = fmaf(__builtin_amdgcn_exp2f(du.x * Av2[11]), h[11], du.y * b2.w);
            h[12] = fmaf(__builtin_amdgcn_exp2f(du.x * Av2[12]), h[12], du.y * b3.x);
            h[13] = fmaf(__builtin_amdgcn_exp2f(du.x * Av2[13]), h[13], du.y * b3.y);
            h[14] = fmaf(__builtin_amdgcn_exp2f(du.x * Av2[14]), h[14], du.y * b3.z);
            h[15] = fmaf(__builtin_amdgcn_exp2f(du.x * Av2[15]), h[15], du.y * b3.w);
        }
        __syncthreads();
    }
#pragma unroll
    for (int i = 0; i < 4; ++i)
        *(float4*)(hloc + hidx0 + i * 4) = *(const float4*)&h[i * 4];
    sumd[((b * 128 + (d >> 4)) * SCH + s) * 16 + (d & 15)] = sd;
}

// ---------------- scan phase 2: sequential chunk fix-up + h_last (unchanged layout) ----------------
__global__ __launch_bounds__(256) void scan_p2(const float* __restrict__ hloc,
                                               const float* __restrict__ sumd,
                                               const float* __restrict__ A_log,
                                               float* __restrict__ hin,
                                               float* __restrict__ out_h) {
    const int t = threadIdx.x;
    const int bd = blockIdx.x;
    const int b = bd >> 7;
    const int d = ((bd & 127) << 4) + (t >> 4);
    const int n = t & 15;
    const float Av2 = -__expf(A_log[d * NST + n]) * 1.44269504f;
    float h = 0.f;
#pragma unroll
    for (int s = 0; s < SCH; ++s) {
        const size_t idx = ((size_t)bd * SCH + s) * 256 + t;
        hin[idx] = h;
        float P = __builtin_amdgcn_exp2f(Av2 * sumd[(bd * SCH + s) * 16 + (t >> 4)]);
        h = fmaf(P, h, hloc[idx]);
    }
    out_h[((size_t)(b * DINNER + d)) * NST + n] = h;
}

// ---------------- scan phase 3 (channel-per-lane): replay + gated y ----------------
__global__ __launch_bounds__(SDB) void scan_p3(const float* __restrict__ dlt,
                                               const unsigned short* __restrict__ zb,
                                               unsigned short* uy,
                                               const float* __restrict__ xdbl,
                                               const float* __restrict__ A_log,
                                               const float* __restrict__ D_skip,
                                               const int* __restrict__ lengths,
                                               const float* __restrict__ hin) {
    __shared__ float2 sDU[STT][SDB];   // 16 KB
    __shared__ float  sBC[STT][32];    // B at [r][n], C at [r][16+n]: 2 KB
    __shared__ float  sY[STT][SDB];    // 8 KB
    __shared__ float  sDk[SDB];        // 0.5 KB
    const int t = threadIdx.x;
    const int s = blockIdx.x >> 6;
    const int bd2 = blockIdx.x & 63;
    const int b = bd2 >> 4;
    const int d0 = (bd2 & 15) * SDB;
    const int d = d0 + t;
    if (s * CH >= lengths[b]) return;    // fully masked chunk: y never consumed
    sDk[t] = D_skip[d];
    float Av2[16], h[16];
#pragma unroll
    for (int i = 0; i < 16; ++i)
        Av2[i] = -__expf(A_log[d * NST + i]) * 1.44269504f;
    const size_t hidx0 = ((size_t)(b * 128 + (d >> 4)) * SCH + s) * 256 + (d & 15) * 16;
#pragma unroll
    for (int i = 0; i < 4; ++i)
        *(float4*)&h[i * 4] = *(const float4*)(hin + hidx0 + i * 4);
    const size_t base = (size_t)b * LSEQ + (size_t)s * CH;

    for (int l0 = 0; l0 < CH; l0 += STT) {
#pragma unroll
        for (int i = 0; i < 4; ++i) {
            int lin = i * SDB + t;
            int r = lin >> 5, c = (lin & 31) << 2;
            size_t row = base + l0 + r;
            float4 dv = *(const float4*)(dlt + row * DINNER + d0 + c);
            ushort4 uv = *(const ushort4*)(uy + row * DINNER + d0 + c);
            sDU[r][c + 0] = float2{dv.x, dv.x * bf2f(uv.x)};
            sDU[r][c + 1] = float2{dv.y, dv.y * bf2f(uv.y)};
            sDU[r][c + 2] = float2{dv.z, dv.z * bf2f(uv.z)};
            sDU[r][c + 3] = float2{dv.w, dv.w * bf2f(uv.w)};
        }
        {
            int r = t >> 3, n2 = (t & 7) << 1;
            float2 bv = *(const float2*)(xdbl + (base + l0 + r) * 96 + 64 + n2);
            float2 cv = *(const float2*)(xdbl + (base + l0 + r) * 96 + 80 + n2);
            sBC[r][n2] = bv.x; sBC[r][n2 + 1] = bv.y;
            sBC[r][16 + n2] = cv.x; sBC[r][16 + n2 + 1] = cv.y;
        }
        __syncthreads();
#pragma unroll
        for (int r = 0; r < STT; ++r) {
            float2 du = sDU[r][t];
            float4 b0 = *(const float4*)&sBC[r][0];
            float4 b1 = *(const float4*)&sBC[r][4];
            float4 b2 = *(const float4*)&sBC[r][8];
            float4 b3 = *(const float4*)&sBC[r][12];
            float4 c0 = *(const float4*)&sBC[r][16];
            float4 c1 = *(const float4*)&sBC[r][20];
            float4 c2 = *(const float4*)&sBC[r][24];
            float4 c3 = *(const float4*)&sBC[r][28];
            float y = 0.f;
            h[0]  = fmaf(__builtin_amdgcn_exp2f(du.x * Av2[0]),  h[0],  du.y * b0.x); y = fmaf(h[0],  c0.x, y);
            h[1]  = fmaf(__builtin_amdgcn_exp2f(du.x * Av2[1]),  h[1],  du.y * b0.y); y = fmaf(h[1],  c0.y, y);
            h[2]  = fmaf(__builtin_amdgcn_exp2f(du.x * Av2[2]),  h[2],  du.y * b0.z); y = fmaf(h[2],  c0.z, y);
            h[3]  = fmaf(__builtin_amdgcn_exp2f(du.x * Av2[3]),  h[3],  du.y * b0.w); y = fmaf(h[3],  c0.w, y);
            h[4]  = fmaf(__builtin_amdgcn_exp2f(du.x * Av2[4]),  h[4],  du.y * b1.x); y = fmaf(h[4],  c1.x, y);
            h[5]  = fmaf(__builtin_amdgcn_exp2f(du.x * Av2[5]),  h[5],  du.y * b1.y); y = fmaf(h[5],  c1.y, y);
            h[6]  = fmaf(__builtin_amdgcn_exp2f(du.x * Av2[6]),  h[6],  du.y * b1.z); y = fmaf(h[6],  c1.z, y);
            h[7]  = fmaf(__builtin_amdgcn_exp2f(du.x * Av2[7]),  h[7],  du.y * b1.w); y = fmaf(h[7],  c1.w, y);
            h[8]  = fmaf(__builtin_amdgcn_exp2f(du.x * Av2[8]),  h[8],  du.y * b2.x); y = fmaf(h[8],  c2.x, y);
            h[9]  = fmaf(__builtin_amdgcn_exp2f(du.x * Av2[9]),  h[9],  du.y * b2.y); y = fmaf(h[9],  c2.y, y);
            h[10] = fmaf(__builtin_amdgcn_exp2f(du.x * Av2[10]), h[10], du.y * b2.z); y = fmaf(h[10], c2.z, y);
            h[11] = fmaf(__builtin_amdgcn_exp2f(du.x * Av2[11]), h[11], du.y * b2.w); y = fmaf(h[11], c2.w, y);
            h[12] = fmaf(__builtin_amdgcn_exp2f(du.x * Av2[12]), h[12], du.y * b3.x); y = fmaf(h[12], c3.x, y);
            h[13] = fmaf(__builtin_amdgcn_exp2f(du.x * Av2[13]), h[13], du.y * b3.y); y = fmaf(h[13], c3.y, y);
            h[14] = fmaf(__builtin_amdgcn_exp2f(du.x * Av2[14]), h[14], du.y * b3.z); y = fmaf(h[14], c3.z, y);
            h[15] = fmaf(__builtin_amdgcn_exp2f(du.x * Av2[15]), h[15], du.y * b3.w); y = fmaf(h[15], c3.w, y);
            sY[r][t] = y;
        }
        __syncthreads();
        // write phase: y_out = (y + u*D) * silu(z), coalesced ushort8 stores
#pragma unroll
        for (int i = 0; i < 2; ++i) {
            int lin = i * SDB + t;
            int r = lin >> 4, c8 = (lin & 15) << 3;
            size_t row = base + l0 + r;
            float4 y0 = *(const float4*)&sY[r][c8];
            float4 y1 = *(const float4*)&sY[r][c8 + 4];
            ushort8v uu = *(const ushort8v*)(uy + row * DINNER + d0 + c8);
            ushort8v zz = *(const ushort8v*)(zb + row * DINNER + d0 + c8);
            float4 k0 = *(const float4*)&sDk[c8];
            float4 k1 = *(const float4*)&sDk[c8 + 4];
            ushort8v ov;
            ov[0] = f2bf(fmaf(bf2f(uu[0]), k0.x, y0.x) * siluf(bf2f(zz[0])));
            ov[1] = f2bf(fmaf(bf2f(uu[1]), k0.y, y0.y) * siluf(bf2f(zz[1])));
            ov[2] = f2bf(fmaf(bf2f(uu[2]), k0.z, y0.z) * siluf(bf2f(zz[2])));
            ov[3] = f2bf(fmaf(bf2f(uu[3]), k0.w, y0.w) * siluf(bf2f(zz[3])));
            ov[4] = f2bf(fmaf(bf2f(uu[4]), k1.x, y1.x) * siluf(bf2f(zz[4])));
            ov[5] = f2bf(fmaf(bf2f(uu[5]), k1.y, y1.y) * siluf(bf2f(zz[5])));
            ov[6] = f2bf(fmaf(bf2f(uu[6]), k1.z, y1.z) * siluf(bf2f(zz[6])));
            ov[7] = f2bf(fmaf(bf2f(uu[7]), k1.w, y1.w) * siluf(bf2f(zz[7])));
            *(ushort8v*)(uy + row * DINNER + d0 + c8) = ov;
        }
    }
}

extern "C" void kernel_launch(void* const* d_in, const int* in_sizes, int n_in,
                              void* d_out, int out_size, void* d_ws, size_t ws_size,
                              hipStream_t stream) {
    const float* hs        = (const float*)d_in[0];
    const int*   lengths   = (const int*)d_in[1];
    const float* norm_w    = (const float*)d_in[2];
    const float* in_proj_w = (const float*)d_in[3];
    const float* conv_w    = (const float*)d_in[4];
    const float* x_proj_w  = (const float*)d_in[5];
    const float* dt_proj_w = (const float*)d_in[6];
    const float* dt_proj_b = (const float*)d_in[7];
    const float* A_log     = (const float*)d_in[8];
    const float* D_skip    = (const float*)d_in[9];
    const float* out_proj_w= (const float*)d_in[10];

    float* out = (float*)d_out;

    const int M = NB * LSEQ;                                            // 8192
    float* ur = (float*)d_ws;                                           // 8192x2048 f32: u_raw -> dlt
    unsigned short* zb = (unsigned short*)(ur + (size_t)M * DINNER);    // 8192x2048 bf16: z
    unsigned short* u_bf = zb + (size_t)M * DINNER;                     // 8192x2048 bf16: u -> y
    float* xdbl = (float*)(u_bf + (size_t)M * DINNER);                  // 8192x96 f32
    unsigned short* w_in  = (unsigned short*)(xdbl + (size_t)M * 96);   // 4096x1024
    unsigned short* w_out = w_in + (size_t)4096 * 1024;                 // 1024x2048
    unsigned short* w_x   = w_out + (size_t)1024 * 2048;                // 96x2048
    unsigned short* w_dt  = w_x + (size_t)96 * 2048;                    // 2048x64
    unsigned short* dtr   = w_dt + (size_t)2048 * 64;                   // 8192x64 bf16
    float* hin            = (float*)(dtr + (size_t)M * 64);             // 512*16*256 f32
    unsigned short* xn_bf = u_bf;          // alias: dead once conv overwrites it
    float* dlt  = ur;                      // alias: ur dead after conv
    float* hloc = (float*)w_in;            // alias: w_in dead after in_proj
    float* sumd = (float*)dtr;             // alias: dtr dead after dt_proj

    // 1. fused RMSNorm->bf16 + fused weight conversions
    rmsnorm_cvt_k<<<M, 256, 0, stream>>>(hs, norm_w, xn_bf);
    cvt_all_k<<<6464, 256, 0, stream>>>(in_proj_w, out_proj_w, x_proj_w, dt_proj_w,
                                        w_in, w_out, w_x, w_dt);

    // 2. in_proj (bf16 MFMA dbuf+swz, row-skip): ur f32 | z bf16
    gemm_bf16<0><<<(4096 / 128) * (M / 128), 256, 0, stream>>>(
        xn_bf, DMODEL, w_in, DMODEL, ur, zb, DINNER, M, 4096, DMODEL, 4096 / 128,
        nullptr, nullptr, nullptr, lengths);

    // 3. causal depthwise conv + silu + mask -> u (bf16)
    conv_silu_k<<<NB * 512, 256, 0, stream>>>(ur, conv_w, lengths, u_bf);

    // 4. x_proj (bf16 MFMA dbuf+swz, row-skip): B,C -> xdbl f32; dt_r -> dtr bf16
    gemm_bf16<3><<<1 * (M / 128), 256, 0, stream>>>(
        u_bf, DINNER, w_x, DINNER, xdbl, nullptr, 96, M, 96, DINNER, 1,
        nullptr, nullptr, dtr, lengths);

    // 5. dt_proj (bf16 MFMA dbuf+swz, row-skip) + softplus + mask -> delta f32
    gemm_bf16<1><<<(DINNER / 128) * (M / 128), 256, 0, stream>>>(
        dtr, 64, w_dt, 64, dlt, nullptr, DINNER, M, DINNER, 64, DINNER / 128,
        dt_proj_b, nullptr, nullptr, lengths);

    // 6. chunked selective scan (3 phases, chunk-skip, channel-per-lane p1/p3)
    {
        float* hlast = out + (size_t)M * DMODEL;
        scan_p1<<<SCH * 64, SDB, 0, stream>>>(dlt, u_bf, xdbl, A_log, lengths, hloc, sumd);
        scan_p2<<<NBD, 256, 0, stream>>>(hloc, sumd, A_log, hin, hlast);
        scan_p3<<<SCH * 64, SDB, 0, stream>>>(dlt, zb, u_bf, xdbl, A_log, D_skip, lengths, hin);
    }

    // 7. out_proj (bf16 MFMA dbuf+swz, row-skip -> residual copy) + residual + mask
    gemm_bf16<2><<<(DMODEL / 128) * (M / 128), 256, 0, stream>>>(
        u_bf, DINNER, w_out, DINNER, out, nullptr, DMODEL, M, DMODEL, DINNER, DMODEL / 128,
        nullptr, hs, nullptr, lengths);
}

// Round 14
// 329.239 us; speedup vs baseline: 1.0772x; 1.0772x over previous
//
#include <hip/hip_runtime.h>
#include <cstdint>
#include <cstddef>

#define LSEQ 2048
#define NB   4
#define DMODEL 1024
#define DINNER 2048
#define NST  16
#define CH   128   // scan chunk length == GEMM tile height
#define SCH  (LSEQ / CH)   // 16 chunks
#define NBD  512           // NB * DINNER/16 (p2 layout)
#define STT  16    // scan steps per LDS tile
#define SCB  64    // channels per scan block (4 lanes each)

typedef short bf16x8 __attribute__((ext_vector_type(8)));
typedef float f32x4  __attribute__((ext_vector_type(4)));

__device__ __forceinline__ float siluf(float x) { return x / (1.f + __expf(-x)); }

__device__ __forceinline__ unsigned short f2bf(float f) {
    unsigned u = __float_as_uint(f);
    u += 0x7FFF + ((u >> 16) & 1);     // round-to-nearest-even
    return (unsigned short)(u >> 16);
}
__device__ __forceinline__ float bf2f(unsigned short h) {
    return __uint_as_float(((unsigned)h) << 16);
}
__device__ __forceinline__ void gload_lds16(const void* g, void* l) {
    __builtin_amdgcn_global_load_lds(
        (const __attribute__((address_space(1))) unsigned int*)g,
        (__attribute__((address_space(3))) unsigned int*)l, 16, 0, 0);
}

// DPP quad_perm add helpers: rotate within 4-lane quad
template <int CTRL>
__device__ __forceinline__ float dpp_qp(float v) {
    return __int_as_float(__builtin_amdgcn_update_dpp(
        0, __float_as_int(v), CTRL, 0xf, 0xf, false));
}

// ---------------- fused RMSNorm + bf16 convert ----------------
__global__ __launch_bounds__(256) void rmsnorm_cvt_k(const float* __restrict__ x,
                                                     const float* __restrict__ nw,
                                                     unsigned short* __restrict__ o) {
    int row = blockIdx.x, t = threadIdx.x;
    float4 v = ((const float4*)(x + (size_t)row * DMODEL))[t];
    float s = v.x * v.x + v.y * v.y + v.z * v.z + v.w * v.w;
#pragma unroll
    for (int m = 32; m >= 1; m >>= 1) s += __shfl_xor(s, m);
    __shared__ float wsum[4];
    __shared__ float sinv;
    if ((t & 63) == 0) wsum[t >> 6] = s;
    __syncthreads();
    if (t == 0) {
        float tot = wsum[0] + wsum[1] + wsum[2] + wsum[3];
        sinv = rsqrtf(tot * (1.f / (float)DMODEL) + 1e-6f);
    }
    __syncthreads();
    float iv = sinv;
    float4 w = ((const float4*)nw)[t];
    ushort4 ov;
    ov.x = f2bf(v.x * iv * w.x); ov.y = f2bf(v.y * iv * w.y);
    ov.z = f2bf(v.z * iv * w.z); ov.w = f2bf(v.w * iv * w.w);
    ((ushort4*)(o + (size_t)row * DMODEL))[t] = ov;
}

// ---------------- fused weight conversions (4 matrices, 1 launch) ----------------
__global__ __launch_bounds__(256) void cvt_all_k(const float* __restrict__ s0, const float* __restrict__ s1,
                                                 const float* __restrict__ s2, const float* __restrict__ s3,
                                                 unsigned short* __restrict__ q0, unsigned short* __restrict__ q1,
                                                 unsigned short* __restrict__ q2, unsigned short* __restrict__ q3) {
    int i = blockIdx.x * 256 + threadIdx.x;
    const float* s; unsigned short* d; int off;
    if (i < 1048576)       { s = s0; d = q0; off = i; }
    else if (i < 1572864)  { s = s1; d = q1; off = i - 1048576; }
    else if (i < 1622016)  { s = s2; d = q2; off = i - 1572864; }
    else if (i < 1654784)  { s = s3; d = q3; off = i - 1622016; }
    else return;
    float4 v = ((const float4*)s)[off];
    ushort4 o;
    o.x = f2bf(v.x); o.y = f2bf(v.y); o.z = f2bf(v.z); o.w = f2bf(v.w);
    ((ushort4*)d)[off] = o;
}

// ---------------- bf16 MFMA NT GEMM: dbuf LDS + counted vmcnt + XOR swizzle (round-10) ----------------
template <int EPI>
__global__ __launch_bounds__(256) void gemm_bf16(
    const unsigned short* __restrict__ A, int lda,
    const unsigned short* __restrict__ W, int ldw,
    void* __restrict__ Cv, void* __restrict__ C2v, int ldc,
    int M, int N, int K, int nbx,
    const float* __restrict__ bias,
    const float* __restrict__ residual,
    unsigned short* __restrict__ aux,
    const int* __restrict__ lengths) {
    __shared__ __align__(16) unsigned short As[2][128 * 64];
    __shared__ __align__(16) unsigned short Bs[2][128 * 64];
    const int bid = blockIdx.x;
    const int bx = bid % nbx, by = bid / nbx;
    const int row0 = by * 128, col0 = bx * 128;
    const int t = threadIdx.x;

    const int len0 = lengths[row0 >> 11];
    if ((row0 & (LSEQ - 1)) >= len0) {
        if (EPI == 2) {
            float* C = (float*)Cv;
#pragma unroll
            for (int i = 0; i < 16; ++i) {
                int lin = i * 256 + t;
                int r = lin >> 5, c = (lin & 31) << 2;
                *(float4*)(C + (size_t)(row0 + r) * ldc + col0 + c) =
                    *(const float4*)(residual + (size_t)(row0 + r) * ldc + col0 + c);
            }
        }
        return;
    }

    const int lane = t & 63;
    const int w = t >> 6;
    const int wr = w >> 1, wc = w & 1;

    f32x4 acc[4][4];
#pragma unroll
    for (int m = 0; m < 4; ++m)
#pragma unroll
        for (int n = 0; n < 4; ++n) acc[m][n] = f32x4{0.f, 0.f, 0.f, 0.f};

    const int rA = lane & 15;
    const int kH = (lane >> 4) << 3;
    const int NT = K >> 6;
    const int swzR = (rA & 7) << 3;

    auto STAGE = [&](int sel, int k0) {
#pragma unroll
        for (int it = 0; it < 4; ++it) {
            int c = it * 256 + t;
            int r = c >> 3;
            int cc = ((c & 7) ^ (r & 7)) << 3;
            gload_lds16(A + (size_t)(row0 + r) * lda + k0 + cc, &As[sel][c << 3]);
            int wrow = col0 + r; if (wrow >= N) wrow = N - 1;
            gload_lds16(W + (size_t)wrow * ldw + k0 + cc, &Bs[sel][c << 3]);
        }
    };

    STAGE(0, 0);
    for (int kt = 0; kt < NT; ++kt) {
        const int cur = kt & 1;
        if (kt + 1 < NT) STAGE(cur ^ 1, (kt + 1) << 6);
        __builtin_amdgcn_sched_barrier(0);
        if (kt + 1 < NT) { asm volatile("s_waitcnt vmcnt(8)" ::: "memory"); }
        else             { asm volatile("s_waitcnt vmcnt(0)" ::: "memory"); }
        __builtin_amdgcn_sched_barrier(0);
        __builtin_amdgcn_s_barrier();
        __builtin_amdgcn_sched_barrier(0);
#pragma unroll
        for (int ks = 0; ks < 2; ++ks) {
            const int kkS = (ks * 32 + kH) ^ swzR;
            bf16x8 af[4], bfr[4];
#pragma unroll
            for (int m = 0; m < 4; ++m)
                af[m] = *(const bf16x8*)&As[cur][(wr * 64 + m * 16 + rA) * 64 + kkS];
#pragma unroll
            for (int n = 0; n < 4; ++n)
                bfr[n] = *(const bf16x8*)&Bs[cur][(wc * 64 + n * 16 + rA) * 64 + kkS];
#pragma unroll
            for (int m = 0; m < 4; ++m)
#pragma unroll
                for (int n = 0; n < 4; ++n)
                    acc[m][n] = __builtin_amdgcn_mfma_f32_16x16x32_bf16(
                        af[m], bfr[n], acc[m][n], 0, 0, 0);
        }
        __builtin_amdgcn_sched_barrier(0);
        asm volatile("s_waitcnt lgkmcnt(0)" ::: "memory");
        __builtin_amdgcn_s_barrier();
        __builtin_amdgcn_sched_barrier(0);
    }

    const int cl = lane & 15, rg = lane >> 4;
#pragma unroll
    for (int m = 0; m < 4; ++m) {
#pragma unroll
        for (int j = 0; j < 4; ++j) {
            const int row = row0 + wr * 64 + m * 16 + rg * 4 + j;
            float msk = 1.f;
            if (EPI == 1 || EPI == 2) {
                msk = ((row & (LSEQ - 1)) < len0) ? 1.f : 0.f;
            }
#pragma unroll
            for (int n = 0; n < 4; ++n) {
                const int col = col0 + wc * 64 + n * 16 + cl;
                float v = acc[m][n][j];
                if (EPI == 0) {
                    if (col < DINNER) ((float*)Cv)[(size_t)row * DINNER + col] = v;
                    else ((unsigned short*)C2v)[(size_t)row * DINNER + col - DINNER] = f2bf(v);
                } else if (EPI == 1) {
                    v += bias[col];
                    v = (v > 20.f) ? v : log1pf(__expf(v));
                    ((float*)Cv)[(size_t)row * ldc + col] = v * msk;
                } else if (EPI == 2) {
                    ((float*)Cv)[(size_t)row * ldc + col] =
                        residual[(size_t)row * ldc + col] + msk * v;
                } else {  // EPI 3
                    if (col < 64) aux[(size_t)row * 64 + col] = f2bf(v);
                    else if (col < 96) ((float*)Cv)[(size_t)row * 96 + col] = v;
                }
            }
        }
    }
}

// ---------------- causal depthwise conv (K=4) + SiLU + mask -> bf16 ----------------
__global__ __launch_bounds__(256) void conv_silu_k(const float* __restrict__ ur,
                                                   const float* __restrict__ cw,
                                                   const int* __restrict__ lengths,
                                                   unsigned short* __restrict__ u) {
    const int g = blockIdx.x;              // NB * 512
    const int b = g >> 9;
    const int rem = g & 511;
    const int l0 = (rem >> 1) << 3;
    const int d4 = (rem & 1) * 1024 + threadIdx.x * 4;
    const int len = lengths[b];
    const size_t rb = (size_t)b * LSEQ;
    if (l0 >= len) {
        const int lenUp = (len + CH - 1) & ~(CH - 1);
        if (l0 < lenUp) {
            ushort4 z4 = {0, 0, 0, 0};
#pragma unroll
            for (int i = 0; i < 8; ++i)
                *(ushort4*)(u + (rb + l0 + i) * DINNER + d4) = z4;
        }
        return;
    }
    float4 wq[4];
#pragma unroll
    for (int c = 0; c < 4; ++c) wq[c] = *(const float4*)(cw + 4 * (d4 + c));
    const float4 zero4 = {0.f, 0.f, 0.f, 0.f};
    float4 xm3 = (l0 - 3 >= 0 && l0 - 3 < len) ? *(const float4*)(ur + (rb + l0 - 3) * DINNER + d4) : zero4;
    float4 xm2 = (l0 - 2 >= 0 && l0 - 2 < len) ? *(const float4*)(ur + (rb + l0 - 2) * DINNER + d4) : zero4;
    float4 xm1 = (l0 - 1 >= 0 && l0 - 1 < len) ? *(const float4*)(ur + (rb + l0 - 1) * DINNER + d4) : zero4;
#pragma unroll
    for (int i = 0; i < 8; ++i) {
        const int l = l0 + i;
        const bool act = l < len;
        float4 x0 = act ? *(const float4*)(ur + (rb + l) * DINNER + d4) : zero4;
        float a0 = wq[0].x * xm3.x + wq[0].y * xm2.x + wq[0].z * xm1.x + wq[0].w * x0.x;
        float a1 = wq[1].x * xm3.y + wq[1].y * xm2.y + wq[1].z * xm1.y + wq[1].w * x0.y;
        float a2 = wq[2].x * xm3.z + wq[2].y * xm2.z + wq[2].z * xm1.z + wq[2].w * x0.z;
        float a3 = wq[3].x * xm3.w + wq[3].y * xm2.w + wq[3].z * xm1.w + wq[3].w * x0.w;
        ushort4 ov;
        ov.x = f2bf(act ? siluf(a0) : 0.f);
        ov.y = f2bf(act ? siluf(a1) : 0.f);
        ov.z = f2bf(act ? siluf(a2) : 0.f);
        ov.w = f2bf(act ? siluf(a3) : 0.f);
        *(ushort4*)(u + (rb + l) * DINNER + d4) = ov;
        xm3 = xm2; xm2 = xm1; xm1 = x0;
    }
}

// ---------------- scan phase 1 (4 states/lane): per-chunk local scan ----------------
// grid = SCH*128; block 256 = 64 channels x 4 lanes (lane q owns states 4q..4q+3).
// h op-sequence bit-identical to round-10 p1 -> h_last unchanged.
__global__ __launch_bounds__(256) void scan_p1(const float* __restrict__ dlt,
                                               const unsigned short* __restrict__ uy,
                                               const float* __restrict__ xdbl,
                                               const float* __restrict__ A_log,
                                               const int* __restrict__ lengths,
                                               float* __restrict__ hloc,
                                               float* __restrict__ sumd) {
    __shared__ float2 sDU[STT][SCB];   // 8 KB
    __shared__ float  sB[STT][16];     // 1 KB
    const int t = threadIdx.x;
    const int s = blockIdx.x >> 7;
    const int g = blockIdx.x & 127;
    const int b = g >> 5;
    const int d0 = (g & 31) * SCB;
    const int ch = t >> 2, q = t & 3;
    const int d = d0 + ch;
    const size_t hbase = ((size_t)(b * 128 + (d >> 4)) * SCH + s) * 256 + (size_t)(d & 15) * 16 + q * 4;
    if (s * CH >= lengths[b]) {          // fully masked chunk: exact identity
        *(float4*)(hloc + hbase) = float4{0.f, 0.f, 0.f, 0.f};
        if (q == 0) sumd[((b * 128 + (d >> 4)) * SCH + s) * 16 + (d & 15)] = 0.f;
        return;
    }
    const float Av0 = -__expf(A_log[d * NST + q * 4 + 0]) * 1.44269504f;
    const float Av1 = -__expf(A_log[d * NST + q * 4 + 1]) * 1.44269504f;
    const float Av2_ = -__expf(A_log[d * NST + q * 4 + 2]) * 1.44269504f;
    const float Av3 = -__expf(A_log[d * NST + q * 4 + 3]) * 1.44269504f;
    float h0 = 0.f, h1 = 0.f, h2 = 0.f, h3 = 0.f, sd = 0.f;
    const size_t base = (size_t)b * LSEQ + (size_t)s * CH;

    for (int l0 = 0; l0 < CH; l0 += STT) {
        {
            const int r = t >> 4, c4 = (t & 15) << 2;
            const size_t row = base + l0 + r;
            float4 dv = *(const float4*)(dlt + row * DINNER + d0 + c4);
            ushort4 uv = *(const ushort4*)(uy + row * DINNER + d0 + c4);
            sDU[r][c4 + 0] = float2{dv.x, dv.x * bf2f(uv.x)};
            sDU[r][c4 + 1] = float2{dv.y, dv.y * bf2f(uv.y)};
            sDU[r][c4 + 2] = float2{dv.z, dv.z * bf2f(uv.z)};
            sDU[r][c4 + 3] = float2{dv.w, dv.w * bf2f(uv.w)};
            sB[r][t & 15] = xdbl[row * 96 + 64 + (t & 15)];
        }
        __syncthreads();
#pragma unroll
        for (int r = 0; r < STT; ++r) {
            float2 du = sDU[r][ch];
            float4 bb = *(const float4*)&sB[r][q * 4];
            sd += du.x;
            h0 = fmaf(__builtin_amdgcn_exp2f(du.x * Av0),  h0, du.y * bb.x);
            h1 = fmaf(__builtin_amdgcn_exp2f(du.x * Av1),  h1, du.y * bb.y);
            h2 = fmaf(__builtin_amdgcn_exp2f(du.x * Av2_), h2, du.y * bb.z);
            h3 = fmaf(__builtin_amdgcn_exp2f(du.x * Av3),  h3, du.y * bb.w);
        }
        __syncthreads();
    }
    *(float4*)(hloc + hbase) = float4{h0, h1, h2, h3};
    if (q == 0) sumd[((b * 128 + (d >> 4)) * SCH + s) * 16 + (d & 15)] = sd;
}

// ---------------- scan phase 2: sequential chunk fix-up + h_last (unchanged) ----------------
__global__ __launch_bounds__(256) void scan_p2(const float* __restrict__ hloc,
                                               const float* __restrict__ sumd,
                                               const float* __restrict__ A_log,
                                               float* __restrict__ hin,
                                               float* __restrict__ out_h) {
    const int t = threadIdx.x;
    const int bd = blockIdx.x;
    const int b = bd >> 7;
    const int d = ((bd & 127) << 4) + (t >> 4);
    const int n = t & 15;
    const float Av2 = -__expf(A_log[d * NST + n]) * 1.44269504f;
    float h = 0.f;
#pragma unroll
    for (int s = 0; s < SCH; ++s) {
        const size_t idx = ((size_t)bd * SCH + s) * 256 + t;
        hin[idx] = h;
        float P = __builtin_amdgcn_exp2f(Av2 * sumd[(bd * SCH + s) * 16 + (t >> 4)]);
        h = fmaf(P, h, hloc[idx]);
    }
    out_h[((size_t)(b * DINNER + d)) * NST + n] = h;
}

// ---------------- scan phase 3 (4 states/lane): replay + gated y ----------------
__global__ __launch_bounds__(256) void scan_p3(const float* __restrict__ dlt,
                                               const unsigned short* __restrict__ zb,
                                               unsigned short* uy,
                                               const float* __restrict__ xdbl,
                                               const float* __restrict__ A_log,
                                               const float* __restrict__ D_skip,
                                               const int* __restrict__ lengths,
                                               const float* __restrict__ hin) {
    __shared__ float2 sDU[STT][SCB];   // 8 KB
    __shared__ float  sBC[STT][32];    // 2 KB (xdbl cols 64..95: B then C)
    __shared__ float  sY[STT][SCB];    // 4 KB
    __shared__ float  sDk[SCB];
    const int t = threadIdx.x;
    const int s = blockIdx.x >> 7;
    const int g = blockIdx.x & 127;
    const int b = g >> 5;
    const int d0 = (g & 31) * SCB;
    const int ch = t >> 2, q = t & 3;
    const int d = d0 + ch;
    if (s * CH >= lengths[b]) return;    // fully masked chunk: y never consumed
    if (t < SCB) sDk[t] = D_skip[d0 + t];
    const float Av0 = -__expf(A_log[d * NST + q * 4 + 0]) * 1.44269504f;
    const float Av1 = -__expf(A_log[d * NST + q * 4 + 1]) * 1.44269504f;
    const float Av2_ = -__expf(A_log[d * NST + q * 4 + 2]) * 1.44269504f;
    const float Av3 = -__expf(A_log[d * NST + q * 4 + 3]) * 1.44269504f;
    const size_t hbase = ((size_t)(b * 128 + (d >> 4)) * SCH + s) * 256 + (size_t)(d & 15) * 16 + q * 4;
    float4 hv = *(const float4*)(hin + hbase);
    float h0 = hv.x, h1 = hv.y, h2 = hv.z, h3 = hv.w;
    const size_t base = (size_t)b * LSEQ + (size_t)s * CH;

    for (int l0 = 0; l0 < CH; l0 += STT) {
        {
            const int r = t >> 4, c4 = (t & 15) << 2;
            const size_t row = base + l0 + r;
            float4 dv = *(const float4*)(dlt + row * DINNER + d0 + c4);
            ushort4 uv = *(const ushort4*)(uy + row * DINNER + d0 + c4);
            sDU[r][c4 + 0] = float2{dv.x, dv.x * bf2f(uv.x)};
            sDU[r][c4 + 1] = float2{dv.y, dv.y * bf2f(uv.y)};
            sDU[r][c4 + 2] = float2{dv.z, dv.z * bf2f(uv.z)};
            sDU[r][c4 + 3] = float2{dv.w, dv.w * bf2f(uv.w)};
            float2 bc = *(const float2*)(xdbl + row * 96 + 64 + ((t & 15) << 1));
            sBC[r][((t & 15) << 1) + 0] = bc.x;
            sBC[r][((t & 15) << 1) + 1] = bc.y;
        }
        __syncthreads();
#pragma unroll
        for (int r = 0; r < STT; ++r) {
            float2 du = sDU[r][ch];
            float4 bb = *(const float4*)&sBC[r][q * 4];
            float4 cc = *(const float4*)&sBC[r][16 + q * 4];
            float y;
            h0 = fmaf(__builtin_amdgcn_exp2f(du.x * Av0),  h0, du.y * bb.x); y = h0 * cc.x;
            h1 = fmaf(__builtin_amdgcn_exp2f(du.x * Av1),  h1, du.y * bb.y); y = fmaf(h1, cc.y, y);
            h2 = fmaf(__builtin_amdgcn_exp2f(du.x * Av2_), h2, du.y * bb.z); y = fmaf(h2, cc.z, y);
            h3 = fmaf(__builtin_amdgcn_exp2f(du.x * Av3),  h3, du.y * bb.w); y = fmaf(h3, cc.w, y);
            y += dpp_qp<0x39>(y);   // + rotate1 within quad
            y += dpp_qp<0x4E>(y);   // + rotate2 -> full 16-state sum in all 4 lanes
            if (q == 0) sY[r][ch] = y;
        }
        __syncthreads();
        // write phase: y_out = (y + u*D) * silu(z), coalesced ushort4 stores
        {
            const int r = t >> 4, c4 = (t & 15) << 2;
            const size_t row = base + l0 + r;
            float4 yv = *(const float4*)&sY[r][c4];
            ushort4 uu = *(const ushort4*)(uy + row * DINNER + d0 + c4);
            ushort4 zz = *(const ushort4*)(zb + row * DINNER + d0 + c4);
            float4 kk = *(const float4*)&sDk[c4];
            ushort4 ov;
            ov.x = f2bf(fmaf(bf2f(uu.x), kk.x, yv.x) * siluf(bf2f(zz.x)));
            ov.y = f2bf(fmaf(bf2f(uu.y), kk.y, yv.y) * siluf(bf2f(zz.y)));
            ov.z = f2bf(fmaf(bf2f(uu.z), kk.z, yv.z) * siluf(bf2f(zz.z)));
            ov.w = f2bf(fmaf(bf2f(uu.w), kk.w, yv.w) * siluf(bf2f(zz.w)));
            *(ushort4*)(uy + row * DINNER + d0 + c4) = ov;
        }
        __syncthreads();
    }
}

extern "C" void kernel_launch(void* const* d_in, const int* in_sizes, int n_in,
                              void* d_out, int out_size, void* d_ws, size_t ws_size,
                              hipStream_t stream) {
    const float* hs        = (const float*)d_in[0];
    const int*   lengths   = (const int*)d_in[1];
    const float* norm_w    = (const float*)d_in[2];
    const float* in_proj_w = (const float*)d_in[3];
    const float* conv_w    = (const float*)d_in[4];
    const float* x_proj_w  = (const float*)d_in[5];
    const float* dt_proj_w = (const float*)d_in[6];
    const float* dt_proj_b = (const float*)d_in[7];
    const float* A_log     = (const float*)d_in[8];
    const float* D_skip    = (const float*)d_in[9];
    const float* out_proj_w= (const float*)d_in[10];

    float* out = (float*)d_out;

    const int M = NB * LSEQ;                                            // 8192
    float* ur = (float*)d_ws;                                           // 8192x2048 f32: u_raw -> dlt
    unsigned short* zb = (unsigned short*)(ur + (size_t)M * DINNER);    // 8192x2048 bf16: z
    unsigned short* u_bf = zb + (size_t)M * DINNER;                     // 8192x2048 bf16: u -> y
    float* xdbl = (float*)(u_bf + (size_t)M * DINNER);                  // 8192x96 f32
    unsigned short* w_in  = (unsigned short*)(xdbl + (size_t)M * 96);   // 4096x1024
    unsigned short* w_out = w_in + (size_t)4096 * 1024;                 // 1024x2048
    unsigned short* w_x   = w_out + (size_t)1024 * 2048;                // 96x2048
    unsigned short* w_dt  = w_x + (size_t)96 * 2048;                    // 2048x64
    unsigned short* dtr   = w_dt + (size_t)2048 * 64;                   // 8192x64 bf16
    float* hin            = (float*)(dtr + (size_t)M * 64);             // 512*16*256 f32
    unsigned short* xn_bf = u_bf;          // alias: dead once conv overwrites it
    float* dlt  = ur;                      // alias: ur dead after conv
    float* hloc = (float*)w_in;            // alias: w_in dead after in_proj
    float* sumd = (float*)dtr;             // alias: dtr dead after dt_proj

    // 1. fused RMSNorm->bf16 + fused weight conversions
    rmsnorm_cvt_k<<<M, 256, 0, stream>>>(hs, norm_w, xn_bf);
    cvt_all_k<<<6464, 256, 0, stream>>>(in_proj_w, out_proj_w, x_proj_w, dt_proj_w,
                                        w_in, w_out, w_x, w_dt);

    // 2. in_proj (bf16 MFMA dbuf+swz, row-skip): ur f32 | z bf16
    gemm_bf16<0><<<(4096 / 128) * (M / 128), 256, 0, stream>>>(
        xn_bf, DMODEL, w_in, DMODEL, ur, zb, DINNER, M, 4096, DMODEL, 4096 / 128,
        nullptr, nullptr, nullptr, lengths);

    // 3. causal depthwise conv + silu + mask -> u (bf16)
    conv_silu_k<<<NB * 512, 256, 0, stream>>>(ur, conv_w, lengths, u_bf);

    // 4. x_proj (bf16 MFMA dbuf+swz, row-skip): B,C -> xdbl f32; dt_r -> dtr bf16
    gemm_bf16<3><<<1 * (M / 128), 256, 0, stream>>>(
        u_bf, DINNER, w_x, DINNER, xdbl, nullptr, 96, M, 96, DINNER, 1,
        nullptr, nullptr, dtr, lengths);

    // 5. dt_proj (bf16 MFMA dbuf+swz, row-skip) + softplus + mask -> delta f32
    gemm_bf16<1><<<(DINNER / 128) * (M / 128), 256, 0, stream>>>(
        dtr, 64, w_dt, 64, dlt, nullptr, DINNER, M, DINNER, 64, DINNER / 128,
        dt_proj_b, nullptr, nullptr, lengths);

    // 6. chunked selective scan (3 phases, chunk-skip, 4-state-per-lane p1/p3)
    {
        float* hlast = out + (size_t)M * DMODEL;
        scan_p1<<<SCH * 128, 256, 0, stream>>>(dlt, u_bf, xdbl, A_log, lengths, hloc, sumd);
        scan_p2<<<NBD, 256, 0, stream>>>(hloc, sumd, A_log, hin, hlast);
        scan_p3<<<SCH * 128, 256, 0, stream>>>(dlt, zb, u_bf, xdbl, A_log, D_skip, lengths, hin);
    }

    // 7. out_proj (bf16 MFMA dbuf+swz, row-skip -> residual copy) + residual + mask
    gemm_bf16<2><<<(DMODEL / 128) * (M / 128), 256, 0, stream>>>(
        u_bf, DINNER, w_out, DINNER, out, nullptr, DMODEL, M, DMODEL, DINNER, DMODEL / 128,
        nullptr, hs, nullptr, lengths);
}

// Round 15
// 308.569 us; speedup vs baseline: 1.1493x; 1.0670x over previous
//
#include <hip/hip_runtime.h>
#include <cstdint>
#include <cstddef>

#define LSEQ 2048
#define NB   4
#define DMODEL 1024
#define DINNER 2048
#define NST  16
#define CH   128   // scan chunk length == GEMM tile height
#define SCH  (LSEQ / CH)   // 16 chunks
#define NBD  512           // NB * DINNER/16 (p2 layout)
#define STT  16    // scan steps per LDS tile
#define SCB  64    // channels per scan block (4 lanes each)

typedef short bf16x8 __attribute__((ext_vector_type(8)));
typedef float f32x4  __attribute__((ext_vector_type(4)));

__device__ __forceinline__ float siluf(float x) { return x / (1.f + __expf(-x)); }

__device__ __forceinline__ unsigned short f2bf(float f) {
    unsigned u = __float_as_uint(f);
    u += 0x7FFF + ((u >> 16) & 1);     // round-to-nearest-even
    return (unsigned short)(u >> 16);
}
__device__ __forceinline__ float bf2f(unsigned short h) {
    return __uint_as_float(((unsigned)h) << 16);
}
__device__ __forceinline__ void gload_lds16(const void* g, void* l) {
    __builtin_amdgcn_global_load_lds(
        (const __attribute__((address_space(1))) unsigned int*)g,
        (__attribute__((address_space(3))) unsigned int*)l, 16, 0, 0);
}

// DPP quad_perm add helpers: rotate within 4-lane quad
template <int CTRL>
__device__ __forceinline__ float dpp_qp(float v) {
    return __int_as_float(__builtin_amdgcn_update_dpp(
        0, __float_as_int(v), CTRL, 0xf, 0xf, false));
}

// ---------------- fused RMSNorm + bf16 convert ----------------
__global__ __launch_bounds__(256) void rmsnorm_cvt_k(const float* __restrict__ x,
                                                     const float* __restrict__ nw,
                                                     unsigned short* __restrict__ o) {
    int row = blockIdx.x, t = threadIdx.x;
    float4 v = ((const float4*)(x + (size_t)row * DMODEL))[t];
    float s = v.x * v.x + v.y * v.y + v.z * v.z + v.w * v.w;
#pragma unroll
    for (int m = 32; m >= 1; m >>= 1) s += __shfl_xor(s, m);
    __shared__ float wsum[4];
    __shared__ float sinv;
    if ((t & 63) == 0) wsum[t >> 6] = s;
    __syncthreads();
    if (t == 0) {
        float tot = wsum[0] + wsum[1] + wsum[2] + wsum[3];
        sinv = rsqrtf(tot * (1.f / (float)DMODEL) + 1e-6f);
    }
    __syncthreads();
    float iv = sinv;
    float4 w = ((const float4*)nw)[t];
    ushort4 ov;
    ov.x = f2bf(v.x * iv * w.x); ov.y = f2bf(v.y * iv * w.y);
    ov.z = f2bf(v.z * iv * w.z); ov.w = f2bf(v.w * iv * w.w);
    ((ushort4*)(o + (size_t)row * DMODEL))[t] = ov;
}

// ---------------- fused weight conversions (4 matrices, 1 launch) ----------------
__global__ __launch_bounds__(256) void cvt_all_k(const float* __restrict__ s0, const float* __restrict__ s1,
                                                 const float* __restrict__ s2, const float* __restrict__ s3,
                                                 unsigned short* __restrict__ q0, unsigned short* __restrict__ q1,
                                                 unsigned short* __restrict__ q2, unsigned short* __restrict__ q3) {
    int i = blockIdx.x * 256 + threadIdx.x;
    const float* s; unsigned short* d; int off;
    if (i < 1048576)       { s = s0; d = q0; off = i; }
    else if (i < 1572864)  { s = s1; d = q1; off = i - 1048576; }
    else if (i < 1622016)  { s = s2; d = q2; off = i - 1572864; }
    else if (i < 1654784)  { s = s3; d = q3; off = i - 1622016; }
    else return;
    float4 v = ((const float4*)s)[off];
    ushort4 o;
    o.x = f2bf(v.x); o.y = f2bf(v.y); o.z = f2bf(v.z); o.w = f2bf(v.w);
    ((ushort4*)d)[off] = o;
}

// ---------------- bf16 MFMA NT GEMM: dbuf LDS + counted vmcnt + XOR swizzle (round-10) ----------------
template <int EPI>
__global__ __launch_bounds__(256) void gemm_bf16(
    const unsigned short* __restrict__ A, int lda,
    const unsigned short* __restrict__ W, int ldw,
    void* __restrict__ Cv, void* __restrict__ C2v, int ldc,
    int M, int N, int K, int nbx,
    const float* __restrict__ bias,
    const float* __restrict__ residual,
    unsigned short* __restrict__ aux,
    const int* __restrict__ lengths) {
    __shared__ __align__(16) unsigned short As[2][128 * 64];
    __shared__ __align__(16) unsigned short Bs[2][128 * 64];
    const int bid = blockIdx.x;
    const int bx = bid % nbx, by = bid / nbx;
    const int row0 = by * 128, col0 = bx * 128;
    const int t = threadIdx.x;

    const int len0 = lengths[row0 >> 11];
    if ((row0 & (LSEQ - 1)) >= len0) {
        if (EPI == 2) {
            float* C = (float*)Cv;
#pragma unroll
            for (int i = 0; i < 16; ++i) {
                int lin = i * 256 + t;
                int r = lin >> 5, c = (lin & 31) << 2;
                *(float4*)(C + (size_t)(row0 + r) * ldc + col0 + c) =
                    *(const float4*)(residual + (size_t)(row0 + r) * ldc + col0 + c);
            }
        }
        return;
    }

    const int lane = t & 63;
    const int w = t >> 6;
    const int wr = w >> 1, wc = w & 1;

    f32x4 acc[4][4];
#pragma unroll
    for (int m = 0; m < 4; ++m)
#pragma unroll
        for (int n = 0; n < 4; ++n) acc[m][n] = f32x4{0.f, 0.f, 0.f, 0.f};

    const int rA = lane & 15;
    const int kH = (lane >> 4) << 3;
    const int NT = K >> 6;
    const int swzR = (rA & 7) << 3;

    auto STAGE = [&](int sel, int k0) {
#pragma unroll
        for (int it = 0; it < 4; ++it) {
            int c = it * 256 + t;
            int r = c >> 3;
            int cc = ((c & 7) ^ (r & 7)) << 3;
            gload_lds16(A + (size_t)(row0 + r) * lda + k0 + cc, &As[sel][c << 3]);
            int wrow = col0 + r; if (wrow >= N) wrow = N - 1;
            gload_lds16(W + (size_t)wrow * ldw + k0 + cc, &Bs[sel][c << 3]);
        }
    };

    STAGE(0, 0);
    for (int kt = 0; kt < NT; ++kt) {
        const int cur = kt & 1;
        if (kt + 1 < NT) STAGE(cur ^ 1, (kt + 1) << 6);
        __builtin_amdgcn_sched_barrier(0);
        if (kt + 1 < NT) { asm volatile("s_waitcnt vmcnt(8)" ::: "memory"); }
        else             { asm volatile("s_waitcnt vmcnt(0)" ::: "memory"); }
        __builtin_amdgcn_sched_barrier(0);
        __builtin_amdgcn_s_barrier();
        __builtin_amdgcn_sched_barrier(0);
#pragma unroll
        for (int ks = 0; ks < 2; ++ks) {
            const int kkS = (ks * 32 + kH) ^ swzR;
            bf16x8 af[4], bfr[4];
#pragma unroll
            for (int m = 0; m < 4; ++m)
                af[m] = *(const bf16x8*)&As[cur][(wr * 64 + m * 16 + rA) * 64 + kkS];
#pragma unroll
            for (int n = 0; n < 4; ++n)
                bfr[n] = *(const bf16x8*)&Bs[cur][(wc * 64 + n * 16 + rA) * 64 + kkS];
#pragma unroll
            for (int m = 0; m < 4; ++m)
#pragma unroll
                for (int n = 0; n < 4; ++n)
                    acc[m][n] = __builtin_amdgcn_mfma_f32_16x16x32_bf16(
                        af[m], bfr[n], acc[m][n], 0, 0, 0);
        }
        __builtin_amdgcn_sched_barrier(0);
        asm volatile("s_waitcnt lgkmcnt(0)" ::: "memory");
        __builtin_amdgcn_s_barrier();
        __builtin_amdgcn_sched_barrier(0);
    }

    const int cl = lane & 15, rg = lane >> 4;
#pragma unroll
    for (int m = 0; m < 4; ++m) {
#pragma unroll
        for (int j = 0; j < 4; ++j) {
            const int row = row0 + wr * 64 + m * 16 + rg * 4 + j;
            float msk = 1.f;
            if (EPI == 1 || EPI == 2) {
                msk = ((row & (LSEQ - 1)) < len0) ? 1.f : 0.f;
            }
#pragma unroll
            for (int n = 0; n < 4; ++n) {
                const int col = col0 + wc * 64 + n * 16 + cl;
                float v = acc[m][n][j];
                if (EPI == 0) {
                    if (col < DINNER) ((float*)Cv)[(size_t)row * DINNER + col] = v;
                    else ((unsigned short*)C2v)[(size_t)row * DINNER + col - DINNER] = f2bf(v);
                } else if (EPI == 1) {
                    v += bias[col];
                    v = (v > 20.f) ? v : log1pf(__expf(v));
                    ((float*)Cv)[(size_t)row * ldc + col] = v * msk;
                } else if (EPI == 2) {
                    ((float*)Cv)[(size_t)row * ldc + col] =
                        residual[(size_t)row * ldc + col] + msk * v;
                } else {  // EPI 3
                    if (col < 64) aux[(size_t)row * 64 + col] = f2bf(v);
                    else if (col < 96) ((float*)Cv)[(size_t)row * 96 + col] = v;
                }
            }
        }
    }
}

// ---------------- causal depthwise conv (K=4) + SiLU + mask -> bf16 ----------------
__global__ __launch_bounds__(256) void conv_silu_k(const float* __restrict__ ur,
                                                   const float* __restrict__ cw,
                                                   const int* __restrict__ lengths,
                                                   unsigned short* __restrict__ u) {
    const int g = blockIdx.x;              // NB * 512
    const int b = g >> 9;
    const int rem = g & 511;
    const int l0 = (rem >> 1) << 3;
    const int d4 = (rem & 1) * 1024 + threadIdx.x * 4;
    const int len = lengths[b];
    const size_t rb = (size_t)b * LSEQ;
    if (l0 >= len) {
        const int lenUp = (len + CH - 1) & ~(CH - 1);
        if (l0 < lenUp) {
            ushort4 z4 = {0, 0, 0, 0};
#pragma unroll
            for (int i = 0; i < 8; ++i)
                *(ushort4*)(u + (rb + l0 + i) * DINNER + d4) = z4;
        }
        return;
    }
    float4 wq[4];
#pragma unroll
    for (int c = 0; c < 4; ++c) wq[c] = *(const float4*)(cw + 4 * (d4 + c));
    const float4 zero4 = {0.f, 0.f, 0.f, 0.f};
    float4 xm3 = (l0 - 3 >= 0 && l0 - 3 < len) ? *(const float4*)(ur + (rb + l0 - 3) * DINNER + d4) : zero4;
    float4 xm2 = (l0 - 2 >= 0 && l0 - 2 < len) ? *(const float4*)(ur + (rb + l0 - 2) * DINNER + d4) : zero4;
    float4 xm1 = (l0 - 1 >= 0 && l0 - 1 < len) ? *(const float4*)(ur + (rb + l0 - 1) * DINNER + d4) : zero4;
#pragma unroll
    for (int i = 0; i < 8; ++i) {
        const int l = l0 + i;
        const bool act = l < len;
        float4 x0 = act ? *(const float4*)(ur + (rb + l) * DINNER + d4) : zero4;
        float a0 = wq[0].x * xm3.x + wq[0].y * xm2.x + wq[0].z * xm1.x + wq[0].w * x0.x;
        float a1 = wq[1].x * xm3.y + wq[1].y * xm2.y + wq[1].z * xm1.y + wq[1].w * x0.y;
        float a2 = wq[2].x * xm3.z + wq[2].y * xm2.z + wq[2].z * xm1.z + wq[2].w * x0.z;
        float a3 = wq[3].x * xm3.w + wq[3].y * xm2.w + wq[3].z * xm1.w + wq[3].w * x0.w;
        ushort4 ov;
        ov.x = f2bf(act ? siluf(a0) : 0.f);
        ov.y = f2bf(act ? siluf(a1) : 0.f);
        ov.z = f2bf(act ? siluf(a2) : 0.f);
        ov.w = f2bf(act ? siluf(a3) : 0.f);
        *(ushort4*)(u + (rb + l) * DINNER + d4) = ov;
        xm3 = xm2; xm2 = xm1; xm1 = x0;
    }
}

// ---------------- scan phase 1 (4 states/lane, dbuf + register prefetch) ----------------
// grid = SCH*128; block 256 = 64 channels x 4 lanes (lane q owns states 4q..4q+3).
// h op-sequence bit-identical to round-14 p1 -> h_last unchanged.
__global__ __launch_bounds__(256) void scan_p1(const float* __restrict__ dlt,
                                               const unsigned short* __restrict__ uy,
                                               const float* __restrict__ xdbl,
                                               const float* __restrict__ A_log,
                                               const int* __restrict__ lengths,
                                               float* __restrict__ hloc,
                                               float* __restrict__ sumd) {
    __shared__ float2 sDU[2][STT][SCB];   // 16 KB
    __shared__ float  sB[2][STT][16];     // 2 KB
    const int t = threadIdx.x;
    const int s = blockIdx.x >> 7;
    const int g = blockIdx.x & 127;
    const int b = g >> 5;
    const int d0 = (g & 31) * SCB;
    const int ch = t >> 2, q = t & 3;
    const int d = d0 + ch;
    const size_t hbase = ((size_t)(b * 128 + (d >> 4)) * SCH + s) * 256 + (size_t)(d & 15) * 16 + q * 4;
    if (s * CH >= lengths[b]) {          // fully masked chunk: exact identity
        *(float4*)(hloc + hbase) = float4{0.f, 0.f, 0.f, 0.f};
        if (q == 0) sumd[((b * 128 + (d >> 4)) * SCH + s) * 16 + (d & 15)] = 0.f;
        return;
    }
    const float Av0 = -__expf(A_log[d * NST + q * 4 + 0]) * 1.44269504f;
    const float Av1 = -__expf(A_log[d * NST + q * 4 + 1]) * 1.44269504f;
    const float Av2_ = -__expf(A_log[d * NST + q * 4 + 2]) * 1.44269504f;
    const float Av3 = -__expf(A_log[d * NST + q * 4 + 3]) * 1.44269504f;
    float h0 = 0.f, h1 = 0.f, h2 = 0.f, h3 = 0.f, sd = 0.f;
    const size_t base = (size_t)b * LSEQ + (size_t)s * CH;
    const int r = t >> 4, c4 = (t & 15) << 2, nn = t & 15;

    // prologue: load tile 0 into registers
    size_t row = base + r;
    float4 dv = *(const float4*)(dlt + row * DINNER + d0 + c4);
    ushort4 uv = *(const ushort4*)(uy + row * DINNER + d0 + c4);
    float bv = xdbl[row * 96 + 64 + nn];

    for (int l0 = 0; l0 < CH; l0 += STT) {
        const int cur = (l0 >> 4) & 1;
        // write staged regs -> LDS[cur]
        sDU[cur][r][c4 + 0] = float2{dv.x, dv.x * bf2f(uv.x)};
        sDU[cur][r][c4 + 1] = float2{dv.y, dv.y * bf2f(uv.y)};
        sDU[cur][r][c4 + 2] = float2{dv.z, dv.z * bf2f(uv.z)};
        sDU[cur][r][c4 + 3] = float2{dv.w, dv.w * bf2f(uv.w)};
        sB[cur][r][nn] = bv;
        // prefetch next tile (lands during compute)
        if (l0 + STT < CH) {
            row = base + l0 + STT + r;
            dv = *(const float4*)(dlt + row * DINNER + d0 + c4);
            uv = *(const ushort4*)(uy + row * DINNER + d0 + c4);
            bv = xdbl[row * 96 + 64 + nn];
        }
        __syncthreads();
#pragma unroll
        for (int r2 = 0; r2 < STT; ++r2) {
            float2 du = sDU[cur][r2][ch];
            float4 bb = *(const float4*)&sB[cur][r2][q * 4];
            sd += du.x;
            h0 = fmaf(__builtin_amdgcn_exp2f(du.x * Av0),  h0, du.y * bb.x);
            h1 = fmaf(__builtin_amdgcn_exp2f(du.x * Av1),  h1, du.y * bb.y);
            h2 = fmaf(__builtin_amdgcn_exp2f(du.x * Av2_), h2, du.y * bb.z);
            h3 = fmaf(__builtin_amdgcn_exp2f(du.x * Av3),  h3, du.y * bb.w);
        }
    }
    *(float4*)(hloc + hbase) = float4{h0, h1, h2, h3};
    if (q == 0) sumd[((b * 128 + (d >> 4)) * SCH + s) * 16 + (d & 15)] = sd;
}

// ---------------- scan phase 2: sequential chunk fix-up + h_last (unchanged) ----------------
__global__ __launch_bounds__(256) void scan_p2(const float* __restrict__ hloc,
                                               const float* __restrict__ sumd,
                                               const float* __restrict__ A_log,
                                               float* __restrict__ hin,
                                               float* __restrict__ out_h) {
    const int t = threadIdx.x;
    const int bd = blockIdx.x;
    const int b = bd >> 7;
    const int d = ((bd & 127) << 4) + (t >> 4);
    const int n = t & 15;
    const float Av2 = -__expf(A_log[d * NST + n]) * 1.44269504f;
    float h = 0.f;
#pragma unroll
    for (int s = 0; s < SCH; ++s) {
        const size_t idx = ((size_t)bd * SCH + s) * 256 + t;
        hin[idx] = h;
        float P = __builtin_amdgcn_exp2f(Av2 * sumd[(bd * SCH + s) * 16 + (t >> 4)]);
        h = fmaf(P, h, hloc[idx]);
    }
    out_h[((size_t)(b * DINNER + d)) * NST + n] = h;
}

// ---------------- scan phase 3 (4 states/lane, dbuf + prefetch, reg-carried u/z) ----------------
__global__ __launch_bounds__(256) void scan_p3(const float* __restrict__ dlt,
                                               const unsigned short* __restrict__ zb,
                                               unsigned short* uy,
                                               const float* __restrict__ xdbl,
                                               const float* __restrict__ A_log,
                                               const float* __restrict__ D_skip,
                                               const int* __restrict__ lengths,
                                               const float* __restrict__ hin) {
    __shared__ float2 sDU[2][STT][SCB];   // 16 KB
    __shared__ float  sBC[2][STT][32];    // 4 KB
    __shared__ float  sY[STT][SCB];       // 4 KB
    __shared__ float  sDk[SCB];
    const int t = threadIdx.x;
    const int s = blockIdx.x >> 7;
    const int g = blockIdx.x & 127;
    const int b = g >> 5;
    const int d0 = (g & 31) * SCB;
    const int ch = t >> 2, q = t & 3;
    const int d = d0 + ch;
    if (s * CH >= lengths[b]) return;    // fully masked chunk: y never consumed
    if (t < SCB) sDk[t] = D_skip[d0 + t];
    const float Av0 = -__expf(A_log[d * NST + q * 4 + 0]) * 1.44269504f;
    const float Av1 = -__expf(A_log[d * NST + q * 4 + 1]) * 1.44269504f;
    const float Av2_ = -__expf(A_log[d * NST + q * 4 + 2]) * 1.44269504f;
    const float Av3 = -__expf(A_log[d * NST + q * 4 + 3]) * 1.44269504f;
    const size_t hbase = ((size_t)(b * 128 + (d >> 4)) * SCH + s) * 256 + (size_t)(d & 15) * 16 + q * 4;
    float4 hv = *(const float4*)(hin + hbase);
    float h0 = hv.x, h1 = hv.y, h2 = hv.z, h3 = hv.w;
    const size_t base = (size_t)b * LSEQ + (size_t)s * CH;
    const int r = t >> 4, c4 = (t & 15) << 2, n2 = (t & 15) << 1;

    // prologue: load tile 0 into registers
    size_t row = base + r;
    float4 dv = *(const float4*)(dlt + row * DINNER + d0 + c4);
    ushort4 uv = *(const ushort4*)(uy + row * DINNER + d0 + c4);
    ushort4 zz = *(const ushort4*)(zb + row * DINNER + d0 + c4);
    float2 bc = *(const float2*)(xdbl + row * 96 + 64 + n2);

    for (int l0 = 0; l0 < CH; l0 += STT) {
        const int cur = (l0 >> 4) & 1;
        // write staged regs -> LDS[cur]; keep u/z regs for the write phase
        sDU[cur][r][c4 + 0] = float2{dv.x, dv.x * bf2f(uv.x)};
        sDU[cur][r][c4 + 1] = float2{dv.y, dv.y * bf2f(uv.y)};
        sDU[cur][r][c4 + 2] = float2{dv.z, dv.z * bf2f(uv.z)};
        sDU[cur][r][c4 + 3] = float2{dv.w, dv.w * bf2f(uv.w)};
        sBC[cur][r][n2 + 0] = bc.x;
        sBC[cur][r][n2 + 1] = bc.y;
        const ushort4 uvW = uv;
        const ushort4 zzW = zz;
        const size_t rowW = row;
        // prefetch next tile (lands during compute)
        if (l0 + STT < CH) {
            row = base + l0 + STT + r;
            dv = *(const float4*)(dlt + row * DINNER + d0 + c4);
            uv = *(const ushort4*)(uy + row * DINNER + d0 + c4);
            zz = *(const ushort4*)(zb + row * DINNER + d0 + c4);
            bc = *(const float2*)(xdbl + row * 96 + 64 + n2);
        }
        __syncthreads();
#pragma unroll
        for (int r2 = 0; r2 < STT; ++r2) {
            float2 du = sDU[cur][r2][ch];
            float4 bb = *(const float4*)&sBC[cur][r2][q * 4];
            float4 cc = *(const float4*)&sBC[cur][r2][16 + q * 4];
            float y;
            h0 = fmaf(__builtin_amdgcn_exp2f(du.x * Av0),  h0, du.y * bb.x); y = h0 * cc.x;
            h1 = fmaf(__builtin_amdgcn_exp2f(du.x * Av1),  h1, du.y * bb.y); y = fmaf(h1, cc.y, y);
            h2 = fmaf(__builtin_amdgcn_exp2f(du.x * Av2_), h2, du.y * bb.z); y = fmaf(h2, cc.z, y);
            h3 = fmaf(__builtin_amdgcn_exp2f(du.x * Av3),  h3, du.y * bb.w); y = fmaf(h3, cc.w, y);
            y += dpp_qp<0x39>(y);   // + rotate1 within quad
            y += dpp_qp<0x4E>(y);   // + rotate2 -> full 16-state sum in all 4 lanes
            if (q == 0) sY[r2][ch] = y;
        }
        __syncthreads();
        // write phase: y_out = (y + u*D) * silu(z) from kept registers (no global re-read)
        {
            float4 yv = *(const float4*)&sY[r][c4];
            float4 kk = *(const float4*)&sDk[c4];
            ushort4 ov;
            ov.x = f2bf(fmaf(bf2f(uvW.x), kk.x, yv.x) * siluf(bf2f(zzW.x)));
            ov.y = f2bf(fmaf(bf2f(uvW.y), kk.y, yv.y) * siluf(bf2f(zzW.y)));
            ov.z = f2bf(fmaf(bf2f(uvW.z), kk.z, yv.z) * siluf(bf2f(zzW.z)));
            ov.w = f2bf(fmaf(bf2f(uvW.w), kk.w, yv.w) * siluf(bf2f(zzW.w)));
            *(ushort4*)(uy + rowW * DINNER + d0 + c4) = ov;
        }
    }
}

extern "C" void kernel_launch(void* const* d_in, const int* in_sizes, int n_in,
                              void* d_out, int out_size, void* d_ws, size_t ws_size,
                              hipStream_t stream) {
    const float* hs        = (const float*)d_in[0];
    const int*   lengths   = (const int*)d_in[1];
    const float* norm_w    = (const float*)d_in[2];
    const float* in_proj_w = (const float*)d_in[3];
    const float* conv_w    = (const float*)d_in[4];
    const float* x_proj_w  = (const float*)d_in[5];
    const float* dt_proj_w = (const float*)d_in[6];
    const float* dt_proj_b = (const float*)d_in[7];
    const float* A_log     = (const float*)d_in[8];
    const float* D_skip    = (const float*)d_in[9];
    const float* out_proj_w= (const float*)d_in[10];

    float* out = (float*)d_out;

    const int M = NB * LSEQ;                                            // 8192
    float* ur = (float*)d_ws;                                           // 8192x2048 f32: u_raw -> dlt
    unsigned short* zb = (unsigned short*)(ur + (size_t)M * DINNER);    // 8192x2048 bf16: z
    unsigned short* u_bf = zb + (size_t)M * DINNER;                     // 8192x2048 bf16: u -> y
    float* xdbl = (float*)(u_bf + (size_t)M * DINNER);                  // 8192x96 f32
    unsigned short* w_in  = (unsigned short*)(xdbl + (size_t)M * 96);   // 4096x1024
    unsigned short* w_out = w_in + (size_t)4096 * 1024;                 // 1024x2048
    unsigned short* w_x   = w_out + (size_t)1024 * 2048;                // 96x2048
    unsigned short* w_dt  = w_x + (size_t)96 * 2048;                    // 2048x64
    unsigned short* dtr   = w_dt + (size_t)2048 * 64;                   // 8192x64 bf16
    float* hin            = (float*)(dtr + (size_t)M * 64);             // 512*16*256 f32
    unsigned short* xn_bf = u_bf;          // alias: dead once conv overwrites it
    float* dlt  = ur;                      // alias: ur dead after conv
    float* hloc = (float*)w_in;            // alias: w_in dead after in_proj
    float* sumd = (float*)dtr;             // alias: dtr dead after dt_proj

    // 1. fused RMSNorm->bf16 + fused weight conversions
    rmsnorm_cvt_k<<<M, 256, 0, stream>>>(hs, norm_w, xn_bf);
    cvt_all_k<<<6464, 256, 0, stream>>>(in_proj_w, out_proj_w, x_proj_w, dt_proj_w,
                                        w_in, w_out, w_x, w_dt);

    // 2. in_proj (bf16 MFMA dbuf+swz, row-skip): ur f32 | z bf16
    gemm_bf16<0><<<(4096 / 128) * (M / 128), 256, 0, stream>>>(
        xn_bf, DMODEL, w_in, DMODEL, ur, zb, DINNER, M, 4096, DMODEL, 4096 / 128,
        nullptr, nullptr, nullptr, lengths);

    // 3. causal depthwise conv + silu + mask -> u (bf16)
    conv_silu_k<<<NB * 512, 256, 0, stream>>>(ur, conv_w, lengths, u_bf);

    // 4. x_proj (bf16 MFMA dbuf+swz, row-skip): B,C -> xdbl f32; dt_r -> dtr bf16
    gemm_bf16<3><<<1 * (M / 128), 256, 0, stream>>>(
        u_bf, DINNER, w_x, DINNER, xdbl, nullptr, 96, M, 96, DINNER, 1,
        nullptr, nullptr, dtr, lengths);

    // 5. dt_proj (bf16 MFMA dbuf+swz, row-skip) + softplus + mask -> delta f32
    gemm_bf16<1><<<(DINNER / 128) * (M / 128), 256, 0, stream>>>(
        dtr, 64, w_dt, 64, dlt, nullptr, DINNER, M, DINNER, 64, DINNER / 128,
        dt_proj_b, nullptr, nullptr, lengths);

    // 6. chunked selective scan (3 phases, chunk-skip, dbuf+prefetch p1/p3)
    {
        float* hlast = out + (size_t)M * DMODEL;
        scan_p1<<<SCH * 128, 256, 0, stream>>>(dlt, u_bf, xdbl, A_log, lengths, hloc, sumd);
        scan_p2<<<NBD, 256, 0, stream>>>(hloc, sumd, A_log, hin, hlast);
        scan_p3<<<SCH * 128, 256, 0, stream>>>(dlt, zb, u_bf, xdbl, A_log, D_skip, lengths, hin);
    }

    // 7. out_proj (bf16 MFMA dbuf+swz, row-skip -> residual copy) + residual + mask
    gemm_bf16<2><<<(DMODEL / 128) * (M / 128), 256, 0, stream>>>(
        u_bf, DINNER, w_out, DINNER, out, nullptr, DMODEL, M, DMODEL, DINNER, DMODEL / 128,
        nullptr, hs, nullptr, lengths);
}

// Round 16
// 284.564 us; speedup vs baseline: 1.2463x; 1.0844x over previous
//
#include <hip/hip_runtime.h>
#include <cstdint>
#include <cstddef>

#define LSEQ 2048
#define NB   4
#define DMODEL 1024
#define DINNER 2048
#define NST  16
#define CH   128   // scan chunk length == GEMM tile height
#define SCH  (LSEQ / CH)   // 16 chunks
#define NBD  512           // NB * DINNER/16 (p2 layout)
#define STT  16    // scan steps per LDS tile
#define SCB  64    // channels per scan block (4 lanes each)

typedef short bf16x8 __attribute__((ext_vector_type(8)));
typedef float f32x4  __attribute__((ext_vector_type(4)));

__device__ __forceinline__ float siluf(float x) { return x / (1.f + __expf(-x)); }

__device__ __forceinline__ unsigned short f2bf(float f) {
    unsigned u = __float_as_uint(f);
    u += 0x7FFF + ((u >> 16) & 1);     // round-to-nearest-even
    return (unsigned short)(u >> 16);
}
__device__ __forceinline__ float bf2f(unsigned short h) {
    return __uint_as_float(((unsigned)h) << 16);
}
__device__ __forceinline__ void gload_lds16(const void* g, void* l) {
    __builtin_amdgcn_global_load_lds(
        (const __attribute__((address_space(1))) unsigned int*)g,
        (__attribute__((address_space(3))) unsigned int*)l, 16, 0, 0);
}

// DPP quad_perm add helpers: rotate within 4-lane quad
template <int CTRL>
__device__ __forceinline__ float dpp_qp(float v) {
    return __int_as_float(__builtin_amdgcn_update_dpp(
        0, __float_as_int(v), CTRL, 0xf, 0xf, false));
}

// ---------------- fused RMSNorm + bf16 convert ----------------
__global__ __launch_bounds__(256) void rmsnorm_cvt_k(const float* __restrict__ x,
                                                     const float* __restrict__ nw,
                                                     unsigned short* __restrict__ o) {
    int row = blockIdx.x, t = threadIdx.x;
    float4 v = ((const float4*)(x + (size_t)row * DMODEL))[t];
    float s = v.x * v.x + v.y * v.y + v.z * v.z + v.w * v.w;
#pragma unroll
    for (int m = 32; m >= 1; m >>= 1) s += __shfl_xor(s, m);
    __shared__ float wsum[4];
    __shared__ float sinv;
    if ((t & 63) == 0) wsum[t >> 6] = s;
    __syncthreads();
    if (t == 0) {
        float tot = wsum[0] + wsum[1] + wsum[2] + wsum[3];
        sinv = rsqrtf(tot * (1.f / (float)DMODEL) + 1e-6f);
    }
    __syncthreads();
    float iv = sinv;
    float4 w = ((const float4*)nw)[t];
    ushort4 ov;
    ov.x = f2bf(v.x * iv * w.x); ov.y = f2bf(v.y * iv * w.y);
    ov.z = f2bf(v.z * iv * w.z); ov.w = f2bf(v.w * iv * w.w);
    ((ushort4*)(o + (size_t)row * DMODEL))[t] = ov;
}

// ---------------- fused weight conversions (4 matrices, 1 launch) ----------------
__global__ __launch_bounds__(256) void cvt_all_k(const float* __restrict__ s0, const float* __restrict__ s1,
                                                 const float* __restrict__ s2, const float* __restrict__ s3,
                                                 unsigned short* __restrict__ q0, unsigned short* __restrict__ q1,
                                                 unsigned short* __restrict__ q2, unsigned short* __restrict__ q3) {
    int i = blockIdx.x * 256 + threadIdx.x;
    const float* s; unsigned short* d; int off;
    if (i < 1048576)       { s = s0; d = q0; off = i; }
    else if (i < 1572864)  { s = s1; d = q1; off = i - 1048576; }
    else if (i < 1622016)  { s = s2; d = q2; off = i - 1572864; }
    else if (i < 1654784)  { s = s3; d = q3; off = i - 1622016; }
    else return;
    float4 v = ((const float4*)s)[off];
    ushort4 o;
    o.x = f2bf(v.x); o.y = f2bf(v.y); o.z = f2bf(v.z); o.w = f2bf(v.w);
    ((ushort4*)d)[off] = o;
}

// ---------------- bf16 MFMA NT GEMM: dbuf LDS + counted vmcnt + XOR swizzle ----------------
// EPI 0: split store: col<2048 -> f32 Cv (ur), col>=2048 -> bf16 C2 (z)  (in_proj)
// EPI 1: softplus(acc+bias)*mask -> f32 store                            (dt_proj)
// EPI 2: residual + mask*acc -> f32; skipped tiles copy residual         (out_proj)
// EPI 4: split-K partial: seg = bid&3, K-window seg*512..+512; f32 partial store (x_proj)
template <int EPI>
__global__ __launch_bounds__(256) void gemm_bf16(
    const unsigned short* __restrict__ A, int lda,
    const unsigned short* __restrict__ W, int ldw,
    void* __restrict__ Cv, void* __restrict__ C2v, int ldc,
    int M, int N, int K, int nbx,
    const float* __restrict__ bias,
    const float* __restrict__ residual,
    unsigned short* __restrict__ aux,
    const int* __restrict__ lengths) {
    __shared__ __align__(16) unsigned short As[2][128 * 64];
    __shared__ __align__(16) unsigned short Bs[2][128 * 64];
    const int bid = blockIdx.x;
    int bx, by, seg;
    if (EPI == 4) { seg = bid & 3; by = bid >> 2; bx = 0; }
    else          { seg = 0; bx = bid % nbx; by = bid / nbx; }
    const unsigned short* Ap = A + (size_t)seg * 512;
    const unsigned short* Wp = W + (size_t)seg * 512;
    const int row0 = by * 128, col0 = bx * 128;
    const int t = threadIdx.x;

    const int len0 = lengths[row0 >> 11];
    if ((row0 & (LSEQ - 1)) >= len0) {
        if (EPI == 2) {
            float* C = (float*)Cv;
#pragma unroll
            for (int i = 0; i < 16; ++i) {
                int lin = i * 256 + t;
                int r = lin >> 5, c = (lin & 31) << 2;
                *(float4*)(C + (size_t)(row0 + r) * ldc + col0 + c) =
                    *(const float4*)(residual + (size_t)(row0 + r) * ldc + col0 + c);
            }
        }
        return;
    }

    const int lane = t & 63;
    const int w = t >> 6;
    const int wr = w >> 1, wc = w & 1;

    f32x4 acc[4][4];
#pragma unroll
    for (int m = 0; m < 4; ++m)
#pragma unroll
        for (int n = 0; n < 4; ++n) acc[m][n] = f32x4{0.f, 0.f, 0.f, 0.f};

    const int rA = lane & 15;
    const int kH = (lane >> 4) << 3;
    const int NT = K >> 6;
    const int swzR = (rA & 7) << 3;

    auto STAGE = [&](int sel, int k0) {
#pragma unroll
        for (int it = 0; it < 4; ++it) {
            int c = it * 256 + t;
            int r = c >> 3;
            int cc = ((c & 7) ^ (r & 7)) << 3;
            gload_lds16(Ap + (size_t)(row0 + r) * lda + k0 + cc, &As[sel][c << 3]);
            int wrow = col0 + r; if (wrow >= N) wrow = N - 1;
            gload_lds16(Wp + (size_t)wrow * ldw + k0 + cc, &Bs[sel][c << 3]);
        }
    };

    STAGE(0, 0);
    for (int kt = 0; kt < NT; ++kt) {
        const int cur = kt & 1;
        if (kt + 1 < NT) STAGE(cur ^ 1, (kt + 1) << 6);
        __builtin_amdgcn_sched_barrier(0);
        if (kt + 1 < NT) { asm volatile("s_waitcnt vmcnt(8)" ::: "memory"); }
        else             { asm volatile("s_waitcnt vmcnt(0)" ::: "memory"); }
        __builtin_amdgcn_sched_barrier(0);
        __builtin_amdgcn_s_barrier();
        __builtin_amdgcn_sched_barrier(0);
#pragma unroll
        for (int ks = 0; ks < 2; ++ks) {
            const int kkS = (ks * 32 + kH) ^ swzR;
            bf16x8 af[4], bfr[4];
#pragma unroll
            for (int m = 0; m < 4; ++m)
                af[m] = *(const bf16x8*)&As[cur][(wr * 64 + m * 16 + rA) * 64 + kkS];
#pragma unroll
            for (int n = 0; n < 4; ++n)
                bfr[n] = *(const bf16x8*)&Bs[cur][(wc * 64 + n * 16 + rA) * 64 + kkS];
#pragma unroll
            for (int m = 0; m < 4; ++m)
#pragma unroll
                for (int n = 0; n < 4; ++n)
                    acc[m][n] = __builtin_amdgcn_mfma_f32_16x16x32_bf16(
                        af[m], bfr[n], acc[m][n], 0, 0, 0);
        }
        __builtin_amdgcn_sched_barrier(0);
        asm volatile("s_waitcnt lgkmcnt(0)" ::: "memory");
        __builtin_amdgcn_s_barrier();
        __builtin_amdgcn_sched_barrier(0);
    }

    const int cl = lane & 15, rg = lane >> 4;
#pragma unroll
    for (int m = 0; m < 4; ++m) {
#pragma unroll
        for (int j = 0; j < 4; ++j) {
            const int row = row0 + wr * 64 + m * 16 + rg * 4 + j;
            float msk = 1.f;
            if (EPI == 1 || EPI == 2) {
                msk = ((row & (LSEQ - 1)) < len0) ? 1.f : 0.f;
            }
#pragma unroll
            for (int n = 0; n < 4; ++n) {
                const int col = col0 + wc * 64 + n * 16 + cl;
                float v = acc[m][n][j];
                if (EPI == 0) {
                    if (col < DINNER) ((float*)Cv)[(size_t)row * DINNER + col] = v;
                    else ((unsigned short*)C2v)[(size_t)row * DINNER + col - DINNER] = f2bf(v);
                } else if (EPI == 1) {
                    v += bias[col];
                    v = (v > 20.f) ? v : log1pf(__expf(v));
                    ((float*)Cv)[(size_t)row * ldc + col] = v * msk;
                } else if (EPI == 2) {
                    ((float*)Cv)[(size_t)row * ldc + col] =
                        residual[(size_t)row * ldc + col] + msk * v;
                } else if (EPI == 4) {
                    if (col < 96)
                        ((float*)Cv)[(size_t)seg * M * 96 + (size_t)row * 96 + col] = v;
                }
            }
        }
    }
}

// ---------------- x_proj split-K reduce: sum 4 partials -> dtr bf16 + xdbl f32 ----------------
__global__ __launch_bounds__(384) void xred_k(const float* __restrict__ P,
                                              const int* __restrict__ lengths,
                                              unsigned short* __restrict__ dtr,
                                              float* __restrict__ xdbl) {
    const int t = threadIdx.x;
    const int row = blockIdx.x * 4 + t / 96;
    const int col = t % 96;
    const int b = row >> 11, l = row & (LSEQ - 1);
    const int lenUp = (lengths[b] + CH - 1) & ~(CH - 1);
    if (l >= lenUp) return;
    const size_t SEG = (size_t)8192 * 96;
    const size_t idx = (size_t)row * 96 + col;
    float v = P[idx] + P[idx + SEG] + P[idx + 2 * SEG] + P[idx + 3 * SEG];
    if (col < 64) dtr[(size_t)row * 64 + col] = f2bf(v);
    else xdbl[idx] = v;
}

// ---------------- causal depthwise conv (K=4) + SiLU + mask -> bf16 ----------------
__global__ __launch_bounds__(256) void conv_silu_k(const float* __restrict__ ur,
                                                   const float* __restrict__ cw,
                                                   const int* __restrict__ lengths,
                                                   unsigned short* __restrict__ u) {
    const int g = blockIdx.x;              // NB * 512
    const int b = g >> 9;
    const int rem = g & 511;
    const int l0 = (rem >> 1) << 3;
    const int d4 = (rem & 1) * 1024 + threadIdx.x * 4;
    const int len = lengths[b];
    const size_t rb = (size_t)b * LSEQ;
    if (l0 >= len) {
        const int lenUp = (len + CH - 1) & ~(CH - 1);
        if (l0 < lenUp) {
            ushort4 z4 = {0, 0, 0, 0};
#pragma unroll
            for (int i = 0; i < 8; ++i)
                *(ushort4*)(u + (rb + l0 + i) * DINNER + d4) = z4;
        }
        return;
    }
    float4 wq[4];
#pragma unroll
    for (int c = 0; c < 4; ++c) wq[c] = *(const float4*)(cw + 4 * (d4 + c));
    const float4 zero4 = {0.f, 0.f, 0.f, 0.f};
    float4 xm3 = (l0 - 3 >= 0 && l0 - 3 < len) ? *(const float4*)(ur + (rb + l0 - 3) * DINNER + d4) : zero4;
    float4 xm2 = (l0 - 2 >= 0 && l0 - 2 < len) ? *(const float4*)(ur + (rb + l0 - 2) * DINNER + d4) : zero4;
    float4 xm1 = (l0 - 1 >= 0 && l0 - 1 < len) ? *(const float4*)(ur + (rb + l0 - 1) * DINNER + d4) : zero4;
#pragma unroll
    for (int i = 0; i < 8; ++i) {
        const int l = l0 + i;
        const bool act = l < len;
        float4 x0 = act ? *(const float4*)(ur + (rb + l) * DINNER + d4) : zero4;
        float a0 = wq[0].x * xm3.x + wq[0].y * xm2.x + wq[0].z * xm1.x + wq[0].w * x0.x;
        float a1 = wq[1].x * xm3.y + wq[1].y * xm2.y + wq[1].z * xm1.y + wq[1].w * x0.y;
        float a2 = wq[2].x * xm3.z + wq[2].y * xm2.z + wq[2].z * xm1.z + wq[2].w * x0.z;
        float a3 = wq[3].x * xm3.w + wq[3].y * xm2.w + wq[3].z * xm1.w + wq[3].w * x0.w;
        ushort4 ov;
        ov.x = f2bf(act ? siluf(a0) : 0.f);
        ov.y = f2bf(act ? siluf(a1) : 0.f);
        ov.z = f2bf(act ? siluf(a2) : 0.f);
        ov.w = f2bf(act ? siluf(a3) : 0.f);
        *(ushort4*)(u + (rb + l) * DINNER + d4) = ov;
        xm3 = xm2; xm2 = xm1; xm1 = x0;
    }
}

// ---------------- scan phase 1 (4 states/lane, dbuf + register prefetch) ----------------
__global__ __launch_bounds__(256) void scan_p1(const float* __restrict__ dlt,
                                               const unsigned short* __restrict__ uy,
                                               const float* __restrict__ xdbl,
                                               const float* __restrict__ A_log,
                                               const int* __restrict__ lengths,
                                               float* __restrict__ hloc,
                                               float* __restrict__ sumd) {
    __shared__ float2 sDU[2][STT][SCB];   // 16 KB
    __shared__ float  sB[2][STT][16];     // 2 KB
    const int t = threadIdx.x;
    const int s = blockIdx.x >> 7;
    const int g = blockIdx.x & 127;
    const int b = g >> 5;
    const int d0 = (g & 31) * SCB;
    const int ch = t >> 2, q = t & 3;
    const int d = d0 + ch;
    const size_t hbase = ((size_t)(b * 128 + (d >> 4)) * SCH + s) * 256 + (size_t)(d & 15) * 16 + q * 4;
    if (s * CH >= lengths[b]) {          // fully masked chunk: exact identity
        *(float4*)(hloc + hbase) = float4{0.f, 0.f, 0.f, 0.f};
        if (q == 0) sumd[((b * 128 + (d >> 4)) * SCH + s) * 16 + (d & 15)] = 0.f;
        return;
    }
    const float Av0 = -__expf(A_log[d * NST + q * 4 + 0]) * 1.44269504f;
    const float Av1 = -__expf(A_log[d * NST + q * 4 + 1]) * 1.44269504f;
    const float Av2_ = -__expf(A_log[d * NST + q * 4 + 2]) * 1.44269504f;
    const float Av3 = -__expf(A_log[d * NST + q * 4 + 3]) * 1.44269504f;
    float h0 = 0.f, h1 = 0.f, h2 = 0.f, h3 = 0.f, sd = 0.f;
    const size_t base = (size_t)b * LSEQ + (size_t)s * CH;
    const int r = t >> 4, c4 = (t & 15) << 2, nn = t & 15;

    size_t row = base + r;
    float4 dv = *(const float4*)(dlt + row * DINNER + d0 + c4);
    ushort4 uv = *(const ushort4*)(uy + row * DINNER + d0 + c4);
    float bv = xdbl[row * 96 + 64 + nn];

    for (int l0 = 0; l0 < CH; l0 += STT) {
        const int cur = (l0 >> 4) & 1;
        sDU[cur][r][c4 + 0] = float2{dv.x, dv.x * bf2f(uv.x)};
        sDU[cur][r][c4 + 1] = float2{dv.y, dv.y * bf2f(uv.y)};
        sDU[cur][r][c4 + 2] = float2{dv.z, dv.z * bf2f(uv.z)};
        sDU[cur][r][c4 + 3] = float2{dv.w, dv.w * bf2f(uv.w)};
        sB[cur][r][nn] = bv;
        if (l0 + STT < CH) {
            row = base + l0 + STT + r;
            dv = *(const float4*)(dlt + row * DINNER + d0 + c4);
            uv = *(const ushort4*)(uy + row * DINNER + d0 + c4);
            bv = xdbl[row * 96 + 64 + nn];
        }
        __syncthreads();
#pragma unroll
        for (int r2 = 0; r2 < STT; ++r2) {
            float2 du = sDU[cur][r2][ch];
            float4 bb = *(const float4*)&sB[cur][r2][q * 4];
            sd += du.x;
            h0 = fmaf(__builtin_amdgcn_exp2f(du.x * Av0),  h0, du.y * bb.x);
            h1 = fmaf(__builtin_amdgcn_exp2f(du.x * Av1),  h1, du.y * bb.y);
            h2 = fmaf(__builtin_amdgcn_exp2f(du.x * Av2_), h2, du.y * bb.z);
            h3 = fmaf(__builtin_amdgcn_exp2f(du.x * Av3),  h3, du.y * bb.w);
        }
    }
    *(float4*)(hloc + hbase) = float4{h0, h1, h2, h3};
    if (q == 0) sumd[((b * 128 + (d >> 4)) * SCH + s) * 16 + (d & 15)] = sd;
}

// ---------------- scan phase 2: sequential chunk fix-up + h_last (unchanged) ----------------
__global__ __launch_bounds__(256) void scan_p2(const float* __restrict__ hloc,
                                               const float* __restrict__ sumd,
                                               const float* __restrict__ A_log,
                                               float* __restrict__ hin,
                                               float* __restrict__ out_h) {
    const int t = threadIdx.x;
    const int bd = blockIdx.x;
    const int b = bd >> 7;
    const int d = ((bd & 127) << 4) + (t >> 4);
    const int n = t & 15;
    const float Av2 = -__expf(A_log[d * NST + n]) * 1.44269504f;
    float h = 0.f;
#pragma unroll
    for (int s = 0; s < SCH; ++s) {
        const size_t idx = ((size_t)bd * SCH + s) * 256 + t;
        hin[idx] = h;
        float P = __builtin_amdgcn_exp2f(Av2 * sumd[(bd * SCH + s) * 16 + (t >> 4)]);
        h = fmaf(P, h, hloc[idx]);
    }
    out_h[((size_t)(b * DINNER + d)) * NST + n] = h;
}

// ---------------- scan phase 3: 4 states/lane, dbuf, 1 barrier/tile, deferred writeout ----------------
__global__ __launch_bounds__(256) void scan_p3(const float* __restrict__ dlt,
                                               const unsigned short* __restrict__ zb,
                                               unsigned short* uy,
                                               const float* __restrict__ xdbl,
                                               const float* __restrict__ A_log,
                                               const float* __restrict__ D_skip,
                                               const int* __restrict__ lengths,
                                               const float* __restrict__ hin) {
    __shared__ float2 sDU[2][STT][SCB];   // 16 KB
    __shared__ float  sBC[2][STT][32];    // 4 KB
    __shared__ float  sY[2][STT][SCB];    // 8 KB
    __shared__ float  sDk[SCB];
    const int t = threadIdx.x;
    const int s = blockIdx.x >> 7;
    const int g = blockIdx.x & 127;
    const int b = g >> 5;
    const int d0 = (g & 31) * SCB;
    const int ch = t >> 2, q = t & 3;
    const int d = d0 + ch;
    if (s * CH >= lengths[b]) return;
    if (t < SCB) sDk[t] = D_skip[d0 + t];
    const float Av0 = -__expf(A_log[d * NST + q * 4 + 0]) * 1.44269504f;
    const float Av1 = -__expf(A_log[d * NST + q * 4 + 1]) * 1.44269504f;
    const float Av2_ = -__expf(A_log[d * NST + q * 4 + 2]) * 1.44269504f;
    const float Av3 = -__expf(A_log[d * NST + q * 4 + 3]) * 1.44269504f;
    const size_t hbase = ((size_t)(b * 128 + (d >> 4)) * SCH + s) * 256 + (size_t)(d & 15) * 16 + q * 4;
    float4 hv = *(const float4*)(hin + hbase);
    float h0 = hv.x, h1 = hv.y, h2 = hv.z, h3 = hv.w;
    const size_t base = (size_t)b * LSEQ + (size_t)s * CH;
    const int r = t >> 4, c4 = (t & 15) << 2, n2 = (t & 15) << 1;

    // prologue: tile 0 regs
    size_t row = base + r;
    float4 dv = *(const float4*)(dlt + row * DINNER + d0 + c4);
    ushort4 uv = *(const ushort4*)(uy + row * DINNER + d0 + c4);
    ushort4 zz = *(const ushort4*)(zb + row * DINNER + d0 + c4);
    float2 bc = *(const float2*)(xdbl + row * 96 + 64 + n2);
    ushort4 uvW0, zzW0, uvW1, zzW1;
    size_t rowW0 = 0, rowW1 = 0;

#define P3_STAGE(CUR, UVW, ZZW, ROWW)                          \
    sDU[CUR][r][c4 + 0] = float2{dv.x, dv.x * bf2f(uv.x)};     \
    sDU[CUR][r][c4 + 1] = float2{dv.y, dv.y * bf2f(uv.y)};     \
    sDU[CUR][r][c4 + 2] = float2{dv.z, dv.z * bf2f(uv.z)};     \
    sDU[CUR][r][c4 + 3] = float2{dv.w, dv.w * bf2f(uv.w)};     \
    sBC[CUR][r][n2 + 0] = bc.x; sBC[CUR][r][n2 + 1] = bc.y;    \
    UVW = uv; ZZW = zz; ROWW = row;

#define P3_PREFETCH(L0N)                                                \
    if ((L0N) < CH) {                                                   \
        row = base + (L0N) + r;                                         \
        dv = *(const float4*)(dlt + row * DINNER + d0 + c4);            \
        uv = *(const ushort4*)(uy + row * DINNER + d0 + c4);            \
        zz = *(const ushort4*)(zb + row * DINNER + d0 + c4);            \
        bc = *(const float2*)(xdbl + row * 96 + 64 + n2);               \
    }

#define P3_COMPUTE(CUR)                                                                    \
    _Pragma("unroll")                                                                      \
    for (int r2 = 0; r2 < STT; ++r2) {                                                     \
        float2 du = sDU[CUR][r2][ch];                                                      \
        float4 bb = *(const float4*)&sBC[CUR][r2][q * 4];                                  \
        float4 cc = *(const float4*)&sBC[CUR][r2][16 + q * 4];                             \
        float y;                                                                           \
        h0 = fmaf(__builtin_amdgcn_exp2f(du.x * Av0),  h0, du.y * bb.x); y = h0 * cc.x;    \
        h1 = fmaf(__builtin_amdgcn_exp2f(du.x * Av1),  h1, du.y * bb.y); y = fmaf(h1, cc.y, y); \
        h2 = fmaf(__builtin_amdgcn_exp2f(du.x * Av2_), h2, du.y * bb.z); y = fmaf(h2, cc.z, y); \
        h3 = fmaf(__builtin_amdgcn_exp2f(du.x * Av3),  h3, du.y * bb.w); y = fmaf(h3, cc.w, y); \
        y += dpp_qp<0x39>(y);                                                              \
        y += dpp_qp<0x4E>(y);                                                              \
        if (q == 0) sY[CUR][r2][ch] = y;                                                   \
    }

#define P3_WRITEOUT(CUR, UVW, ZZW, ROWW) {                                        \
        float4 yv = *(const float4*)&sY[CUR][r][c4];                              \
        float4 kk = *(const float4*)&sDk[c4];                                     \
        ushort4 ov;                                                               \
        ov.x = f2bf(fmaf(bf2f(UVW.x), kk.x, yv.x) * siluf(bf2f(ZZW.x)));          \
        ov.y = f2bf(fmaf(bf2f(UVW.y), kk.y, yv.y) * siluf(bf2f(ZZW.y)));          \
        ov.z = f2bf(fmaf(bf2f(UVW.z), kk.z, yv.z) * siluf(bf2f(ZZW.z)));          \
        ov.w = f2bf(fmaf(bf2f(UVW.w), kk.w, yv.w) * siluf(bf2f(ZZW.w)));          \
        *(ushort4*)(uy + (ROWW) * DINNER + d0 + c4) = ov;                         \
    }

    for (int ii = 0; ii < 4; ++ii) {
        const int l0a = ii * 32;
        // tile 2ii (buffer 0)
        P3_STAGE(0, uvW0, zzW0, rowW0)
        P3_PREFETCH(l0a + 16)
        __syncthreads();
        if (ii > 0) P3_WRITEOUT(1, uvW1, zzW1, rowW1)   // finish tile 2ii-1
        P3_COMPUTE(0)
        // tile 2ii+1 (buffer 1)
        P3_STAGE(1, uvW1, zzW1, rowW1)
        P3_PREFETCH(l0a + 32)
        __syncthreads();
        P3_WRITEOUT(0, uvW0, zzW0, rowW0)               // finish tile 2ii
        P3_COMPUTE(1)
    }
    __syncthreads();
    P3_WRITEOUT(1, uvW1, zzW1, rowW1)                   // finish tile 7

#undef P3_STAGE
#undef P3_PREFETCH
#undef P3_COMPUTE
#undef P3_WRITEOUT
}

extern "C" void kernel_launch(void* const* d_in, const int* in_sizes, int n_in,
                              void* d_out, int out_size, void* d_ws, size_t ws_size,
                              hipStream_t stream) {
    const float* hs        = (const float*)d_in[0];
    const int*   lengths   = (const int*)d_in[1];
    const float* norm_w    = (const float*)d_in[2];
    const float* in_proj_w = (const float*)d_in[3];
    const float* conv_w    = (const float*)d_in[4];
    const float* x_proj_w  = (const float*)d_in[5];
    const float* dt_proj_w = (const float*)d_in[6];
    const float* dt_proj_b = (const float*)d_in[7];
    const float* A_log     = (const float*)d_in[8];
    const float* D_skip    = (const float*)d_in[9];
    const float* out_proj_w= (const float*)d_in[10];

    float* out = (float*)d_out;

    const int M = NB * LSEQ;                                            // 8192
    float* ur = (float*)d_ws;                                           // 8192x2048 f32: u_raw -> dlt
    unsigned short* zb = (unsigned short*)(ur + (size_t)M * DINNER);    // 8192x2048 bf16: z
    unsigned short* u_bf = zb + (size_t)M * DINNER;                     // 8192x2048 bf16: u -> y
    float* xdbl = (float*)(u_bf + (size_t)M * DINNER);                  // 8192x96 f32
    unsigned short* w_in  = (unsigned short*)(xdbl + (size_t)M * 96);   // 4096x1024
    unsigned short* w_out = w_in + (size_t)4096 * 1024;                 // 1024x2048
    unsigned short* w_x   = w_out + (size_t)1024 * 2048;                // 96x2048
    unsigned short* w_dt  = w_x + (size_t)96 * 2048;                    // 2048x64
    unsigned short* dtr   = w_dt + (size_t)2048 * 64;                   // 8192x64 bf16
    float* hin            = (float*)(dtr + (size_t)M * 64);             // 512*16*256 f32 (8MB)
    float* xpart          = hin + (size_t)NBD * SCH * 256;              // 4x8192x96 f32 (12.6MB)
    unsigned short* xn_bf = u_bf;          // alias: dead once conv overwrites it
    float* dlt  = ur;                      // alias: ur dead after conv
    float* hloc = (float*)w_in;            // alias: w_in dead after in_proj
    float* sumd = (float*)dtr;             // alias: dtr dead after dt_proj

    // 1. fused RMSNorm->bf16 + fused weight conversions
    rmsnorm_cvt_k<<<M, 256, 0, stream>>>(hs, norm_w, xn_bf);
    cvt_all_k<<<6464, 256, 0, stream>>>(in_proj_w, out_proj_w, x_proj_w, dt_proj_w,
                                        w_in, w_out, w_x, w_dt);

    // 2. in_proj (bf16 MFMA dbuf+swz, row-skip): ur f32 | z bf16
    gemm_bf16<0><<<(4096 / 128) * (M / 128), 256, 0, stream>>>(
        xn_bf, DMODEL, w_in, DMODEL, ur, zb, DINNER, M, 4096, DMODEL, 4096 / 128,
        nullptr, nullptr, nullptr, lengths);

    // 3. causal depthwise conv + silu + mask -> u (bf16)
    conv_silu_k<<<NB * 512, 256, 0, stream>>>(ur, conv_w, lengths, u_bf);

    // 4. x_proj split-K4 (grid 256) -> partials; reduce -> dtr bf16 + xdbl f32
    gemm_bf16<4><<<4 * (M / 128), 256, 0, stream>>>(
        u_bf, DINNER, w_x, DINNER, xpart, nullptr, 96, M, 96, 512, 1,
        nullptr, nullptr, nullptr, lengths);
    xred_k<<<M / 4, 384, 0, stream>>>(xpart, lengths, dtr, xdbl);

    // 5. dt_proj (bf16 MFMA dbuf+swz, row-skip) + softplus + mask -> delta f32
    gemm_bf16<1><<<(DINNER / 128) * (M / 128), 256, 0, stream>>>(
        dtr, 64, w_dt, 64, dlt, nullptr, DINNER, M, DINNER, 64, DINNER / 128,
        dt_proj_b, nullptr, nullptr, lengths);

    // 6. chunked selective scan (3 phases, chunk-skip, dbuf+prefetch)
    {
        float* hlast = out + (size_t)M * DMODEL;
        scan_p1<<<SCH * 128, 256, 0, stream>>>(dlt, u_bf, xdbl, A_log, lengths, hloc, sumd);
        scan_p2<<<NBD, 256, 0, stream>>>(hloc, sumd, A_log, hin, hlast);
        scan_p3<<<SCH * 128, 256, 0, stream>>>(dlt, zb, u_bf, xdbl, A_log, D_skip, lengths, hin);
    }

    // 7. out_proj (bf16 MFMA dbuf+swz, row-skip -> residual copy) + residual + mask
    gemm_bf16<2><<<(DMODEL / 128) * (M / 128), 256, 0, stream>>>(
        u_bf, DINNER, w_out, DINNER, out, nullptr, DMODEL, M, DMODEL, DINNER, DMODEL / 128,
        nullptr, hs, nullptr, lengths);
}

// Round 17
// 277.901 us; speedup vs baseline: 1.2762x; 1.0240x over previous
//
#include <hip/hip_runtime.h>
#include <cstdint>
#include <cstddef>

#define LSEQ 2048
#define NB   4
#define DMODEL 1024
#define DINNER 2048
#define NST  16
#define CH   128   // scan chunk length == GEMM tile height
#define SCH  (LSEQ / CH)   // 16 chunks
#define NBD  512           // NB * DINNER/16 (p2 layout)
#define STT  16    // scan steps per LDS tile
#define SCB  64    // channels per scan block (4 lanes each)

typedef short bf16x8 __attribute__((ext_vector_type(8)));
typedef float f32x4  __attribute__((ext_vector_type(4)));

__device__ __forceinline__ float siluf(float x) { return x / (1.f + __expf(-x)); }

__device__ __forceinline__ unsigned short f2bf(float f) {
    unsigned u = __float_as_uint(f);
    u += 0x7FFF + ((u >> 16) & 1);     // round-to-nearest-even
    return (unsigned short)(u >> 16);
}
__device__ __forceinline__ float bf2f(unsigned short h) {
    return __uint_as_float(((unsigned)h) << 16);
}
__device__ __forceinline__ void gload_lds16(const void* g, void* l) {
    __builtin_amdgcn_global_load_lds(
        (const __attribute__((address_space(1))) unsigned int*)g,
        (__attribute__((address_space(3))) unsigned int*)l, 16, 0, 0);
}

// DPP quad_perm add helpers: rotate within 4-lane quad
template <int CTRL>
__device__ __forceinline__ float dpp_qp(float v) {
    return __int_as_float(__builtin_amdgcn_update_dpp(
        0, __float_as_int(v), CTRL, 0xf, 0xf, false));
}

// ---------------- fused RMSNorm + bf16 convert ----------------
__global__ __launch_bounds__(256) void rmsnorm_cvt_k(const float* __restrict__ x,
                                                     const float* __restrict__ nw,
                                                     unsigned short* __restrict__ o) {
    int row = blockIdx.x, t = threadIdx.x;
    float4 v = ((const float4*)(x + (size_t)row * DMODEL))[t];
    float s = v.x * v.x + v.y * v.y + v.z * v.z + v.w * v.w;
#pragma unroll
    for (int m = 32; m >= 1; m >>= 1) s += __shfl_xor(s, m);
    __shared__ float wsum[4];
    __shared__ float sinv;
    if ((t & 63) == 0) wsum[t >> 6] = s;
    __syncthreads();
    if (t == 0) {
        float tot = wsum[0] + wsum[1] + wsum[2] + wsum[3];
        sinv = rsqrtf(tot * (1.f / (float)DMODEL) + 1e-6f);
    }
    __syncthreads();
    float iv = sinv;
    float4 w = ((const float4*)nw)[t];
    ushort4 ov;
    ov.x = f2bf(v.x * iv * w.x); ov.y = f2bf(v.y * iv * w.y);
    ov.z = f2bf(v.z * iv * w.z); ov.w = f2bf(v.w * iv * w.w);
    ((ushort4*)(o + (size_t)row * DMODEL))[t] = ov;
}

// ---------------- fused weight conversions (4 matrices, 1 launch) ----------------
__global__ __launch_bounds__(256) void cvt_all_k(const float* __restrict__ s0, const float* __restrict__ s1,
                                                 const float* __restrict__ s2, const float* __restrict__ s3,
                                                 unsigned short* __restrict__ q0, unsigned short* __restrict__ q1,
                                                 unsigned short* __restrict__ q2, unsigned short* __restrict__ q3) {
    int i = blockIdx.x * 256 + threadIdx.x;
    const float* s; unsigned short* d; int off;
    if (i < 1048576)       { s = s0; d = q0; off = i; }
    else if (i < 1572864)  { s = s1; d = q1; off = i - 1048576; }
    else if (i < 1622016)  { s = s2; d = q2; off = i - 1572864; }
    else if (i < 1654784)  { s = s3; d = q3; off = i - 1622016; }
    else return;
    float4 v = ((const float4*)s)[off];
    ushort4 o;
    o.x = f2bf(v.x); o.y = f2bf(v.y); o.z = f2bf(v.z); o.w = f2bf(v.w);
    ((ushort4*)d)[off] = o;
}

// ---------------- bf16 MFMA NT GEMM: dbuf LDS + counted vmcnt + XOR swizzle ----------------
// EPI 0: split store: col<2048 -> f32 Cv (ur), col>=2048 -> bf16 C2 (z)  (in_proj)
// EPI 1: softplus(acc+bias)*mask -> f32 store                            (dt_proj)
// EPI 4: split-K partial: seg = bid&3; f32 partial store                 (x_proj)
template <int EPI>
__global__ __launch_bounds__(256) void gemm_bf16(
    const unsigned short* __restrict__ A, int lda,
    const unsigned short* __restrict__ W, int ldw,
    void* __restrict__ Cv, void* __restrict__ C2v, int ldc,
    int M, int N, int K, int nbx,
    const float* __restrict__ bias,
    const float* __restrict__ residual,
    unsigned short* __restrict__ aux,
    const int* __restrict__ lengths) {
    __shared__ __align__(16) unsigned short As[2][128 * 64];
    __shared__ __align__(16) unsigned short Bs[2][128 * 64];
    const int bid = blockIdx.x;
    int bx, by, seg;
    if (EPI == 4) { seg = bid & 3; by = bid >> 2; bx = 0; }
    else          { seg = 0; bx = bid % nbx; by = bid / nbx; }
    const unsigned short* Ap = A + (size_t)seg * 512;
    const unsigned short* Wp = W + (size_t)seg * 512;
    const int row0 = by * 128, col0 = bx * 128;
    const int t = threadIdx.x;

    const int len0 = lengths[row0 >> 11];
    if ((row0 & (LSEQ - 1)) >= len0) return;

    const int lane = t & 63;
    const int w = t >> 6;
    const int wr = w >> 1, wc = w & 1;

    f32x4 acc[4][4];
#pragma unroll
    for (int m = 0; m < 4; ++m)
#pragma unroll
        for (int n = 0; n < 4; ++n) acc[m][n] = f32x4{0.f, 0.f, 0.f, 0.f};

    const int rA = lane & 15;
    const int kH = (lane >> 4) << 3;
    const int NT = K >> 6;
    const int swzR = (rA & 7) << 3;

    auto STAGE = [&](int sel, int k0) {
#pragma unroll
        for (int it = 0; it < 4; ++it) {
            int c = it * 256 + t;
            int r = c >> 3;
            int cc = ((c & 7) ^ (r & 7)) << 3;
            gload_lds16(Ap + (size_t)(row0 + r) * lda + k0 + cc, &As[sel][c << 3]);
            int wrow = col0 + r; if (wrow >= N) wrow = N - 1;
            gload_lds16(Wp + (size_t)wrow * ldw + k0 + cc, &Bs[sel][c << 3]);
        }
    };

    STAGE(0, 0);
    for (int kt = 0; kt < NT; ++kt) {
        const int cur = kt & 1;
        if (kt + 1 < NT) STAGE(cur ^ 1, (kt + 1) << 6);
        __builtin_amdgcn_sched_barrier(0);
        if (kt + 1 < NT) { asm volatile("s_waitcnt vmcnt(8)" ::: "memory"); }
        else             { asm volatile("s_waitcnt vmcnt(0)" ::: "memory"); }
        __builtin_amdgcn_sched_barrier(0);
        __builtin_amdgcn_s_barrier();
        __builtin_amdgcn_sched_barrier(0);
#pragma unroll
        for (int ks = 0; ks < 2; ++ks) {
            const int kkS = (ks * 32 + kH) ^ swzR;
            bf16x8 af[4], bfr[4];
#pragma unroll
            for (int m = 0; m < 4; ++m)
                af[m] = *(const bf16x8*)&As[cur][(wr * 64 + m * 16 + rA) * 64 + kkS];
#pragma unroll
            for (int n = 0; n < 4; ++n)
                bfr[n] = *(const bf16x8*)&Bs[cur][(wc * 64 + n * 16 + rA) * 64 + kkS];
#pragma unroll
            for (int m = 0; m < 4; ++m)
#pragma unroll
                for (int n = 0; n < 4; ++n)
                    acc[m][n] = __builtin_amdgcn_mfma_f32_16x16x32_bf16(
                        af[m], bfr[n], acc[m][n], 0, 0, 0);
        }
        __builtin_amdgcn_sched_barrier(0);
        asm volatile("s_waitcnt lgkmcnt(0)" ::: "memory");
        __builtin_amdgcn_s_barrier();
        __builtin_amdgcn_sched_barrier(0);
    }

    const int cl = lane & 15, rg = lane >> 4;
#pragma unroll
    for (int m = 0; m < 4; ++m) {
#pragma unroll
        for (int j = 0; j < 4; ++j) {
            const int row = row0 + wr * 64 + m * 16 + rg * 4 + j;
            float msk = 1.f;
            if (EPI == 1) {
                msk = ((row & (LSEQ - 1)) < len0) ? 1.f : 0.f;
            }
#pragma unroll
            for (int n = 0; n < 4; ++n) {
                const int col = col0 + wc * 64 + n * 16 + cl;
                float v = acc[m][n][j];
                if (EPI == 0) {
                    if (col < DINNER) ((float*)Cv)[(size_t)row * DINNER + col] = v;
                    else ((unsigned short*)C2v)[(size_t)row * DINNER + col - DINNER] = f2bf(v);
                } else if (EPI == 1) {
                    v += bias[col];
                    v = (v > 20.f) ? v : log1pf(__expf(v));
                    ((float*)Cv)[(size_t)row * ldc + col] = v * msk;
                } else if (EPI == 4) {
                    if (col < 96)
                        ((float*)Cv)[(size_t)seg * M * 96 + (size_t)row * 96 + col] = v;
                }
            }
        }
    }
}

// ---------------- out_proj: intra-block K-split GEMM (8 waves, 2 K-groups) ----------------
// 128x128 tile, K=2048 split as 2x1024 across wave-groups; sbuf 64KB; LDS reused
// post-loop as the f32 cross-group reduction buffer. Epilogue: residual + mask.
__global__ __launch_bounds__(512) void gemm_out_ks(
    const unsigned short* __restrict__ A, int lda,   // y (u_bf), 2048
    const unsigned short* __restrict__ W, int ldw,   // w_out, 2048
    float* __restrict__ C, int ldc,                  // out, 1024
    const float* __restrict__ residual,
    const int* __restrict__ lengths) {
    __shared__ __align__(16) unsigned short As[2][128 * 64];   // [group][tile] 32KB
    __shared__ __align__(16) unsigned short Bs[2][128 * 64];   // 32KB
    const int bid = blockIdx.x;
    const int bx = bid & 7, by = bid >> 3;
    const int row0 = by * 128, col0 = bx * 128;
    const int t = threadIdx.x;

    const int len0 = lengths[row0 >> 11];
    if ((row0 & (LSEQ - 1)) >= len0) {
        // fully-masked tile: out = residual (4096 float4 over 512 threads)
#pragma unroll
        for (int i = 0; i < 8; ++i) {
            int lin = i * 512 + t;
            int r = lin >> 5, c = (lin & 31) << 2;
            *(float4*)(C + (size_t)(row0 + r) * ldc + col0 + c) =
                *(const float4*)(residual + (size_t)(row0 + r) * ldc + col0 + c);
        }
        return;
    }

    const int tg = t & 255;            // thread within K-group
    const int lane = t & 63;
    const int w = t >> 6;              // 0..7
    const int seg = w >> 2;            // K-group
    const int wg = w & 3;              // wave within group
    const int wr = wg >> 1, wc = wg & 1;
    const unsigned short* Ap = A + (size_t)seg * 1024;
    const unsigned short* Wp = W + (size_t)seg * 1024;

    f32x4 acc[4][4];
#pragma unroll
    for (int m = 0; m < 4; ++m)
#pragma unroll
        for (int n = 0; n < 4; ++n) acc[m][n] = f32x4{0.f, 0.f, 0.f, 0.f};

    const int rA = lane & 15;
    const int kH = (lane >> 4) << 3;
    const int swzR = (rA & 7) << 3;

    for (int kt = 0; kt < 16; ++kt) {
        // each group's 256 threads stage its own 128x64 A/B pair
#pragma unroll
        for (int it = 0; it < 4; ++it) {
            int c = it * 256 + tg;
            int r = c >> 3;
            int cc = ((c & 7) ^ (r & 7)) << 3;
            gload_lds16(Ap + (size_t)(row0 + r) * lda + (kt << 6) + cc, &As[seg][c << 3]);
            gload_lds16(Wp + (size_t)(col0 + r) * ldw + (kt << 6) + cc, &Bs[seg][c << 3]);
        }
        __builtin_amdgcn_sched_barrier(0);
        asm volatile("s_waitcnt vmcnt(0)" ::: "memory");
        __builtin_amdgcn_sched_barrier(0);
        __builtin_amdgcn_s_barrier();
        __builtin_amdgcn_sched_barrier(0);
#pragma unroll
        for (int ks = 0; ks < 2; ++ks) {
            const int kkS = (ks * 32 + kH) ^ swzR;
            bf16x8 af[4], bfr[4];
#pragma unroll
            for (int m = 0; m < 4; ++m)
                af[m] = *(const bf16x8*)&As[seg][(wr * 64 + m * 16 + rA) * 64 + kkS];
#pragma unroll
            for (int n = 0; n < 4; ++n)
                bfr[n] = *(const bf16x8*)&Bs[seg][(wc * 64 + n * 16 + rA) * 64 + kkS];
#pragma unroll
            for (int m = 0; m < 4; ++m)
#pragma unroll
                for (int n = 0; n < 4; ++n)
                    acc[m][n] = __builtin_amdgcn_mfma_f32_16x16x32_bf16(
                        af[m], bfr[n], acc[m][n], 0, 0, 0);
        }
        __builtin_amdgcn_sched_barrier(0);
        asm volatile("s_waitcnt lgkmcnt(0)" ::: "memory");
        __builtin_amdgcn_s_barrier();
        __builtin_amdgcn_sched_barrier(0);
    }

    // cross-group reduction: staging LDS (64KB) is dead -> f32 exchange buffer.
    // sRed[idx*256 + tg]: seg1 thread tg and seg0 thread tg own identical output coords.
    float* sRed = (float*)&As[0][0];
    if (seg == 1) {
#pragma unroll
        for (int m = 0; m < 4; ++m)
#pragma unroll
            for (int n = 0; n < 4; ++n)
#pragma unroll
                for (int j = 0; j < 4; ++j)
                    sRed[((m * 4 + n) * 4 + j) * 256 + tg] = acc[m][n][j];
    }
    __syncthreads();
    if (seg == 0) {
        const int cl = lane & 15, rg = lane >> 4;
#pragma unroll
        for (int m = 0; m < 4; ++m) {
#pragma unroll
            for (int j = 0; j < 4; ++j) {
                const int row = row0 + wr * 64 + m * 16 + rg * 4 + j;
                const float msk = ((row & (LSEQ - 1)) < len0) ? 1.f : 0.f;
#pragma unroll
                for (int n = 0; n < 4; ++n) {
                    const int col = col0 + wc * 64 + n * 16 + cl;
                    float v = acc[m][n][j] + sRed[((m * 4 + n) * 4 + j) * 256 + tg];
                    C[(size_t)row * ldc + col] =
                        residual[(size_t)row * ldc + col] + msk * v;
                }
            }
        }
    }
}

// ---------------- x_proj split-K reduce: sum 4 partials -> dtr bf16 + xdbl f32 ----------------
__global__ __launch_bounds__(384) void xred_k(const float* __restrict__ P,
                                              const int* __restrict__ lengths,
                                              unsigned short* __restrict__ dtr,
                                              float* __restrict__ xdbl) {
    const int t = threadIdx.x;
    const int row = blockIdx.x * 4 + t / 96;
    const int col = t % 96;
    const int b = row >> 11, l = row & (LSEQ - 1);
    const int lenUp = (lengths[b] + CH - 1) & ~(CH - 1);
    if (l >= lenUp) return;
    const size_t SEG = (size_t)8192 * 96;
    const size_t idx = (size_t)row * 96 + col;
    float v = P[idx] + P[idx + SEG] + P[idx + 2 * SEG] + P[idx + 3 * SEG];
    if (col < 64) dtr[(size_t)row * 64 + col] = f2bf(v);
    else xdbl[idx] = v;
}

// ---------------- causal depthwise conv (K=4) + SiLU + mask -> bf16 ----------------
__global__ __launch_bounds__(256) void conv_silu_k(const float* __restrict__ ur,
                                                   const float* __restrict__ cw,
                                                   const int* __restrict__ lengths,
                                                   unsigned short* __restrict__ u) {
    const int g = blockIdx.x;              // NB * 512
    const int b = g >> 9;
    const int rem = g & 511;
    const int l0 = (rem >> 1) << 3;
    const int d4 = (rem & 1) * 1024 + threadIdx.x * 4;
    const int len = lengths[b];
    const size_t rb = (size_t)b * LSEQ;
    if (l0 >= len) {
        const int lenUp = (len + CH - 1) & ~(CH - 1);
        if (l0 < lenUp) {
            ushort4 z4 = {0, 0, 0, 0};
#pragma unroll
            for (int i = 0; i < 8; ++i)
                *(ushort4*)(u + (rb + l0 + i) * DINNER + d4) = z4;
        }
        return;
    }
    float4 wq[4];
#pragma unroll
    for (int c = 0; c < 4; ++c) wq[c] = *(const float4*)(cw + 4 * (d4 + c));
    const float4 zero4 = {0.f, 0.f, 0.f, 0.f};
    float4 xm3 = (l0 - 3 >= 0 && l0 - 3 < len) ? *(const float4*)(ur + (rb + l0 - 3) * DINNER + d4) : zero4;
    float4 xm2 = (l0 - 2 >= 0 && l0 - 2 < len) ? *(const float4*)(ur + (rb + l0 - 2) * DINNER + d4) : zero4;
    float4 xm1 = (l0 - 1 >= 0 && l0 - 1 < len) ? *(const float4*)(ur + (rb + l0 - 1) * DINNER + d4) : zero4;
#pragma unroll
    for (int i = 0; i < 8; ++i) {
        const int l = l0 + i;
        const bool act = l < len;
        float4 x0 = act ? *(const float4*)(ur + (rb + l) * DINNER + d4) : zero4;
        float a0 = wq[0].x * xm3.x + wq[0].y * xm2.x + wq[0].z * xm1.x + wq[0].w * x0.x;
        float a1 = wq[1].x * xm3.y + wq[1].y * xm2.y + wq[1].z * xm1.y + wq[1].w * x0.y;
        float a2 = wq[2].x * xm3.z + wq[2].y * xm2.z + wq[2].z * xm1.z + wq[2].w * x0.z;
        float a3 = wq[3].x * xm3.w + wq[3].y * xm2.w + wq[3].z * xm1.w + wq[3].w * x0.w;
        ushort4 ov;
        ov.x = f2bf(act ? siluf(a0) : 0.f);
        ov.y = f2bf(act ? siluf(a1) : 0.f);
        ov.z = f2bf(act ? siluf(a2) : 0.f);
        ov.w = f2bf(act ? siluf(a3) : 0.f);
        *(ushort4*)(u + (rb + l) * DINNER + d4) = ov;
        xm3 = xm2; xm2 = xm1; xm1 = x0;
    }
}

// ---------------- scan phase 1 (4 states/lane, dbuf + register prefetch) ----------------
__global__ __launch_bounds__(256) void scan_p1(const float* __restrict__ dlt,
                                               const unsigned short* __restrict__ uy,
                                               const float* __restrict__ xdbl,
                                               const float* __restrict__ A_log,
                                               const int* __restrict__ lengths,
                                               float* __restrict__ hloc,
                                               float* __restrict__ sumd) {
    __shared__ float2 sDU[2][STT][SCB];   // 16 KB
    __shared__ float  sB[2][STT][16];     // 2 KB
    const int t = threadIdx.x;
    const int s = blockIdx.x >> 7;
    const int g = blockIdx.x & 127;
    const int b = g >> 5;
    const int d0 = (g & 31) * SCB;
    const int ch = t >> 2, q = t & 3;
    const int d = d0 + ch;
    const size_t hbase = ((size_t)(b * 128 + (d >> 4)) * SCH + s) * 256 + (size_t)(d & 15) * 16 + q * 4;
    if (s * CH >= lengths[b]) {          // fully masked chunk: exact identity
        *(float4*)(hloc + hbase) = float4{0.f, 0.f, 0.f, 0.f};
        if (q == 0) sumd[((b * 128 + (d >> 4)) * SCH + s) * 16 + (d & 15)] = 0.f;
        return;
    }
    const float Av0 = -__expf(A_log[d * NST + q * 4 + 0]) * 1.44269504f;
    const float Av1 = -__expf(A_log[d * NST + q * 4 + 1]) * 1.44269504f;
    const float Av2_ = -__expf(A_log[d * NST + q * 4 + 2]) * 1.44269504f;
    const float Av3 = -__expf(A_log[d * NST + q * 4 + 3]) * 1.44269504f;
    float h0 = 0.f, h1 = 0.f, h2 = 0.f, h3 = 0.f, sd = 0.f;
    const size_t base = (size_t)b * LSEQ + (size_t)s * CH;
    const int r = t >> 4, c4 = (t & 15) << 2, nn = t & 15;

    size_t row = base + r;
    float4 dv = *(const float4*)(dlt + row * DINNER + d0 + c4);
    ushort4 uv = *(const ushort4*)(uy + row * DINNER + d0 + c4);
    float bv = xdbl[row * 96 + 64 + nn];

    for (int l0 = 0; l0 < CH; l0 += STT) {
        const int cur = (l0 >> 4) & 1;
        sDU[cur][r][c4 + 0] = float2{dv.x, dv.x * bf2f(uv.x)};
        sDU[cur][r][c4 + 1] = float2{dv.y, dv.y * bf2f(uv.y)};
        sDU[cur][r][c4 + 2] = float2{dv.z, dv.z * bf2f(uv.z)};
        sDU[cur][r][c4 + 3] = float2{dv.w, dv.w * bf2f(uv.w)};
        sB[cur][r][nn] = bv;
        if (l0 + STT < CH) {
            row = base + l0 + STT + r;
            dv = *(const float4*)(dlt + row * DINNER + d0 + c4);
            uv = *(const ushort4*)(uy + row * DINNER + d0 + c4);
            bv = xdbl[row * 96 + 64 + nn];
        }
        __syncthreads();
#pragma unroll
        for (int r2 = 0; r2 < STT; ++r2) {
            float2 du = sDU[cur][r2][ch];
            float4 bb = *(const float4*)&sB[cur][r2][q * 4];
            sd += du.x;
            h0 = fmaf(__builtin_amdgcn_exp2f(du.x * Av0),  h0, du.y * bb.x);
            h1 = fmaf(__builtin_amdgcn_exp2f(du.x * Av1),  h1, du.y * bb.y);
            h2 = fmaf(__builtin_amdgcn_exp2f(du.x * Av2_), h2, du.y * bb.z);
            h3 = fmaf(__builtin_amdgcn_exp2f(du.x * Av3),  h3, du.y * bb.w);
        }
    }
    *(float4*)(hloc + hbase) = float4{h0, h1, h2, h3};
    if (q == 0) sumd[((b * 128 + (d >> 4)) * SCH + s) * 16 + (d & 15)] = sd;
}

// ---------------- scan phase 2: sequential chunk fix-up + h_last (unchanged) ----------------
__global__ __launch_bounds__(256) void scan_p2(const float* __restrict__ hloc,
                                               const float* __restrict__ sumd,
                                               const float* __restrict__ A_log,
                                               float* __restrict__ hin,
                                               float* __restrict__ out_h) {
    const int t = threadIdx.x;
    const int bd = blockIdx.x;
    const int b = bd >> 7;
    const int d = ((bd & 127) << 4) + (t >> 4);
    const int n = t & 15;
    const float Av2 = -__expf(A_log[d * NST + n]) * 1.44269504f;
    float h = 0.f;
#pragma unroll
    for (int s = 0; s < SCH; ++s) {
        const size_t idx = ((size_t)bd * SCH + s) * 256 + t;
        hin[idx] = h;
        float P = __builtin_amdgcn_exp2f(Av2 * sumd[(bd * SCH + s) * 16 + (t >> 4)]);
        h = fmaf(P, h, hloc[idx]);
    }
    out_h[((size_t)(b * DINNER + d)) * NST + n] = h;
}

// ---------------- scan phase 3: 4 states/lane, dbuf, 1 barrier/tile, deferred writeout ----------------
__global__ __launch_bounds__(256) void scan_p3(const float* __restrict__ dlt,
                                               const unsigned short* __restrict__ zb,
                                               unsigned short* uy,
                                               const float* __restrict__ xdbl,
                                               const float* __restrict__ A_log,
                                               const float* __restrict__ D_skip,
                                               const int* __restrict__ lengths,
                                               const float* __restrict__ hin) {
    __shared__ float2 sDU[2][STT][SCB];   // 16 KB
    __shared__ float  sBC[2][STT][32];    // 4 KB
    __shared__ float  sY[2][STT][SCB];    // 8 KB
    __shared__ float  sDk[SCB];
    const int t = threadIdx.x;
    const int s = blockIdx.x >> 7;
    const int g = blockIdx.x & 127;
    const int b = g >> 5;
    const int d0 = (g & 31) * SCB;
    const int ch = t >> 2, q = t & 3;
    const int d = d0 + ch;
    if (s * CH >= lengths[b]) return;
    if (t < SCB) sDk[t] = D_skip[d0 + t];
    const float Av0 = -__expf(A_log[d * NST + q * 4 + 0]) * 1.44269504f;
    const float Av1 = -__expf(A_log[d * NST + q * 4 + 1]) * 1.44269504f;
    const float Av2_ = -__expf(A_log[d * NST + q * 4 + 2]) * 1.44269504f;
    const float Av3 = -__expf(A_log[d * NST + q * 4 + 3]) * 1.44269504f;
    const size_t hbase = ((size_t)(b * 128 + (d >> 4)) * SCH + s) * 256 + (size_t)(d & 15) * 16 + q * 4;
    float4 hv = *(const float4*)(hin + hbase);
    float h0 = hv.x, h1 = hv.y, h2 = hv.z, h3 = hv.w;
    const size_t base = (size_t)b * LSEQ + (size_t)s * CH;
    const int r = t >> 4, c4 = (t & 15) << 2, n2 = (t & 15) << 1;

    size_t row = base + r;
    float4 dv = *(const float4*)(dlt + row * DINNER + d0 + c4);
    ushort4 uv = *(const ushort4*)(uy + row * DINNER + d0 + c4);
    ushort4 zz = *(const ushort4*)(zb + row * DINNER + d0 + c4);
    float2 bc = *(const float2*)(xdbl + row * 96 + 64 + n2);
    ushort4 uvW0, zzW0, uvW1, zzW1;
    size_t rowW0 = 0, rowW1 = 0;

#define P3_STAGE(CUR, UVW, ZZW, ROWW)                          \
    sDU[CUR][r][c4 + 0] = float2{dv.x, dv.x * bf2f(uv.x)};     \
    sDU[CUR][r][c4 + 1] = float2{dv.y, dv.y * bf2f(uv.y)};     \
    sDU[CUR][r][c4 + 2] = float2{dv.z, dv.z * bf2f(uv.z)};     \
    sDU[CUR][r][c4 + 3] = float2{dv.w, dv.w * bf2f(uv.w)};     \
    sBC[CUR][r][n2 + 0] = bc.x; sBC[CUR][r][n2 + 1] = bc.y;    \
    UVW = uv; ZZW = zz; ROWW = row;

#define P3_PREFETCH(L0N)                                                \
    if ((L0N) < CH) {                                                   \
        row = base + (L0N) + r;                                         \
        dv = *(const float4*)(dlt + row * DINNER + d0 + c4);            \
        uv = *(const ushort4*)(uy + row * DINNER + d0 + c4);            \
        zz = *(const ushort4*)(zb + row * DINNER + d0 + c4);            \
        bc = *(const float2*)(xdbl + row * 96 + 64 + n2);               \
    }

#define P3_COMPUTE(CUR)                                                                    \
    _Pragma("unroll")                                                                      \
    for (int r2 = 0; r2 < STT; ++r2) {                                                     \
        float2 du = sDU[CUR][r2][ch];                                                      \
        float4 bb = *(const float4*)&sBC[CUR][r2][q * 4];                                  \
        float4 cc = *(const float4*)&sBC[CUR][r2][16 + q * 4];                             \
        float y;                                                                           \
        h0 = fmaf(__builtin_amdgcn_exp2f(du.x * Av0),  h0, du.y * bb.x); y = h0 * cc.x;    \
        h1 = fmaf(__builtin_amdgcn_exp2f(du.x * Av1),  h1, du.y * bb.y); y = fmaf(h1, cc.y, y); \
        h2 = fmaf(__builtin_amdgcn_exp2f(du.x * Av2_), h2, du.y * bb.z); y = fmaf(h2, cc.z, y); \
        h3 = fmaf(__builtin_amdgcn_exp2f(du.x * Av3),  h3, du.y * bb.w); y = fmaf(h3, cc.w, y); \
        y += dpp_qp<0x39>(y);                                                              \
        y += dpp_qp<0x4E>(y);                                                              \
        if (q == 0) sY[CUR][r2][ch] = y;                                                   \
    }

#define P3_WRITEOUT(CUR, UVW, ZZW, ROWW) {                                        \
        float4 yv = *(const float4*)&sY[CUR][r][c4];                              \
        float4 kk = *(const float4*)&sDk[c4];                                     \
        ushort4 ov;                                                               \
        ov.x = f2bf(fmaf(bf2f(UVW.x), kk.x, yv.x) * siluf(bf2f(ZZW.x)));          \
        ov.y = f2bf(fmaf(bf2f(UVW.y), kk.y, yv.y) * siluf(bf2f(ZZW.y)));          \
        ov.z = f2bf(fmaf(bf2f(UVW.z), kk.z, yv.z) * siluf(bf2f(ZZW.z)));          \
        ov.w = f2bf(fmaf(bf2f(UVW.w), kk.w, yv.w) * siluf(bf2f(ZZW.w)));          \
        *(ushort4*)(uy + (ROWW) * DINNER + d0 + c4) = ov;                         \
    }

    for (int ii = 0; ii < 4; ++ii) {
        const int l0a = ii * 32;
        P3_STAGE(0, uvW0, zzW0, rowW0)
        P3_PREFETCH(l0a + 16)
        __syncthreads();
        if (ii > 0) P3_WRITEOUT(1, uvW1, zzW1, rowW1)
        P3_COMPUTE(0)
        P3_STAGE(1, uvW1, zzW1, rowW1)
        P3_PREFETCH(l0a + 32)
        __syncthreads();
        P3_WRITEOUT(0, uvW0, zzW0, rowW0)
        P3_COMPUTE(1)
    }
    __syncthreads();
    P3_WRITEOUT(1, uvW1, zzW1, rowW1)

#undef P3_STAGE
#undef P3_PREFETCH
#undef P3_COMPUTE
#undef P3_WRITEOUT
}

extern "C" void kernel_launch(void* const* d_in, const int* in_sizes, int n_in,
                              void* d_out, int out_size, void* d_ws, size_t ws_size,
                              hipStream_t stream) {
    const float* hs        = (const float*)d_in[0];
    const int*   lengths   = (const int*)d_in[1];
    const float* norm_w    = (const float*)d_in[2];
    const float* in_proj_w = (const float*)d_in[3];
    const float* conv_w    = (const float*)d_in[4];
    const float* x_proj_w  = (const float*)d_in[5];
    const float* dt_proj_w = (const float*)d_in[6];
    const float* dt_proj_b = (const float*)d_in[7];
    const float* A_log     = (const float*)d_in[8];
    const float* D_skip    = (const float*)d_in[9];
    const float* out_proj_w= (const float*)d_in[10];

    float* out = (float*)d_out;

    const int M = NB * LSEQ;                                            // 8192
    float* ur = (float*)d_ws;                                           // 8192x2048 f32: u_raw -> dlt
    unsigned short* zb = (unsigned short*)(ur + (size_t)M * DINNER);    // 8192x2048 bf16: z
    unsigned short* u_bf = zb + (size_t)M * DINNER;                     // 8192x2048 bf16: u -> y
    float* xdbl = (float*)(u_bf + (size_t)M * DINNER);                  // 8192x96 f32
    unsigned short* w_in  = (unsigned short*)(xdbl + (size_t)M * 96);   // 4096x1024
    unsigned short* w_out = w_in + (size_t)4096 * 1024;                 // 1024x2048
    unsigned short* w_x   = w_out + (size_t)1024 * 2048;                // 96x2048
    unsigned short* w_dt  = w_x + (size_t)96 * 2048;                    // 2048x64
    unsigned short* dtr   = w_dt + (size_t)2048 * 64;                   // 8192x64 bf16
    float* hin            = (float*)(dtr + (size_t)M * 64);             // 512*16*256 f32 (8MB)
    float* xpart          = hin + (size_t)NBD * SCH * 256;              // 4x8192x96 f32 (12.6MB)
    unsigned short* xn_bf = u_bf;          // alias: dead once conv overwrites it
    float* dlt  = ur;                      // alias: ur dead after conv
    float* hloc = (float*)w_in;            // alias: w_in dead after in_proj
    float* sumd = (float*)dtr;             // alias: dtr dead after dt_proj

    // 1. fused RMSNorm->bf16 + fused weight conversions
    rmsnorm_cvt_k<<<M, 256, 0, stream>>>(hs, norm_w, xn_bf);
    cvt_all_k<<<6464, 256, 0, stream>>>(in_proj_w, out_proj_w, x_proj_w, dt_proj_w,
                                        w_in, w_out, w_x, w_dt);

    // 2. in_proj (bf16 MFMA dbuf+swz, row-skip): ur f32 | z bf16
    gemm_bf16<0><<<(4096 / 128) * (M / 128), 256, 0, stream>>>(
        xn_bf, DMODEL, w_in, DMODEL, ur, zb, DINNER, M, 4096, DMODEL, 4096 / 128,
        nullptr, nullptr, nullptr, lengths);

    // 3. causal depthwise conv + silu + mask -> u (bf16)
    conv_silu_k<<<NB * 512, 256, 0, stream>>>(ur, conv_w, lengths, u_bf);

    // 4. x_proj split-K4 (grid 256) -> partials; reduce -> dtr bf16 + xdbl f32
    gemm_bf16<4><<<4 * (M / 128), 256, 0, stream>>>(
        u_bf, DINNER, w_x, DINNER, xpart, nullptr, 96, M, 96, 512, 1,
        nullptr, nullptr, nullptr, lengths);
    xred_k<<<M / 4, 384, 0, stream>>>(xpart, lengths, dtr, xdbl);

    // 5. dt_proj (bf16 MFMA dbuf+swz, row-skip) + softplus + mask -> delta f32
    gemm_bf16<1><<<(DINNER / 128) * (M / 128), 256, 0, stream>>>(
        dtr, 64, w_dt, 64, dlt, nullptr, DINNER, M, DINNER, 64, DINNER / 128,
        dt_proj_b, nullptr, nullptr, lengths);

    // 6. chunked selective scan (3 phases, chunk-skip, dbuf+prefetch)
    {
        float* hlast = out + (size_t)M * DMODEL;
        scan_p1<<<SCH * 128, 256, 0, stream>>>(dlt, u_bf, xdbl, A_log, lengths, hloc, sumd);
        scan_p2<<<NBD, 256, 0, stream>>>(hloc, sumd, A_log, hin, hlast);
        scan_p3<<<SCH * 128, 256, 0, stream>>>(dlt, zb, u_bf, xdbl, A_log, D_skip, lengths, hin);
    }

    // 7. out_proj: intra-block K-split (8 waves, 2x K=1024) + residual + mask
    gemm_out_ks<<<(DMODEL / 128) * (M / 128), 512, 0, stream>>>(
        u_bf, DINNER, w_out, DINNER, out, DMODEL, hs, lengths);
}

// Round 18
// 261.006 us; speedup vs baseline: 1.3588x; 1.0647x over previous
//
#include <hip/hip_runtime.h>
#include <cstdint>
#include <cstddef>

#define LSEQ 2048
#define NB   4
#define DMODEL 1024
#define DINNER 2048
#define NST  16
#define CH   128   // scan chunk length == GEMM tile height
#define SCH  (LSEQ / CH)   // 16 chunks
#define NBD  512           // NB * DINNER/16 (p2 layout)
#define STT  16    // scan steps per LDS tile
#define SCB  64    // channels per scan block (4 lanes each)

typedef short bf16x8 __attribute__((ext_vector_type(8)));
typedef float f32x4  __attribute__((ext_vector_type(4)));

__device__ __forceinline__ float siluf(float x) { return x / (1.f + __expf(-x)); }

__device__ __forceinline__ unsigned short f2bf(float f) {
    unsigned u = __float_as_uint(f);
    u += 0x7FFF + ((u >> 16) & 1);     // round-to-nearest-even
    return (unsigned short)(u >> 16);
}
__device__ __forceinline__ float bf2f(unsigned short h) {
    return __uint_as_float(((unsigned)h) << 16);
}
__device__ __forceinline__ void gload_lds16(const void* g, void* l) {
    __builtin_amdgcn_global_load_lds(
        (const __attribute__((address_space(1))) unsigned int*)g,
        (__attribute__((address_space(3))) unsigned int*)l, 16, 0, 0);
}

// DPP quad_perm add helpers: rotate within 4-lane quad
template <int CTRL>
__device__ __forceinline__ float dpp_qp(float v) {
    return __int_as_float(__builtin_amdgcn_update_dpp(
        0, __float_as_int(v), CTRL, 0xf, 0xf, false));
}

// ---------------- fused RMSNorm + bf16 convert ----------------
__global__ __launch_bounds__(256) void rmsnorm_cvt_k(const float* __restrict__ x,
                                                     const float* __restrict__ nw,
                                                     unsigned short* __restrict__ o) {
    int row = blockIdx.x, t = threadIdx.x;
    float4 v = ((const float4*)(x + (size_t)row * DMODEL))[t];
    float s = v.x * v.x + v.y * v.y + v.z * v.z + v.w * v.w;
#pragma unroll
    for (int m = 32; m >= 1; m >>= 1) s += __shfl_xor(s, m);
    __shared__ float wsum[4];
    __shared__ float sinv;
    if ((t & 63) == 0) wsum[t >> 6] = s;
    __syncthreads();
    if (t == 0) {
        float tot = wsum[0] + wsum[1] + wsum[2] + wsum[3];
        sinv = rsqrtf(tot * (1.f / (float)DMODEL) + 1e-6f);
    }
    __syncthreads();
    float iv = sinv;
    float4 w = ((const float4*)nw)[t];
    ushort4 ov;
    ov.x = f2bf(v.x * iv * w.x); ov.y = f2bf(v.y * iv * w.y);
    ov.z = f2bf(v.z * iv * w.z); ov.w = f2bf(v.w * iv * w.w);
    ((ushort4*)(o + (size_t)row * DMODEL))[t] = ov;
}

// ---------------- fused weight conversions (4 matrices, 1 launch) ----------------
__global__ __launch_bounds__(256) void cvt_all_k(const float* __restrict__ s0, const float* __restrict__ s1,
                                                 const float* __restrict__ s2, const float* __restrict__ s3,
                                                 unsigned short* __restrict__ q0, unsigned short* __restrict__ q1,
                                                 unsigned short* __restrict__ q2, unsigned short* __restrict__ q3) {
    int i = blockIdx.x * 256 + threadIdx.x;
    const float* s; unsigned short* d; int off;
    if (i < 1048576)       { s = s0; d = q0; off = i; }
    else if (i < 1572864)  { s = s1; d = q1; off = i - 1048576; }
    else if (i < 1622016)  { s = s2; d = q2; off = i - 1572864; }
    else if (i < 1654784)  { s = s3; d = q3; off = i - 1622016; }
    else return;
    float4 v = ((const float4*)s)[off];
    ushort4 o;
    o.x = f2bf(v.x); o.y = f2bf(v.y); o.z = f2bf(v.z); o.w = f2bf(v.w);
    ((ushort4*)d)[off] = o;
}

// ---------------- bf16 MFMA NT GEMM: dbuf+swz K-loop, LDS-staged vectorized epilogue ----------------
// EPI 0: col<2048 -> f32 Cv (ur), col>=2048 -> bf16 C2 (z)  (in_proj; tile-uniform branch)
// EPI 1: softplus(acc+bias)*mask -> f32                      (dt_proj)
// EPI 4: split-K partial (seg=bid&3) -> f32 partial          (x_proj)
template <int EPI>
__global__ __launch_bounds__(256) void gemm_bf16(
    const unsigned short* __restrict__ A, int lda,
    const unsigned short* __restrict__ W, int ldw,
    void* __restrict__ Cv, void* __restrict__ C2v, int ldc,
    int M, int N, int K, int nbx,
    const float* __restrict__ bias,
    const float* __restrict__ residual,
    unsigned short* __restrict__ aux,
    const int* __restrict__ lengths) {
    __shared__ __align__(16) unsigned short smem[4][128 * 64];  // A0,A1,B0,B1 = 64KB
    const int bid = blockIdx.x;
    int bx, by, seg;
    if (EPI == 4) { seg = bid & 3; by = bid >> 2; bx = 0; }
    else          { seg = 0; bx = bid % nbx; by = bid / nbx; }
    const unsigned short* Ap = A + (size_t)seg * 512;
    const unsigned short* Wp = W + (size_t)seg * 512;
    const int row0 = by * 128, col0 = bx * 128;
    const int t = threadIdx.x;

    const int len0 = lengths[row0 >> 11];
    if ((row0 & (LSEQ - 1)) >= len0) return;

    const int lane = t & 63;
    const int w = t >> 6;
    const int wr = w >> 1, wc = w & 1;

    f32x4 acc[4][4];
#pragma unroll
    for (int m = 0; m < 4; ++m)
#pragma unroll
        for (int n = 0; n < 4; ++n) acc[m][n] = f32x4{0.f, 0.f, 0.f, 0.f};

    const int rA = lane & 15;
    const int kH = (lane >> 4) << 3;
    const int NT = K >> 6;
    const int swzR = (rA & 7) << 3;

    auto STAGE = [&](int sel, int k0) {
#pragma unroll
        for (int it = 0; it < 4; ++it) {
            int c = it * 256 + t;
            int r = c >> 3;
            int cc = ((c & 7) ^ (r & 7)) << 3;
            gload_lds16(Ap + (size_t)(row0 + r) * lda + k0 + cc, &smem[sel][c << 3]);
            int wrow = col0 + r; if (wrow >= N) wrow = N - 1;
            gload_lds16(Wp + (size_t)wrow * ldw + k0 + cc, &smem[2 + sel][c << 3]);
        }
    };

    STAGE(0, 0);
    for (int kt = 0; kt < NT; ++kt) {
        const int cur = kt & 1;
        if (kt + 1 < NT) STAGE(cur ^ 1, (kt + 1) << 6);
        __builtin_amdgcn_sched_barrier(0);
        if (kt + 1 < NT) { asm volatile("s_waitcnt vmcnt(8)" ::: "memory"); }
        else             { asm volatile("s_waitcnt vmcnt(0)" ::: "memory"); }
        __builtin_amdgcn_sched_barrier(0);
        __builtin_amdgcn_s_barrier();
        __builtin_amdgcn_sched_barrier(0);
#pragma unroll
        for (int ks = 0; ks < 2; ++ks) {
            const int kkS = (ks * 32 + kH) ^ swzR;
            bf16x8 af[4], bfr[4];
#pragma unroll
            for (int m = 0; m < 4; ++m)
                af[m] = *(const bf16x8*)&smem[cur][(wr * 64 + m * 16 + rA) * 64 + kkS];
#pragma unroll
            for (int n = 0; n < 4; ++n)
                bfr[n] = *(const bf16x8*)&smem[2 + cur][(wc * 64 + n * 16 + rA) * 64 + kkS];
#pragma unroll
            for (int m = 0; m < 4; ++m)
#pragma unroll
                for (int n = 0; n < 4; ++n)
                    acc[m][n] = __builtin_amdgcn_mfma_f32_16x16x32_bf16(
                        af[m], bfr[n], acc[m][n], 0, 0, 0);
        }
        __builtin_amdgcn_sched_barrier(0);
        asm volatile("s_waitcnt lgkmcnt(0)" ::: "memory");
        __builtin_amdgcn_s_barrier();
        __builtin_amdgcn_sched_barrier(0);
    }

    // ---- LDS-staged vectorized epilogue (staging LDS is dead after the loop) ----
    float* sC = (float*)smem;                 // 128x128 f32, col XOR-swizzled by ((row&7)<<2)
    const int cl = lane & 15, rg = lane >> 4;
#pragma unroll
    for (int m = 0; m < 4; ++m) {
#pragma unroll
        for (int j = 0; j < 4; ++j) {
            const int rl = wr * 64 + m * 16 + rg * 4 + j;
            const int msw = (rl & 7) << 2;
#pragma unroll
            for (int n = 0; n < 4; ++n) {
                const int cc = wc * 64 + n * 16 + cl;
                sC[rl * 128 + (cc ^ msw)] = acc[m][n][j];
            }
        }
    }
    __syncthreads();
#pragma unroll
    for (int i = 0; i < 16; ++i) {
        const int lin = i * 256 + t;
        const int r = lin >> 5, cc4 = (lin & 31) << 2;
        const int row = row0 + r;
        float4 v = *(const float4*)&sC[r * 128 + (cc4 ^ ((r & 7) << 2))];
        if (EPI == 0) {
            if (col0 < DINNER) {
                *(float4*)((float*)Cv + (size_t)row * DINNER + col0 + cc4) = v;
            } else {
                ushort4 ov;
                ov.x = f2bf(v.x); ov.y = f2bf(v.y); ov.z = f2bf(v.z); ov.w = f2bf(v.w);
                *(ushort4*)((unsigned short*)C2v + (size_t)row * DINNER + col0 - DINNER + cc4) = ov;
            }
        } else if (EPI == 1) {
            const float msk = ((row & (LSEQ - 1)) < len0) ? 1.f : 0.f;
            float4 bb = *(const float4*)(bias + col0 + cc4);
            v.x += bb.x; v.y += bb.y; v.z += bb.z; v.w += bb.w;
            v.x = ((v.x > 20.f) ? v.x : log1pf(__expf(v.x))) * msk;
            v.y = ((v.y > 20.f) ? v.y : log1pf(__expf(v.y))) * msk;
            v.z = ((v.z > 20.f) ? v.z : log1pf(__expf(v.z))) * msk;
            v.w = ((v.w > 20.f) ? v.w : log1pf(__expf(v.w))) * msk;
            *(float4*)((float*)Cv + (size_t)row * ldc + col0 + cc4) = v;
        } else {  // EPI 4: x_proj partial, only cols < 96
            if (cc4 < 96)
                *(float4*)((float*)Cv + (size_t)seg * M * 96 + (size_t)row * 96 + cc4) = v;
        }
    }
}

// ---------------- out_proj: intra-block K-split, LDS reduce + vectorized epilogue ----------------
__global__ __launch_bounds__(512) void gemm_out_ks(
    const unsigned short* __restrict__ A, int lda,   // y (u_bf), 2048
    const unsigned short* __restrict__ W, int ldw,   // w_out, 2048
    float* __restrict__ C, int ldc,                  // out, 1024
    const float* __restrict__ residual,
    const int* __restrict__ lengths) {
    __shared__ __align__(16) unsigned short smem[4][128 * 64];  // [A0,A1(B-group),B0,B1] 64KB
    const int bid = blockIdx.x;
    const int bx = bid & 7, by = bid >> 3;
    const int row0 = by * 128, col0 = bx * 128;
    const int t = threadIdx.x;

    const int len0 = lengths[row0 >> 11];
    if ((row0 & (LSEQ - 1)) >= len0) {
#pragma unroll
        for (int i = 0; i < 8; ++i) {
            int lin = i * 512 + t;
            int r = lin >> 5, c = (lin & 31) << 2;
            *(float4*)(C + (size_t)(row0 + r) * ldc + col0 + c) =
                *(const float4*)(residual + (size_t)(row0 + r) * ldc + col0 + c);
        }
        return;
    }

    const int tg = t & 255;            // thread within K-group
    const int lane = t & 63;
    const int w = t >> 6;              // 0..7
    const int seg = w >> 2;            // K-group
    const int wg = w & 3;              // wave within group
    const int wr = wg >> 1, wc = wg & 1;
    const unsigned short* Ap = A + (size_t)seg * 1024;
    const unsigned short* Wp = W + (size_t)seg * 1024;

    f32x4 acc[4][4];
#pragma unroll
    for (int m = 0; m < 4; ++m)
#pragma unroll
        for (int n = 0; n < 4; ++n) acc[m][n] = f32x4{0.f, 0.f, 0.f, 0.f};

    const int rA = lane & 15;
    const int kH = (lane >> 4) << 3;
    const int swzR = (rA & 7) << 3;

    for (int kt = 0; kt < 16; ++kt) {
#pragma unroll
        for (int it = 0; it < 4; ++it) {
            int c = it * 256 + tg;
            int r = c >> 3;
            int cc = ((c & 7) ^ (r & 7)) << 3;
            gload_lds16(Ap + (size_t)(row0 + r) * lda + (kt << 6) + cc, &smem[seg][c << 3]);
            gload_lds16(Wp + (size_t)(col0 + r) * ldw + (kt << 6) + cc, &smem[2 + seg][c << 3]);
        }
        __builtin_amdgcn_sched_barrier(0);
        asm volatile("s_waitcnt vmcnt(0)" ::: "memory");
        __builtin_amdgcn_sched_barrier(0);
        __builtin_amdgcn_s_barrier();
        __builtin_amdgcn_sched_barrier(0);
#pragma unroll
        for (int ks = 0; ks < 2; ++ks) {
            const int kkS = (ks * 32 + kH) ^ swzR;
            bf16x8 af[4], bfr[4];
#pragma unroll
            for (int m = 0; m < 4; ++m)
                af[m] = *(const bf16x8*)&smem[seg][(wr * 64 + m * 16 + rA) * 64 + kkS];
#pragma unroll
            for (int n = 0; n < 4; ++n)
                bfr[n] = *(const bf16x8*)&smem[2 + seg][(wc * 64 + n * 16 + rA) * 64 + kkS];
#pragma unroll
            for (int m = 0; m < 4; ++m)
#pragma unroll
                for (int n = 0; n < 4; ++n)
                    acc[m][n] = __builtin_amdgcn_mfma_f32_16x16x32_bf16(
                        af[m], bfr[n], acc[m][n], 0, 0, 0);
        }
        __builtin_amdgcn_sched_barrier(0);
        asm volatile("s_waitcnt lgkmcnt(0)" ::: "memory");
        __builtin_amdgcn_s_barrier();
        __builtin_amdgcn_sched_barrier(0);
    }

    // ---- cross-group reduce in dead LDS + vectorized epilogue ----
    float* sC = (float*)smem;                 // 128x128 f32, swizzled
    const int cl = lane & 15, rg = lane >> 4;
    if (seg == 1) {
#pragma unroll
        for (int m = 0; m < 4; ++m)
#pragma unroll
            for (int j = 0; j < 4; ++j) {
                const int rl = wr * 64 + m * 16 + rg * 4 + j;
                const int msw = (rl & 7) << 2;
#pragma unroll
                for (int n = 0; n < 4; ++n) {
                    const int cc = wc * 64 + n * 16 + cl;
                    sC[rl * 128 + (cc ^ msw)] = acc[m][n][j];
                }
            }
    }
    __syncthreads();
    if (seg == 0) {
#pragma unroll
        for (int m = 0; m < 4; ++m)
#pragma unroll
            for (int j = 0; j < 4; ++j) {
                const int rl = wr * 64 + m * 16 + rg * 4 + j;
                const int msw = (rl & 7) << 2;
#pragma unroll
                for (int n = 0; n < 4; ++n) {
                    const int cc = wc * 64 + n * 16 + cl;
                    sC[rl * 128 + (cc ^ msw)] += acc[m][n][j];
                }
            }
    }
    __syncthreads();
#pragma unroll
    for (int i = 0; i < 8; ++i) {
        const int lin = i * 512 + t;
        const int r = lin >> 5, cc4 = (lin & 31) << 2;
        const int row = row0 + r;
        const float msk = ((row & (LSEQ - 1)) < len0) ? 1.f : 0.f;
        float4 v = *(const float4*)&sC[r * 128 + (cc4 ^ ((r & 7) << 2))];
        float4 res = *(const float4*)(residual + (size_t)row * ldc + col0 + cc4);
        float4 o;
        o.x = res.x + msk * v.x; o.y = res.y + msk * v.y;
        o.z = res.z + msk * v.z; o.w = res.w + msk * v.w;
        *(float4*)(C + (size_t)row * ldc + col0 + cc4) = o;
    }
}

// ---------------- x_proj split-K reduce: sum 4 partials -> dtr bf16 + xdbl f32 ----------------
__global__ __launch_bounds__(384) void xred_k(const float* __restrict__ P,
                                              const int* __restrict__ lengths,
                                              unsigned short* __restrict__ dtr,
                                              float* __restrict__ xdbl) {
    const int t = threadIdx.x;
    const int row = blockIdx.x * 4 + t / 96;
    const int col = t % 96;
    const int b = row >> 11, l = row & (LSEQ - 1);
    const int lenUp = (lengths[b] + CH - 1) & ~(CH - 1);
    if (l >= lenUp) return;
    const size_t SEG = (size_t)8192 * 96;
    const size_t idx = (size_t)row * 96 + col;
    float v = P[idx] + P[idx + SEG] + P[idx + 2 * SEG] + P[idx + 3 * SEG];
    if (col < 64) dtr[(size_t)row * 64 + col] = f2bf(v);
    else xdbl[idx] = v;
}

// ---------------- causal depthwise conv (K=4) + SiLU + mask -> bf16 ----------------
__global__ __launch_bounds__(256) void conv_silu_k(const float* __restrict__ ur,
                                                   const float* __restrict__ cw,
                                                   const int* __restrict__ lengths,
                                                   unsigned short* __restrict__ u) {
    const int g = blockIdx.x;              // NB * 512
    const int b = g >> 9;
    const int rem = g & 511;
    const int l0 = (rem >> 1) << 3;
    const int d4 = (rem & 1) * 1024 + threadIdx.x * 4;
    const int len = lengths[b];
    const size_t rb = (size_t)b * LSEQ;
    if (l0 >= len) {
        const int lenUp = (len + CH - 1) & ~(CH - 1);
        if (l0 < lenUp) {
            ushort4 z4 = {0, 0, 0, 0};
#pragma unroll
            for (int i = 0; i < 8; ++i)
                *(ushort4*)(u + (rb + l0 + i) * DINNER + d4) = z4;
        }
        return;
    }
    float4 wq[4];
#pragma unroll
    for (int c = 0; c < 4; ++c) wq[c] = *(const float4*)(cw + 4 * (d4 + c));
    const float4 zero4 = {0.f, 0.f, 0.f, 0.f};
    float4 xm3 = (l0 - 3 >= 0 && l0 - 3 < len) ? *(const float4*)(ur + (rb + l0 - 3) * DINNER + d4) : zero4;
    float4 xm2 = (l0 - 2 >= 0 && l0 - 2 < len) ? *(const float4*)(ur + (rb + l0 - 2) * DINNER + d4) : zero4;
    float4 xm1 = (l0 - 1 >= 0 && l0 - 1 < len) ? *(const float4*)(ur + (rb + l0 - 1) * DINNER + d4) : zero4;
#pragma unroll
    for (int i = 0; i < 8; ++i) {
        const int l = l0 + i;
        const bool act = l < len;
        float4 x0 = act ? *(const float4*)(ur + (rb + l) * DINNER + d4) : zero4;
        float a0 = wq[0].x * xm3.x + wq[0].y * xm2.x + wq[0].z * xm1.x + wq[0].w * x0.x;
        float a1 = wq[1].x * xm3.y + wq[1].y * xm2.y + wq[1].z * xm1.y + wq[1].w * x0.y;
        float a2 = wq[2].x * xm3.z + wq[2].y * xm2.z + wq[2].z * xm1.z + wq[2].w * x0.z;
        float a3 = wq[3].x * xm3.w + wq[3].y * xm2.w + wq[3].z * xm1.w + wq[3].w * x0.w;
        ushort4 ov;
        ov.x = f2bf(act ? siluf(a0) : 0.f);
        ov.y = f2bf(act ? siluf(a1) : 0.f);
        ov.z = f2bf(act ? siluf(a2) : 0.f);
        ov.w = f2bf(act ? siluf(a3) : 0.f);
        *(ushort4*)(u + (rb + l) * DINNER + d4) = ov;
        xm3 = xm2; xm2 = xm1; xm1 = x0;
    }
}

// ---------------- scan phase 1 (4 states/lane, dbuf + register prefetch) ----------------
__global__ __launch_bounds__(256) void scan_p1(const float* __restrict__ dlt,
                                               const unsigned short* __restrict__ uy,
                                               const float* __restrict__ xdbl,
                                               const float* __restrict__ A_log,
                                               const int* __restrict__ lengths,
                                               float* __restrict__ hloc,
                                               float* __restrict__ sumd) {
    __shared__ float2 sDU[2][STT][SCB];   // 16 KB
    __shared__ float  sB[2][STT][16];     // 2 KB
    const int t = threadIdx.x;
    const int s = blockIdx.x >> 7;
    const int g = blockIdx.x & 127;
    const int b = g >> 5;
    const int d0 = (g & 31) * SCB;
    const int ch = t >> 2, q = t & 3;
    const int d = d0 + ch;
    const size_t hbase = ((size_t)(b * 128 + (d >> 4)) * SCH + s) * 256 + (size_t)(d & 15) * 16 + q * 4;
    if (s * CH >= lengths[b]) {          // fully masked chunk: exact identity
        *(float4*)(hloc + hbase) = float4{0.f, 0.f, 0.f, 0.f};
        if (q == 0) sumd[((b * 128 + (d >> 4)) * SCH + s) * 16 + (d & 15)] = 0.f;
        return;
    }
    const float Av0 = -__expf(A_log[d * NST + q * 4 + 0]) * 1.44269504f;
    const float Av1 = -__expf(A_log[d * NST + q * 4 + 1]) * 1.44269504f;
    const float Av2_ = -__expf(A_log[d * NST + q * 4 + 2]) * 1.44269504f;
    const float Av3 = -__expf(A_log[d * NST + q * 4 + 3]) * 1.44269504f;
    float h0 = 0.f, h1 = 0.f, h2 = 0.f, h3 = 0.f, sd = 0.f;
    const size_t base = (size_t)b * LSEQ + (size_t)s * CH;
    const int r = t >> 4, c4 = (t & 15) << 2, nn = t & 15;

    size_t row = base + r;
    float4 dv = *(const float4*)(dlt + row * DINNER + d0 + c4);
    ushort4 uv = *(const ushort4*)(uy + row * DINNER + d0 + c4);
    float bv = xdbl[row * 96 + 64 + nn];

    for (int l0 = 0; l0 < CH; l0 += STT) {
        const int cur = (l0 >> 4) & 1;
        sDU[cur][r][c4 + 0] = float2{dv.x, dv.x * bf2f(uv.x)};
        sDU[cur][r][c4 + 1] = float2{dv.y, dv.y * bf2f(uv.y)};
        sDU[cur][r][c4 + 2] = float2{dv.z, dv.z * bf2f(uv.z)};
        sDU[cur][r][c4 + 3] = float2{dv.w, dv.w * bf2f(uv.w)};
        sB[cur][r][nn] = bv;
        if (l0 + STT < CH) {
            row = base + l0 + STT + r;
            dv = *(const float4*)(dlt + row * DINNER + d0 + c4);
            uv = *(const ushort4*)(uy + row * DINNER + d0 + c4);
            bv = xdbl[row * 96 + 64 + nn];
        }
        __syncthreads();
#pragma unroll
        for (int r2 = 0; r2 < STT; ++r2) {
            float2 du = sDU[cur][r2][ch];
            float4 bb = *(const float4*)&sB[cur][r2][q * 4];
            sd += du.x;
            h0 = fmaf(__builtin_amdgcn_exp2f(du.x * Av0),  h0, du.y * bb.x);
            h1 = fmaf(__builtin_amdgcn_exp2f(du.x * Av1),  h1, du.y * bb.y);
            h2 = fmaf(__builtin_amdgcn_exp2f(du.x * Av2_), h2, du.y * bb.z);
            h3 = fmaf(__builtin_amdgcn_exp2f(du.x * Av3),  h3, du.y * bb.w);
        }
    }
    *(float4*)(hloc + hbase) = float4{h0, h1, h2, h3};
    if (q == 0) sumd[((b * 128 + (d >> 4)) * SCH + s) * 16 + (d & 15)] = sd;
}

// ---------------- scan phase 2: sequential chunk fix-up + h_last (unchanged) ----------------
__global__ __launch_bounds__(256) void scan_p2(const float* __restrict__ hloc,
                                               const float* __restrict__ sumd,
                                               const float* __restrict__ A_log,
                                               float* __restrict__ hin,
                                               float* __restrict__ out_h) {
    const int t = threadIdx.x;
    const int bd = blockIdx.x;
    const int b = bd >> 7;
    const int d = ((bd & 127) << 4) + (t >> 4);
    const int n = t & 15;
    const float Av2 = -__expf(A_log[d * NST + n]) * 1.44269504f;
    float h = 0.f;
#pragma unroll
    for (int s = 0; s < SCH; ++s) {
        const size_t idx = ((size_t)bd * SCH + s) * 256 + t;
        hin[idx] = h;
        float P = __builtin_amdgcn_exp2f(Av2 * sumd[(bd * SCH + s) * 16 + (t >> 4)]);
        h = fmaf(P, h, hloc[idx]);
    }
    out_h[((size_t)(b * DINNER + d)) * NST + n] = h;
}

// ---------------- scan phase 3: 4 states/lane, dbuf, 1 barrier/tile, deferred writeout ----------------
__global__ __launch_bounds__(256) void scan_p3(const float* __restrict__ dlt,
                                               const unsigned short* __restrict__ zb,
                                               unsigned short* uy,
                                               const float* __restrict__ xdbl,
                                               const float* __restrict__ A_log,
                                               const float* __restrict__ D_skip,
                                               const int* __restrict__ lengths,
                                               const float* __restrict__ hin) {
    __shared__ float2 sDU[2][STT][SCB];   // 16 KB
    __shared__ float  sBC[2][STT][32];    // 4 KB
    __shared__ float  sY[2][STT][SCB];    // 8 KB
    __shared__ float  sDk[SCB];
    const int t = threadIdx.x;
    const int s = blockIdx.x >> 7;
    const int g = blockIdx.x & 127;
    const int b = g >> 5;
    const int d0 = (g & 31) * SCB;
    const int ch = t >> 2, q = t & 3;
    const int d = d0 + ch;
    if (s * CH >= lengths[b]) return;
    if (t < SCB) sDk[t] = D_skip[d0 + t];
    const float Av0 = -__expf(A_log[d * NST + q * 4 + 0]) * 1.44269504f;
    const float Av1 = -__expf(A_log[d * NST + q * 4 + 1]) * 1.44269504f;
    const float Av2_ = -__expf(A_log[d * NST + q * 4 + 2]) * 1.44269504f;
    const float Av3 = -__expf(A_log[d * NST + q * 4 + 3]) * 1.44269504f;
    const size_t hbase = ((size_t)(b * 128 + (d >> 4)) * SCH + s) * 256 + (size_t)(d & 15) * 16 + q * 4;
    float4 hv = *(const float4*)(hin + hbase);
    float h0 = hv.x, h1 = hv.y, h2 = hv.z, h3 = hv.w;
    const size_t base = (size_t)b * LSEQ + (size_t)s * CH;
    const int r = t >> 4, c4 = (t & 15) << 2, n2 = (t & 15) << 1;

    size_t row = base + r;
    float4 dv = *(const float4*)(dlt + row * DINNER + d0 + c4);
    ushort4 uv = *(const ushort4*)(uy + row * DINNER + d0 + c4);
    ushort4 zz = *(const ushort4*)(zb + row * DINNER + d0 + c4);
    float2 bc = *(const float2*)(xdbl + row * 96 + 64 + n2);
    ushort4 uvW0, zzW0, uvW1, zzW1;
    size_t rowW0 = 0, rowW1 = 0;

#define P3_STAGE(CUR, UVW, ZZW, ROWW)                          \
    sDU[CUR][r][c4 + 0] = float2{dv.x, dv.x * bf2f(uv.x)};     \
    sDU[CUR][r][c4 + 1] = float2{dv.y, dv.y * bf2f(uv.y)};     \
    sDU[CUR][r][c4 + 2] = float2{dv.z, dv.z * bf2f(uv.z)};     \
    sDU[CUR][r][c4 + 3] = float2{dv.w, dv.w * bf2f(uv.w)};     \
    sBC[CUR][r][n2 + 0] = bc.x; sBC[CUR][r][n2 + 1] = bc.y;    \
    UVW = uv; ZZW = zz; ROWW = row;

#define P3_PREFETCH(L0N)                                                \
    if ((L0N) < CH) {                                                   \
        row = base + (L0N) + r;                                         \
        dv = *(const float4*)(dlt + row * DINNER + d0 + c4);            \
        uv = *(const ushort4*)(uy + row * DINNER + d0 + c4);            \
        zz = *(const ushort4*)(zb + row * DINNER + d0 + c4);            \
        bc = *(const float2*)(xdbl + row * 96 + 64 + n2);               \
    }

#define P3_COMPUTE(CUR)                                                                    \
    _Pragma("unroll")                                                                      \
    for (int r2 = 0; r2 < STT; ++r2) {                                                     \
        float2 du = sDU[CUR][r2][ch];                                                      \
        float4 bb = *(const float4*)&sBC[CUR][r2][q * 4];                                  \
        float4 cc = *(const float4*)&sBC[CUR][r2][16 + q * 4];                             \
        float y;                                                                           \
        h0 = fmaf(__builtin_amdgcn_exp2f(du.x * Av0),  h0, du.y * bb.x); y = h0 * cc.x;    \
        h1 = fmaf(__builtin_amdgcn_exp2f(du.x * Av1),  h1, du.y * bb.y); y = fmaf(h1, cc.y, y); \
        h2 = fmaf(__builtin_amdgcn_exp2f(du.x * Av2_), h2, du.y * bb.z); y = fmaf(h2, cc.z, y); \
        h3 = fmaf(__builtin_amdgcn_exp2f(du.x * Av3),  h3, du.y * bb.w); y = fmaf(h3, cc.w, y); \
        y += dpp_qp<0x39>(y);                                                              \
        y += dpp_qp<0x4E>(y);                                                              \
        if (q == 0) sY[CUR][r2][ch] = y;                                                   \
    }

#define P3_WRITEOUT(CUR, UVW, ZZW, ROWW) {                                        \
        float4 yv = *(const float4*)&sY[CUR][r][c4];                              \
        float4 kk = *(const float4*)&sDk[c4];                                     \
        ushort4 ov;                                                               \
        ov.x = f2bf(fmaf(bf2f(UVW.x), kk.x, yv.x) * siluf(bf2f(ZZW.x)));          \
        ov.y = f2bf(fmaf(bf2f(UVW.y), kk.y, yv.y) * siluf(bf2f(ZZW.y)));          \
        ov.z = f2bf(fmaf(bf2f(UVW.z), kk.z, yv.z) * siluf(bf2f(ZZW.z)));          \
        ov.w = f2bf(fmaf(bf2f(UVW.w), kk.w, yv.w) * siluf(bf2f(ZZW.w)));          \
        *(ushort4*)(uy + (ROWW) * DINNER + d0 + c4) = ov;                         \
    }

    for (int ii = 0; ii < 4; ++ii) {
        const int l0a = ii * 32;
        P3_STAGE(0, uvW0, zzW0, rowW0)
        P3_PREFETCH(l0a + 16)
        __syncthreads();
        if (ii > 0) P3_WRITEOUT(1, uvW1, zzW1, rowW1)
        P3_COMPUTE(0)
        P3_STAGE(1, uvW1, zzW1, rowW1)
        P3_PREFETCH(l0a + 32)
        __syncthreads();
        P3_WRITEOUT(0, uvW0, zzW0, rowW0)
        P3_COMPUTE(1)
    }
    __syncthreads();
    P3_WRITEOUT(1, uvW1, zzW1, rowW1)

#undef P3_STAGE
#undef P3_PREFETCH
#undef P3_COMPUTE
#undef P3_WRITEOUT
}

extern "C" void kernel_launch(void* const* d_in, const int* in_sizes, int n_in,
                              void* d_out, int out_size, void* d_ws, size_t ws_size,
                              hipStream_t stream) {
    const float* hs        = (const float*)d_in[0];
    const int*   lengths   = (const int*)d_in[1];
    const float* norm_w    = (const float*)d_in[2];
    const float* in_proj_w = (const float*)d_in[3];
    const float* conv_w    = (const float*)d_in[4];
    const float* x_proj_w  = (const float*)d_in[5];
    const float* dt_proj_w = (const float*)d_in[6];
    const float* dt_proj_b = (const float*)d_in[7];
    const float* A_log     = (const float*)d_in[8];
    const float* D_skip    = (const float*)d_in[9];
    const float* out_proj_w= (const float*)d_in[10];

    float* out = (float*)d_out;

    const int M = NB * LSEQ;                                            // 8192
    float* ur = (float*)d_ws;                                           // 8192x2048 f32: u_raw -> dlt
    unsigned short* zb = (unsigned short*)(ur + (size_t)M * DINNER);    // 8192x2048 bf16: z
    unsigned short* u_bf = zb + (size_t)M * DINNER;                     // 8192x2048 bf16: u -> y
    float* xdbl = (float*)(u_bf + (size_t)M * DINNER);                  // 8192x96 f32
    unsigned short* w_in  = (unsigned short*)(xdbl + (size_t)M * 96);   // 4096x1024
    unsigned short* w_out = w_in + (size_t)4096 * 1024;                 // 1024x2048
    unsigned short* w_x   = w_out + (size_t)1024 * 2048;                // 96x2048
    unsigned short* w_dt  = w_x + (size_t)96 * 2048;                    // 2048x64
    unsigned short* dtr   = w_dt + (size_t)2048 * 64;                   // 8192x64 bf16
    float* hin            = (float*)(dtr + (size_t)M * 64);             // 512*16*256 f32 (8MB)
    float* xpart          = hin + (size_t)NBD * SCH * 256;              // 4x8192x96 f32 (12.6MB)
    unsigned short* xn_bf = u_bf;          // alias: dead once conv overwrites it
    float* dlt  = ur;                      // alias: ur dead after conv
    float* hloc = (float*)w_in;            // alias: w_in dead after in_proj
    float* sumd = (float*)dtr;             // alias: dtr dead after dt_proj

    // 1. fused RMSNorm->bf16 + fused weight conversions
    rmsnorm_cvt_k<<<M, 256, 0, stream>>>(hs, norm_w, xn_bf);
    cvt_all_k<<<6464, 256, 0, stream>>>(in_proj_w, out_proj_w, x_proj_w, dt_proj_w,
                                        w_in, w_out, w_x, w_dt);

    // 2. in_proj (bf16 MFMA dbuf+swz, row-skip, vectorized epilogue): ur f32 | z bf16
    gemm_bf16<0><<<(4096 / 128) * (M / 128), 256, 0, stream>>>(
        xn_bf, DMODEL, w_in, DMODEL, ur, zb, DINNER, M, 4096, DMODEL, 4096 / 128,
        nullptr, nullptr, nullptr, lengths);

    // 3. causal depthwise conv + silu + mask -> u (bf16)
    conv_silu_k<<<NB * 512, 256, 0, stream>>>(ur, conv_w, lengths, u_bf);

    // 4. x_proj split-K4 (grid 256) -> partials; reduce -> dtr bf16 + xdbl f32
    gemm_bf16<4><<<4 * (M / 128), 256, 0, stream>>>(
        u_bf, DINNER, w_x, DINNER, xpart, nullptr, 96, M, 96, 512, 1,
        nullptr, nullptr, nullptr, lengths);
    xred_k<<<M / 4, 384, 0, stream>>>(xpart, lengths, dtr, xdbl);

    // 5. dt_proj (bf16 MFMA, row-skip, vectorized epilogue) + softplus + mask -> delta f32
    gemm_bf16<1><<<(DINNER / 128) * (M / 128), 256, 0, stream>>>(
        dtr, 64, w_dt, 64, dlt, nullptr, DINNER, M, DINNER, 64, DINNER / 128,
        dt_proj_b, nullptr, nullptr, lengths);

    // 6. chunked selective scan (3 phases, chunk-skip, dbuf+prefetch)
    {
        float* hlast = out + (size_t)M * DMODEL;
        scan_p1<<<SCH * 128, 256, 0, stream>>>(dlt, u_bf, xdbl, A_log, lengths, hloc, sumd);
        scan_p2<<<NBD, 256, 0, stream>>>(hloc, sumd, A_log, hin, hlast);
        scan_p3<<<SCH * 128, 256, 0, stream>>>(dlt, zb, u_bf, xdbl, A_log, D_skip, lengths, hin);
    }

    // 7. out_proj: intra-block K-split + LDS-reduced vectorized epilogue
    gemm_out_ks<<<(DMODEL / 128) * (M / 128), 512, 0, stream>>>(
        u_bf, DINNER, w_out, DINNER, out, DMODEL, hs, lengths);
}

// Round 19
// 223.261 us; speedup vs baseline: 1.5885x; 1.1691x over previous
//
#include <hip/hip_runtime.h>
#include <cstdint>
#include <cstddef>

#define LSEQ 2048
#define NB   4
#define DMODEL 1024
#define DINNER 2048
#define NST  16
#define CH   128   // scan chunk length == GEMM tile height
#define SCH  (LSEQ / CH)   // 16 chunks
#define NBD  512           // NB * DINNER/16 (p2 layout)
#define STT  16    // scan steps per LDS tile
#define SCB  64    // channels per scan block (4 lanes each)

typedef short bf16x8 __attribute__((ext_vector_type(8)));
typedef float f32x4  __attribute__((ext_vector_type(4)));

__device__ __forceinline__ float siluf(float x) { return x / (1.f + __expf(-x)); }
__device__ __forceinline__ float softplusf(float x) {
    // fast softplus: log(1+exp(x)) via v_exp_f32/v_log_f32; linear guard for large x.
    return (x > 20.f) ? x : __logf(1.f + __expf(x));
}

__device__ __forceinline__ unsigned short f2bf(float f) {
    unsigned u = __float_as_uint(f);
    u += 0x7FFF + ((u >> 16) & 1);     // round-to-nearest-even
    return (unsigned short)(u >> 16);
}
__device__ __forceinline__ float bf2f(unsigned short h) {
    return __uint_as_float(((unsigned)h) << 16);
}
__device__ __forceinline__ void gload_lds16(const void* g, void* l) {
    __builtin_amdgcn_global_load_lds(
        (const __attribute__((address_space(1))) unsigned int*)g,
        (__attribute__((address_space(3))) unsigned int*)l, 16, 0, 0);
}

// DPP quad_perm add helpers: rotate within 4-lane quad
template <int CTRL>
__device__ __forceinline__ float dpp_qp(float v) {
    return __int_as_float(__builtin_amdgcn_update_dpp(
        0, __float_as_int(v), CTRL, 0xf, 0xf, false));
}

// ---------------- fused RMSNorm + bf16 convert ----------------
__global__ __launch_bounds__(256) void rmsnorm_cvt_k(const float* __restrict__ x,
                                                     const float* __restrict__ nw,
                                                     unsigned short* __restrict__ o) {
    int row = blockIdx.x, t = threadIdx.x;
    float4 v = ((const float4*)(x + (size_t)row * DMODEL))[t];
    float s = v.x * v.x + v.y * v.y + v.z * v.z + v.w * v.w;
#pragma unroll
    for (int m = 32; m >= 1; m >>= 1) s += __shfl_xor(s, m);
    __shared__ float wsum[4];
    __shared__ float sinv;
    if ((t & 63) == 0) wsum[t >> 6] = s;
    __syncthreads();
    if (t == 0) {
        float tot = wsum[0] + wsum[1] + wsum[2] + wsum[3];
        sinv = rsqrtf(tot * (1.f / (float)DMODEL) + 1e-6f);
    }
    __syncthreads();
    float iv = sinv;
    float4 w = ((const float4*)nw)[t];
    ushort4 ov;
    ov.x = f2bf(v.x * iv * w.x); ov.y = f2bf(v.y * iv * w.y);
    ov.z = f2bf(v.z * iv * w.z); ov.w = f2bf(v.w * iv * w.w);
    ((ushort4*)(o + (size_t)row * DMODEL))[t] = ov;
}

// ---------------- fused weight conversions (4 matrices, 1 launch) ----------------
__global__ __launch_bounds__(256) void cvt_all_k(const float* __restrict__ s0, const float* __restrict__ s1,
                                                 const float* __restrict__ s2, const float* __restrict__ s3,
                                                 unsigned short* __restrict__ q0, unsigned short* __restrict__ q1,
                                                 unsigned short* __restrict__ q2, unsigned short* __restrict__ q3) {
    int i = blockIdx.x * 256 + threadIdx.x;
    const float* s; unsigned short* d; int off;
    if (i < 1048576)       { s = s0; d = q0; off = i; }
    else if (i < 1572864)  { s = s1; d = q1; off = i - 1048576; }
    else if (i < 1622016)  { s = s2; d = q2; off = i - 1572864; }
    else if (i < 1654784)  { s = s3; d = q3; off = i - 1622016; }
    else return;
    float4 v = ((const float4*)s)[off];
    ushort4 o;
    o.x = f2bf(v.x); o.y = f2bf(v.y); o.z = f2bf(v.z); o.w = f2bf(v.w);
    ((ushort4*)d)[off] = o;
}

// ---------------- bf16 MFMA NT GEMM: dbuf+swz K-loop, LDS-staged vectorized epilogue ----------------
// EPI 0: col<2048 -> f32 Cv (ur), col>=2048 -> bf16 C2 (z)  (in_proj; tile-uniform branch)
// EPI 1: softplus(acc+bias)*mask -> f32                      (dt_proj)
// EPI 4: split-K partial (seg=bid&3) -> f32 partial          (x_proj)
template <int EPI>
__global__ __launch_bounds__(256) void gemm_bf16(
    const unsigned short* __restrict__ A, int lda,
    const unsigned short* __restrict__ W, int ldw,
    void* __restrict__ Cv, void* __restrict__ C2v, int ldc,
    int M, int N, int K, int nbx,
    const float* __restrict__ bias,
    const float* __restrict__ residual,
    unsigned short* __restrict__ aux,
    const int* __restrict__ lengths) {
    __shared__ __align__(16) unsigned short smem[4][128 * 64];  // A0,A1,B0,B1 = 64KB
    const int bid = blockIdx.x;
    int bx, by, seg;
    if (EPI == 4) { seg = bid & 3; by = bid >> 2; bx = 0; }
    else          { seg = 0; bx = bid % nbx; by = bid / nbx; }
    const unsigned short* Ap = A + (size_t)seg * 512;
    const unsigned short* Wp = W + (size_t)seg * 512;
    const int row0 = by * 128, col0 = bx * 128;
    const int t = threadIdx.x;

    const int len0 = lengths[row0 >> 11];
    if ((row0 & (LSEQ - 1)) >= len0) return;

    const int lane = t & 63;
    const int w = t >> 6;
    const int wr = w >> 1, wc = w & 1;

    f32x4 acc[4][4];
#pragma unroll
    for (int m = 0; m < 4; ++m)
#pragma unroll
        for (int n = 0; n < 4; ++n) acc[m][n] = f32x4{0.f, 0.f, 0.f, 0.f};

    const int rA = lane & 15;
    const int kH = (lane >> 4) << 3;
    const int NT = K >> 6;
    const int swzR = (rA & 7) << 3;

    auto STAGE = [&](int sel, int k0) {
#pragma unroll
        for (int it = 0; it < 4; ++it) {
            int c = it * 256 + t;
            int r = c >> 3;
            int cc = ((c & 7) ^ (r & 7)) << 3;
            gload_lds16(Ap + (size_t)(row0 + r) * lda + k0 + cc, &smem[sel][c << 3]);
            int wrow = col0 + r; if (wrow >= N) wrow = N - 1;
            gload_lds16(Wp + (size_t)wrow * ldw + k0 + cc, &smem[2 + sel][c << 3]);
        }
    };

    STAGE(0, 0);
    for (int kt = 0; kt < NT; ++kt) {
        const int cur = kt & 1;
        if (kt + 1 < NT) STAGE(cur ^ 1, (kt + 1) << 6);
        __builtin_amdgcn_sched_barrier(0);
        if (kt + 1 < NT) { asm volatile("s_waitcnt vmcnt(8)" ::: "memory"); }
        else             { asm volatile("s_waitcnt vmcnt(0)" ::: "memory"); }
        __builtin_amdgcn_sched_barrier(0);
        __builtin_amdgcn_s_barrier();
        __builtin_amdgcn_sched_barrier(0);
#pragma unroll
        for (int ks = 0; ks < 2; ++ks) {
            const int kkS = (ks * 32 + kH) ^ swzR;
            bf16x8 af[4], bfr[4];
#pragma unroll
            for (int m = 0; m < 4; ++m)
                af[m] = *(const bf16x8*)&smem[cur][(wr * 64 + m * 16 + rA) * 64 + kkS];
#pragma unroll
            for (int n = 0; n < 4; ++n)
                bfr[n] = *(const bf16x8*)&smem[2 + cur][(wc * 64 + n * 16 + rA) * 64 + kkS];
#pragma unroll
            for (int m = 0; m < 4; ++m)
#pragma unroll
                for (int n = 0; n < 4; ++n)
                    acc[m][n] = __builtin_amdgcn_mfma_f32_16x16x32_bf16(
                        af[m], bfr[n], acc[m][n], 0, 0, 0);
        }
        __builtin_amdgcn_sched_barrier(0);
        asm volatile("s_waitcnt lgkmcnt(0)" ::: "memory");
        __builtin_amdgcn_s_barrier();
        __builtin_amdgcn_sched_barrier(0);
    }

    // ---- LDS-staged vectorized epilogue (staging LDS is dead after the loop) ----
    float* sC = (float*)smem;                 // 128x128 f32, col XOR-swizzled by ((row&7)<<2)
    const int cl = lane & 15, rg = lane >> 4;
#pragma unroll
    for (int m = 0; m < 4; ++m) {
#pragma unroll
        for (int j = 0; j < 4; ++j) {
            const int rl = wr * 64 + m * 16 + rg * 4 + j;
            const int msw = (rl & 7) << 2;
#pragma unroll
            for (int n = 0; n < 4; ++n) {
                const int cc = wc * 64 + n * 16 + cl;
                sC[rl * 128 + (cc ^ msw)] = acc[m][n][j];
            }
        }
    }
    __syncthreads();
#pragma unroll
    for (int i = 0; i < 16; ++i) {
        const int lin = i * 256 + t;
        const int r = lin >> 5, cc4 = (lin & 31) << 2;
        const int row = row0 + r;
        float4 v = *(const float4*)&sC[r * 128 + (cc4 ^ ((r & 7) << 2))];
        if (EPI == 0) {
            if (col0 < DINNER) {
                *(float4*)((float*)Cv + (size_t)row * DINNER + col0 + cc4) = v;
            } else {
                ushort4 ov;
                ov.x = f2bf(v.x); ov.y = f2bf(v.y); ov.z = f2bf(v.z); ov.w = f2bf(v.w);
                *(ushort4*)((unsigned short*)C2v + (size_t)row * DINNER + col0 - DINNER + cc4) = ov;
            }
        } else if (EPI == 1) {
            const float msk = ((row & (LSEQ - 1)) < len0) ? 1.f : 0.f;
            float4 bb = *(const float4*)(bias + col0 + cc4);
            v.x = softplusf(v.x + bb.x) * msk;
            v.y = softplusf(v.y + bb.y) * msk;
            v.z = softplusf(v.z + bb.z) * msk;
            v.w = softplusf(v.w + bb.w) * msk;
            *(float4*)((float*)Cv + (size_t)row * ldc + col0 + cc4) = v;
        } else {  // EPI 4: x_proj partial, only cols < 96
            if (cc4 < 96)
                *(float4*)((float*)Cv + (size_t)seg * M * 96 + (size_t)row * 96 + cc4) = v;
        }
    }
}

// ---------------- out_proj: intra-block K-split, LDS reduce + vectorized epilogue ----------------
__global__ __launch_bounds__(512) void gemm_out_ks(
    const unsigned short* __restrict__ A, int lda,   // y (u_bf), 2048
    const unsigned short* __restrict__ W, int ldw,   // w_out, 2048
    float* __restrict__ C, int ldc,                  // out, 1024
    const float* __restrict__ residual,
    const int* __restrict__ lengths) {
    __shared__ __align__(16) unsigned short smem[4][128 * 64];  // [A0,A1(B-group),B0,B1] 64KB
    const int bid = blockIdx.x;
    const int bx = bid & 7, by = bid >> 3;
    const int row0 = by * 128, col0 = bx * 128;
    const int t = threadIdx.x;

    const int len0 = lengths[row0 >> 11];
    if ((row0 & (LSEQ - 1)) >= len0) {
#pragma unroll
        for (int i = 0; i < 8; ++i) {
            int lin = i * 512 + t;
            int r = lin >> 5, c = (lin & 31) << 2;
            *(float4*)(C + (size_t)(row0 + r) * ldc + col0 + c) =
                *(const float4*)(residual + (size_t)(row0 + r) * ldc + col0 + c);
        }
        return;
    }

    const int tg = t & 255;            // thread within K-group
    const int lane = t & 63;
    const int w = t >> 6;              // 0..7
    const int seg = w >> 2;            // K-group
    const int wg = w & 3;              // wave within group
    const int wr = wg >> 1, wc = wg & 1;
    const unsigned short* Ap = A + (size_t)seg * 1024;
    const unsigned short* Wp = W + (size_t)seg * 1024;

    f32x4 acc[4][4];
#pragma unroll
    for (int m = 0; m < 4; ++m)
#pragma unroll
        for (int n = 0; n < 4; ++n) acc[m][n] = f32x4{0.f, 0.f, 0.f, 0.f};

    const int rA = lane & 15;
    const int kH = (lane >> 4) << 3;
    const int swzR = (rA & 7) << 3;

    for (int kt = 0; kt < 16; ++kt) {
#pragma unroll
        for (int it = 0; it < 4; ++it) {
            int c = it * 256 + tg;
            int r = c >> 3;
            int cc = ((c & 7) ^ (r & 7)) << 3;
            gload_lds16(Ap + (size_t)(row0 + r) * lda + (kt << 6) + cc, &smem[seg][c << 3]);
            gload_lds16(Wp + (size_t)(col0 + r) * ldw + (kt << 6) + cc, &smem[2 + seg][c << 3]);
        }
        __builtin_amdgcn_sched_barrier(0);
        asm volatile("s_waitcnt vmcnt(0)" ::: "memory");
        __builtin_amdgcn_sched_barrier(0);
        __builtin_amdgcn_s_barrier();
        __builtin_amdgcn_sched_barrier(0);
#pragma unroll
        for (int ks = 0; ks < 2; ++ks) {
            const int kkS = (ks * 32 + kH) ^ swzR;
            bf16x8 af[4], bfr[4];
#pragma unroll
            for (int m = 0; m < 4; ++m)
                af[m] = *(const bf16x8*)&smem[seg][(wr * 64 + m * 16 + rA) * 64 + kkS];
#pragma unroll
            for (int n = 0; n < 4; ++n)
                bfr[n] = *(const bf16x8*)&smem[2 + seg][(wc * 64 + n * 16 + rA) * 64 + kkS];
#pragma unroll
            for (int m = 0; m < 4; ++m)
#pragma unroll
                for (int n = 0; n < 4; ++n)
                    acc[m][n] = __builtin_amdgcn_mfma_f32_16x16x32_bf16(
                        af[m], bfr[n], acc[m][n], 0, 0, 0);
        }
        __builtin_amdgcn_sched_barrier(0);
        asm volatile("s_waitcnt lgkmcnt(0)" ::: "memory");
        __builtin_amdgcn_s_barrier();
        __builtin_amdgcn_sched_barrier(0);
    }

    // ---- cross-group reduce in dead LDS + vectorized epilogue ----
    float* sC = (float*)smem;                 // 128x128 f32, swizzled
    const int cl = lane & 15, rg = lane >> 4;
    if (seg == 1) {
#pragma unroll
        for (int m = 0; m < 4; ++m)
#pragma unroll
            for (int j = 0; j < 4; ++j) {
                const int rl = wr * 64 + m * 16 + rg * 4 + j;
                const int msw = (rl & 7) << 2;
#pragma unroll
                for (int n = 0; n < 4; ++n) {
                    const int cc = wc * 64 + n * 16 + cl;
                    sC[rl * 128 + (cc ^ msw)] = acc[m][n][j];
                }
            }
    }
    __syncthreads();
    if (seg == 0) {
#pragma unroll
        for (int m = 0; m < 4; ++m)
#pragma unroll
            for (int j = 0; j < 4; ++j) {
                const int rl = wr * 64 + m * 16 + rg * 4 + j;
                const int msw = (rl & 7) << 2;
#pragma unroll
                for (int n = 0; n < 4; ++n) {
                    const int cc = wc * 64 + n * 16 + cl;
                    sC[rl * 128 + (cc ^ msw)] += acc[m][n][j];
                }
            }
    }
    __syncthreads();
#pragma unroll
    for (int i = 0; i < 8; ++i) {
        const int lin = i * 512 + t;
        const int r = lin >> 5, cc4 = (lin & 31) << 2;
        const int row = row0 + r;
        const float msk = ((row & (LSEQ - 1)) < len0) ? 1.f : 0.f;
        float4 v = *(const float4*)&sC[r * 128 + (cc4 ^ ((r & 7) << 2))];
        float4 res = *(const float4*)(residual + (size_t)row * ldc + col0 + cc4);
        float4 o;
        o.x = res.x + msk * v.x; o.y = res.y + msk * v.y;
        o.z = res.z + msk * v.z; o.w = res.w + msk * v.w;
        *(float4*)(C + (size_t)row * ldc + col0 + cc4) = o;
    }
}

// ---------------- x_proj split-K reduce: sum 4 partials -> dtr bf16 + xdbl f32 ----------------
__global__ __launch_bounds__(384) void xred_k(const float* __restrict__ P,
                                              const int* __restrict__ lengths,
                                              unsigned short* __restrict__ dtr,
                                              float* __restrict__ xdbl) {
    const int t = threadIdx.x;
    const int row = blockIdx.x * 4 + t / 96;
    const int col = t % 96;
    const int b = row >> 11, l = row & (LSEQ - 1);
    const int lenUp = (lengths[b] + CH - 1) & ~(CH - 1);
    if (l >= lenUp) return;
    const size_t SEG = (size_t)8192 * 96;
    const size_t idx = (size_t)row * 96 + col;
    float v = P[idx] + P[idx + SEG] + P[idx + 2 * SEG] + P[idx + 3 * SEG];
    if (col < 64) dtr[(size_t)row * 64 + col] = f2bf(v);
    else xdbl[idx] = v;
}

// ---------------- causal depthwise conv (K=4) + SiLU + mask -> bf16 ----------------
__global__ __launch_bounds__(256) void conv_silu_k(const float* __restrict__ ur,
                                                   const float* __restrict__ cw,
                                                   const int* __restrict__ lengths,
                                                   unsigned short* __restrict__ u) {
    const int g = blockIdx.x;              // NB * 512
    const int b = g >> 9;
    const int rem = g & 511;
    const int l0 = (rem >> 1) << 3;
    const int d4 = (rem & 1) * 1024 + threadIdx.x * 4;
    const int len = lengths[b];
    const size_t rb = (size_t)b * LSEQ;
    if (l0 >= len) {
        const int lenUp = (len + CH - 1) & ~(CH - 1);
        if (l0 < lenUp) {
            ushort4 z4 = {0, 0, 0, 0};
#pragma unroll
            for (int i = 0; i < 8; ++i)
                *(ushort4*)(u + (rb + l0 + i) * DINNER + d4) = z4;
        }
        return;
    }
    float4 wq[4];
#pragma unroll
    for (int c = 0; c < 4; ++c) wq[c] = *(const float4*)(cw + 4 * (d4 + c));
    const float4 zero4 = {0.f, 0.f, 0.f, 0.f};
    float4 xm3 = (l0 - 3 >= 0 && l0 - 3 < len) ? *(const float4*)(ur + (rb + l0 - 3) * DINNER + d4) : zero4;
    float4 xm2 = (l0 - 2 >= 0 && l0 - 2 < len) ? *(const float4*)(ur + (rb + l0 - 2) * DINNER + d4) : zero4;
    float4 xm1 = (l0 - 1 >= 0 && l0 - 1 < len) ? *(const float4*)(ur + (rb + l0 - 1) * DINNER + d4) : zero4;
#pragma unroll
    for (int i = 0; i < 8; ++i) {
        const int l = l0 + i;
        const bool act = l < len;
        float4 x0 = act ? *(const float4*)(ur + (rb + l) * DINNER + d4) : zero4;
        float a0 = wq[0].x * xm3.x + wq[0].y * xm2.x + wq[0].z * xm1.x + wq[0].w * x0.x;
        float a1 = wq[1].x * xm3.y + wq[1].y * xm2.y + wq[1].z * xm1.y + wq[1].w * x0.y;
        float a2 = wq[2].x * xm3.z + wq[2].y * xm2.z + wq[2].z * xm1.z + wq[2].w * x0.z;
        float a3 = wq[3].x * xm3.w + wq[3].y * xm2.w + wq[3].z * xm1.w + wq[3].w * x0.w;
        ushort4 ov;
        ov.x = f2bf(act ? siluf(a0) : 0.f);
        ov.y = f2bf(act ? siluf(a1) : 0.f);
        ov.z = f2bf(act ? siluf(a2) : 0.f);
        ov.w = f2bf(act ? siluf(a3) : 0.f);
        *(ushort4*)(u + (rb + l) * DINNER + d4) = ov;
        xm3 = xm2; xm2 = xm1; xm1 = x0;
    }
}

// ---------------- scan phase 1 (4 states/lane, dbuf + register prefetch) ----------------
__global__ __launch_bounds__(256) void scan_p1(const float* __restrict__ dlt,
                                               const unsigned short* __restrict__ uy,
                                               const float* __restrict__ xdbl,
                                               const float* __restrict__ A_log,
                                               const int* __restrict__ lengths,
                                               float* __restrict__ hloc,
                                               float* __restrict__ sumd) {
    __shared__ float2 sDU[2][STT][SCB];   // 16 KB
    __shared__ float  sB[2][STT][16];     // 2 KB
    const int t = threadIdx.x;
    const int s = blockIdx.x >> 7;
    const int g = blockIdx.x & 127;
    const int b = g >> 5;
    const int d0 = (g & 31) * SCB;
    const int ch = t >> 2, q = t & 3;
    const int d = d0 + ch;
    const size_t hbase = ((size_t)(b * 128 + (d >> 4)) * SCH + s) * 256 + (size_t)(d & 15) * 16 + q * 4;
    if (s * CH >= lengths[b]) {          // fully masked chunk: exact identity
        *(float4*)(hloc + hbase) = float4{0.f, 0.f, 0.f, 0.f};
        if (q == 0) sumd[((b * 128 + (d >> 4)) * SCH + s) * 16 + (d & 15)] = 0.f;
        return;
    }
    const float Av0 = -__expf(A_log[d * NST + q * 4 + 0]) * 1.44269504f;
    const float Av1 = -__expf(A_log[d * NST + q * 4 + 1]) * 1.44269504f;
    const float Av2_ = -__expf(A_log[d * NST + q * 4 + 2]) * 1.44269504f;
    const float Av3 = -__expf(A_log[d * NST + q * 4 + 3]) * 1.44269504f;
    float h0 = 0.f, h1 = 0.f, h2 = 0.f, h3 = 0.f, sd = 0.f;
    const size_t base = (size_t)b * LSEQ + (size_t)s * CH;
    const int r = t >> 4, c4 = (t & 15) << 2, nn = t & 15;

    size_t row = base + r;
    float4 dv = *(const float4*)(dlt + row * DINNER + d0 + c4);
    ushort4 uv = *(const ushort4*)(uy + row * DINNER + d0 + c4);
    float bv = xdbl[row * 96 + 64 + nn];

    for (int l0 = 0; l0 < CH; l0 += STT) {
        const int cur = (l0 >> 4) & 1;
        sDU[cur][r][c4 + 0] = float2{dv.x, dv.x * bf2f(uv.x)};
        sDU[cur][r][c4 + 1] = float2{dv.y, dv.y * bf2f(uv.y)};
        sDU[cur][r][c4 + 2] = float2{dv.z, dv.z * bf2f(uv.z)};
        sDU[cur][r][c4 + 3] = float2{dv.w, dv.w * bf2f(uv.w)};
        sB[cur][r][nn] = bv;
        if (l0 + STT < CH) {
            row = base + l0 + STT + r;
            dv = *(const float4*)(dlt + row * DINNER + d0 + c4);
            uv = *(const ushort4*)(uy + row * DINNER + d0 + c4);
            bv = xdbl[row * 96 + 64 + nn];
        }
        __syncthreads();
#pragma unroll
        for (int r2 = 0; r2 < STT; ++r2) {
            float2 du = sDU[cur][r2][ch];
            float4 bb = *(const float4*)&sB[cur][r2][q * 4];
            sd += du.x;
            h0 = fmaf(__builtin_amdgcn_exp2f(du.x * Av0),  h0, du.y * bb.x);
            h1 = fmaf(__builtin_amdgcn_exp2f(du.x * Av1),  h1, du.y * bb.y);
            h2 = fmaf(__builtin_amdgcn_exp2f(du.x * Av2_), h2, du.y * bb.z);
            h3 = fmaf(__builtin_amdgcn_exp2f(du.x * Av3),  h3, du.y * bb.w);
        }
    }
    *(float4*)(hloc + hbase) = float4{h0, h1, h2, h3};
    if (q == 0) sumd[((b * 128 + (d >> 4)) * SCH + s) * 16 + (d & 15)] = sd;
}

// ---------------- scan phase 2: sequential chunk fix-up + h_last (unchanged) ----------------
__global__ __launch_bounds__(256) void scan_p2(const float* __restrict__ hloc,
                                               const float* __restrict__ sumd,
                                               const float* __restrict__ A_log,
                                               float* __restrict__ hin,
                                               float* __restrict__ out_h) {
    const int t = threadIdx.x;
    const int bd = blockIdx.x;
    const int b = bd >> 7;
    const int d = ((bd & 127) << 4) + (t >> 4);
    const int n = t & 15;
    const float Av2 = -__expf(A_log[d * NST + n]) * 1.44269504f;
    float h = 0.f;
#pragma unroll
    for (int s = 0; s < SCH; ++s) {
        const size_t idx = ((size_t)bd * SCH + s) * 256 + t;
        hin[idx] = h;
        float P = __builtin_amdgcn_exp2f(Av2 * sumd[(bd * SCH + s) * 16 + (t >> 4)]);
        h = fmaf(P, h, hloc[idx]);
    }
    out_h[((size_t)(b * DINNER + d)) * NST + n] = h;
}

// ---------------- scan phase 3: 4 states/lane, dbuf, 1 barrier/tile, deferred writeout ----------------
__global__ __launch_bounds__(256) void scan_p3(const float* __restrict__ dlt,
                                               const unsigned short* __restrict__ zb,
                                               unsigned short* uy,
                                               const float* __restrict__ xdbl,
                                               const float* __restrict__ A_log,
                                               const float* __restrict__ D_skip,
                                               const int* __restrict__ lengths,
                                               const float* __restrict__ hin) {
    __shared__ float2 sDU[2][STT][SCB];   // 16 KB
    __shared__ float  sBC[2][STT][32];    // 4 KB
    __shared__ float  sY[2][STT][SCB];    // 8 KB
    __shared__ float  sDk[SCB];
    const int t = threadIdx.x;
    const int s = blockIdx.x >> 7;
    const int g = blockIdx.x & 127;
    const int b = g >> 5;
    const int d0 = (g & 31) * SCB;
    const int ch = t >> 2, q = t & 3;
    const int d = d0 + ch;
    if (s * CH >= lengths[b]) return;
    if (t < SCB) sDk[t] = D_skip[d0 + t];
    const float Av0 = -__expf(A_log[d * NST + q * 4 + 0]) * 1.44269504f;
    const float Av1 = -__expf(A_log[d * NST + q * 4 + 1]) * 1.44269504f;
    const float Av2_ = -__expf(A_log[d * NST + q * 4 + 2]) * 1.44269504f;
    const float Av3 = -__expf(A_log[d * NST + q * 4 + 3]) * 1.44269504f;
    const size_t hbase = ((size_t)(b * 128 + (d >> 4)) * SCH + s) * 256 + (size_t)(d & 15) * 16 + q * 4;
    float4 hv = *(const float4*)(hin + hbase);
    float h0 = hv.x, h1 = hv.y, h2 = hv.z, h3 = hv.w;
    const size_t base = (size_t)b * LSEQ + (size_t)s * CH;
    const int r = t >> 4, c4 = (t & 15) << 2, n2 = (t & 15) << 1;

    size_t row = base + r;
    float4 dv = *(const float4*)(dlt + row * DINNER + d0 + c4);
    ushort4 uv = *(const ushort4*)(uy + row * DINNER + d0 + c4);
    ushort4 zz = *(const ushort4*)(zb + row * DINNER + d0 + c4);
    float2 bc = *(const float2*)(xdbl + row * 96 + 64 + n2);
    ushort4 uvW0, zzW0, uvW1, zzW1;
    size_t rowW0 = 0, rowW1 = 0;

#define P3_STAGE(CUR, UVW, ZZW, ROWW)                          \
    sDU[CUR][r][c4 + 0] = float2{dv.x, dv.x * bf2f(uv.x)};     \
    sDU[CUR][r][c4 + 1] = float2{dv.y, dv.y * bf2f(uv.y)};     \
    sDU[CUR][r][c4 + 2] = float2{dv.z, dv.z * bf2f(uv.z)};     \
    sDU[CUR][r][c4 + 3] = float2{dv.w, dv.w * bf2f(uv.w)};     \
    sBC[CUR][r][n2 + 0] = bc.x; sBC[CUR][r][n2 + 1] = bc.y;    \
    UVW = uv; ZZW = zz; ROWW = row;

#define P3_PREFETCH(L0N)                                                \
    if ((L0N) < CH) {                                                   \
        row = base + (L0N) + r;                                         \
        dv = *(const float4*)(dlt + row * DINNER + d0 + c4);            \
        uv = *(const ushort4*)(uy + row * DINNER + d0 + c4);            \
        zz = *(const ushort4*)(zb + row * DINNER + d0 + c4);            \
        bc = *(const float2*)(xdbl + row * 96 + 64 + n2);               \
    }

#define P3_COMPUTE(CUR)                                                                    \
    _Pragma("unroll")                                                                      \
    for (int r2 = 0; r2 < STT; ++r2) {                                                     \
        float2 du = sDU[CUR][r2][ch];                                                      \
        float4 bb = *(const float4*)&sBC[CUR][r2][q * 4];                                  \
        float4 cc = *(const float4*)&sBC[CUR][r2][16 + q * 4];                             \
        float y;                                                                           \
        h0 = fmaf(__builtin_amdgcn_exp2f(du.x * Av0),  h0, du.y * bb.x); y = h0 * cc.x;    \
        h1 = fmaf(__builtin_amdgcn_exp2f(du.x * Av1),  h1, du.y * bb.y); y = fmaf(h1, cc.y, y); \
        h2 = fmaf(__builtin_amdgcn_exp2f(du.x * Av2_), h2, du.y * bb.z); y = fmaf(h2, cc.z, y); \
        h3 = fmaf(__builtin_amdgcn_exp2f(du.x * Av3),  h3, du.y * bb.w); y = fmaf(h3, cc.w, y); \
        y += dpp_qp<0x39>(y);                                                              \
        y += dpp_qp<0x4E>(y);                                                              \
        if (q == 0) sY[CUR][r2][ch] = y;                                                   \
    }

#define P3_WRITEOUT(CUR, UVW, ZZW, ROWW) {                                        \
        float4 yv = *(const float4*)&sY[CUR][r][c4];                              \
        float4 kk = *(const float4*)&sDk[c4];                                     \
        ushort4 ov;                                                               \
        ov.x = f2bf(fmaf(bf2f(UVW.x), kk.x, yv.x) * siluf(bf2f(ZZW.x)));          \
        ov.y = f2bf(fmaf(bf2f(UVW.y), kk.y, yv.y) * siluf(bf2f(ZZW.y)));          \
        ov.z = f2bf(fmaf(bf2f(UVW.z), kk.z, yv.z) * siluf(bf2f(ZZW.z)));          \
        ov.w = f2bf(fmaf(bf2f(UVW.w), kk.w, yv.w) * siluf(bf2f(ZZW.w)));          \
        *(ushort4*)(uy + (ROWW) * DINNER + d0 + c4) = ov;                         \
    }

    for (int ii = 0; ii < 4; ++ii) {
        const int l0a = ii * 32;
        P3_STAGE(0, uvW0, zzW0, rowW0)
        P3_PREFETCH(l0a + 16)
        __syncthreads();
        if (ii > 0) P3_WRITEOUT(1, uvW1, zzW1, rowW1)
        P3_COMPUTE(0)
        P3_STAGE(1, uvW1, zzW1, rowW1)
        P3_PREFETCH(l0a + 32)
        __syncthreads();
        P3_WRITEOUT(0, uvW0, zzW0, rowW0)
        P3_COMPUTE(1)
    }
    __syncthreads();
    P3_WRITEOUT(1, uvW1, zzW1, rowW1)

#undef P3_STAGE
#undef P3_PREFETCH
#undef P3_COMPUTE
#undef P3_WRITEOUT
}

extern "C" void kernel_launch(void* const* d_in, const int* in_sizes, int n_in,
                              void* d_out, int out_size, void* d_ws, size_t ws_size,
                              hipStream_t stream) {
    const float* hs        = (const float*)d_in[0];
    const int*   lengths   = (const int*)d_in[1];
    const float* norm_w    = (const float*)d_in[2];
    const float* in_proj_w = (const float*)d_in[3];
    const float* conv_w    = (const float*)d_in[4];
    const float* x_proj_w  = (const float*)d_in[5];
    const float* dt_proj_w = (const float*)d_in[6];
    const float* dt_proj_b = (const float*)d_in[7];
    const float* A_log     = (const float*)d_in[8];
    const float* D_skip    = (const float*)d_in[9];
    const float* out_proj_w= (const float*)d_in[10];

    float* out = (float*)d_out;

    const int M = NB * LSEQ;                                            // 8192
    float* ur = (float*)d_ws;                                           // 8192x2048 f32: u_raw -> dlt
    unsigned short* zb = (unsigned short*)(ur + (size_t)M * DINNER);    // 8192x2048 bf16: z
    unsigned short* u_bf = zb + (size_t)M * DINNER;                     // 8192x2048 bf16: u -> y
    float* xdbl = (float*)(u_bf + (size_t)M * DINNER);                  // 8192x96 f32
    unsigned short* w_in  = (unsigned short*)(xdbl + (size_t)M * 96);   // 4096x1024
    unsigned short* w_out = w_in + (size_t)4096 * 1024;                 // 1024x2048
    unsigned short* w_x   = w_out + (size_t)1024 * 2048;                // 96x2048
    unsigned short* w_dt  = w_x + (size_t)96 * 2048;                    // 2048x64
    unsigned short* dtr   = w_dt + (size_t)2048 * 64;                   // 8192x64 bf16
    float* hin            = (float*)(dtr + (size_t)M * 64);             // 512*16*256 f32 (8MB)
    float* xpart          = hin + (size_t)NBD * SCH * 256;              // 4x8192x96 f32 (12.6MB)
    unsigned short* xn_bf = u_bf;          // alias: dead once conv overwrites it
    float* dlt  = ur;                      // alias: ur dead after conv
    float* hloc = (float*)w_in;            // alias: w_in dead after in_proj
    float* sumd = (float*)dtr;             // alias: dtr dead after dt_proj

    // 1. fused RMSNorm->bf16 + fused weight conversions
    rmsnorm_cvt_k<<<M, 256, 0, stream>>>(hs, norm_w, xn_bf);
    cvt_all_k<<<6464, 256, 0, stream>>>(in_proj_w, out_proj_w, x_proj_w, dt_proj_w,
                                        w_in, w_out, w_x, w_dt);

    // 2. in_proj (bf16 MFMA dbuf+swz, row-skip, vectorized epilogue): ur f32 | z bf16
    gemm_bf16<0><<<(4096 / 128) * (M / 128), 256, 0, stream>>>(
        xn_bf, DMODEL, w_in, DMODEL, ur, zb, DINNER, M, 4096, DMODEL, 4096 / 128,
        nullptr, nullptr, nullptr, lengths);

    // 3. causal depthwise conv + silu + mask -> u (bf16)
    conv_silu_k<<<NB * 512, 256, 0, stream>>>(ur, conv_w, lengths, u_bf);

    // 4. x_proj split-K4 (grid 256) -> partials; reduce -> dtr bf16 + xdbl f32
    gemm_bf16<4><<<4 * (M / 128), 256, 0, stream>>>(
        u_bf, DINNER, w_x, DINNER, xpart, nullptr, 96, M, 96, 512, 1,
        nullptr, nullptr, nullptr, lengths);
    xred_k<<<M / 4, 384, 0, stream>>>(xpart, lengths, dtr, xdbl);

    // 5. dt_proj (bf16 MFMA, row-skip, fast-softplus vectorized epilogue) -> delta f32
    gemm_bf16<1><<<(DINNER / 128) * (M / 128), 256, 0, stream>>>(
        dtr, 64, w_dt, 64, dlt, nullptr, DINNER, M, DINNER, 64, DINNER / 128,
        dt_proj_b, nullptr, nullptr, lengths);

    // 6. chunked selective scan (3 phases, chunk-skip, dbuf+prefetch)
    {
        float* hlast = out + (size_t)M * DMODEL;
        scan_p1<<<SCH * 128, 256, 0, stream>>>(dlt, u_bf, xdbl, A_log, lengths, hloc, sumd);
        scan_p2<<<NBD, 256, 0, stream>>>(hloc, sumd, A_log, hin, hlast);
        scan_p3<<<SCH * 128, 256, 0, stream>>>(dlt, zb, u_bf, xdbl, A_log, D_skip, lengths, hin);
    }

    // 7. out_proj: intra-block K-split + LDS-reduced vectorized epilogue
    gemm_out_ks<<<(DMODEL / 128) * (M / 128), 512, 0, stream>>>(
        u_bf, DINNER, w_out, DINNER, out, DMODEL, hs, lengths);
}